// Round 6
// baseline (3819.295 us; speedup 1.0000x reference)
//
#include <hip/hip_runtime.h>
#include <math.h>

#define LN   720
#define NBIN 361
#define CCH  128
#define NPAIRS 8128   // 128*127/2
#define NP     4      // pairs per k_pc block (8128 = 4*2032 exactly)
#define NPG    2032   // 8128/4
#define NB     6      // bins per thread (64*6=384 >= 361)

// ---------------------------------------------------------------- tables
__global__ void k_twiddle(double* __restrict__ ct, double* __restrict__ st) {
  int m = blockIdx.x * 256 + threadIdx.x;
  if (m < LN) {
    double a = 6.2831853071795864769252867665590057684 * (double)m / 720.0;
    ct[m] = cos(a);
    st[m] = sin(a);
  }
}

// Cm[k*720+n] = ct[(k*n)%720], Sm likewise — bit-identical to the LDS gather values.
__global__ void k_wmat(const double* __restrict__ ct, const double* __restrict__ st,
                       double* __restrict__ Cm, double* __restrict__ Sm) {
  int idx = blockIdx.x * 256 + threadIdx.x;
  if (idx < NBIN * LN) {
    int k = idx / LN, n = idx - k * LN;
    int r = (int)(((long long)k * n) % LN);
    Cm[idx] = ct[r];
    Sm[idx] = st[r];
  }
}

__global__ void k_ptab(int2* __restrict__ ptab) {
  int p = blockIdx.x * 256 + threadIdx.x;
  if (p < NPAIRS) {
    int i = 0, rem = p;
    while (rem >= 127 - i) { rem -= 127 - i; i++; }
    ptab[p] = make_int2(i, i + 1 + rem);
  }
}

// D[k*720+l] and transposed Dt[l*720+k] (same values; Dt gives lane-coalesced
// phase-2 reads in k_out).
__global__ void k_dctmat(float* __restrict__ D, float* __restrict__ Dt) {
  int idx = blockIdx.x * 256 + threadIdx.x;
  if (idx < LN * LN) {
    int k = idx / LN, l = idx - k * LN;
    double ang = 3.1415926535897932384626433832795028842 * (double)((2 * l + 1) * k) / 1440.0;
    double v = cos(ang) * sqrt(2.0 / 720.0);
    if (k == 0) v *= 0.70710678118654752440084436210485;
    float f = (float)v;
    D[idx] = f;
    Dt[l * LN + k] = f;
  }
}

// ---------------------------------------------------------------- rfft (fp64 backbone) -> fp32-quantized nrf
__global__ __launch_bounds__(256) void k_rfft(const float* __restrict__ x,
                                              const double* __restrict__ ctg,
                                              const double* __restrict__ stg,
                                              float* __restrict__ nR,
                                              float* __restrict__ nI) {
  __shared__ double sd[LN];
  __shared__ double ctsP[768], stsP[768];
  int b = blockIdx.x >> 7, c = blockIdx.x & 127;
  int t = threadIdx.x;
  for (int m = t; m < LN; m += 256) {
    int a = m + (m >> 4);
    ctsP[a] = ctg[m]; stsP[a] = stg[m];
  }
  for (int l = t; l < LN; l += 256) sd[l] = (double)x[(b * LN + l) * CCH + c];
  __syncthreads();
  size_t gbase = (size_t)blockIdx.x * NBIN;
  for (int k = t; k < NBIN; k += 256) {
    double re = 0.0, im = 0.0;
    int idx = 0;
    for (int l = 0; l < LN; l++) {
      double s = sd[l];
      int a = idx + (idx >> 4);
      re += s * ctsP[a];
      im -= s * stsP[a];
      idx += k; if (idx >= LN) idx -= LN;
    }
    float reF = (float)re, imF = (float)im;        // complex64 quantization of rf
    float mag = hypotf(reF, imF);
    float d = fmaxf(mag, 1e-8f);
    nR[gbase + k] = __fdiv_rn(reF, d);
    nI[gbase + k] = __fdiv_rn(imF, d);
  }
}

// ---------------------------------------------------------------- phase correlation
// cross in strict fp32 (frozen invariant), irfft backbone fp64, k-ascending per
// accumulator. pc fp32-quantized before max/argmax; ties -> lowest index.
//
// Round 11: W=1 restructure. Key accounting: with W waves/block, B bins/thread,
// NP pairs/block, total FMA depends only on W*B (invariant at 456us), but the
// cvt(f32->f64) and LDS-read totals scale with W alone (each wave redundantly
// converts/re-reads the same cross values). Round 10 ran W=3. Now:
//  - 64-thread blocks (W=1), B=6 bins/thread, NP=4 pairs/block.
//  - whole 361-bin cross staged once in LDS as float2 [361][4] (11.6KB):
//    no k-chunking, no mid-loop barriers; 4 pairs contiguous at fixed k ->
//    2 broadcast ds_read_b128 per k-iter (was 10 ds_read_b64 per wave).
//  - cvt total drops 3x, LDS-read total drops 3x (~455us saved at issue).
// Per-(pair,bin) fp64 chains keep exact k-ascending fma order -> bit-identical.
__global__ __launch_bounds__(64, 3) void k_pc(const float* __restrict__ nR,
                                              const float* __restrict__ nI,
                                              const double* __restrict__ Cm,
                                              const double* __restrict__ Sm,
                                              const int2* __restrict__ ptab,
                                              float* __restrict__ Mv, int* __restrict__ Mi) {
  __shared__ float2 cK[NBIN][NP];        // .x = Re, .y = Im (fp32 cross), pairs contiguous
  __shared__ int2 spair[NP];
  int b = blockIdx.x / NPG;
  int pg = blockIdx.x - b * NPG;
  int pbase = pg * NP;                   // always 4 full pairs (8128 = 4*2032)
  int t = threadIdx.x;
  if (t < NP) spair[t] = ptab[pbase + t];
  __syncthreads();

  // stage the full cross spectrum for the 4 pairs (strict fp32)
#pragma unroll
  for (int p = 0; p < NP; p++) {
    int i = spair[p].x, j = spair[p].y;
    size_t ib = ((size_t)(b << 7) + i) * NBIN;
    size_t jb = ((size_t)(b << 7) + j) * NBIN;
    for (int k = t; k < NBIN; k += 64) {
      float aR = nR[ib + k], aI = nI[ib + k];
      float bR = nR[jb + k], bI = nI[jb + k];
      float xr = __fadd_rn(__fmul_rn(aR, bR), __fmul_rn(aI, bI));
      float xi = __fsub_rn(__fmul_rn(aI, bR), __fmul_rn(aR, bI));
      cK[k][p] = make_float2(xr, xi);
    }
  }
  __syncthreads();

  // thread t owns bins n = t + 64q, q=0..5 (n>360 lanes compute discarded
  // garbage; table columns up to 719 exist so loads stay in-bounds).
  double cosA[NP][NB], sinA[NP][NB];
#pragma unroll
  for (int p = 0; p < NP; p++)
#pragma unroll
    for (int q = 0; q < NB; q++) { cosA[p][q] = 0.0; sinA[p][q] = 0.0; }

  {
    const double* Cr = Cm + (size_t)1 * LN;
    const double* Sr = Sm + (size_t)1 * LN;
    double C[NB], S[NB];
#pragma unroll
    for (int q = 0; q < NB; q++) { C[q] = Cr[t + 64 * q]; S[q] = Sr[t + 64 * q]; }
    for (int k = 1; k < 360; k++) {
      // prefetch next k's table row (row k+1 <= 360 exists)
      const double* Crn = Cm + (size_t)(k + 1) * LN;
      const double* Srn = Sm + (size_t)(k + 1) * LN;
      double nC[NB], nS[NB];
#pragma unroll
      for (int q = 0; q < NB; q++) { nC[q] = Crn[t + 64 * q]; nS[q] = Srn[t + 64 * q]; }
      // broadcast-read the 4 pairs' cross at k (2 x ds_read_b128)
      float4 r0 = *(const float4*)&cK[k][0];
      float4 r1 = *(const float4*)&cK[k][2];
      double cr0 = (double)r0.x, ci0 = (double)r0.y;
      double cr1 = (double)r0.z, ci1 = (double)r0.w;
      double cr2 = (double)r1.x, ci2 = (double)r1.y;
      double cr3 = (double)r1.z, ci3 = (double)r1.w;
#pragma unroll
      for (int q = 0; q < NB; q++) {
        cosA[0][q] = fma(cr0, C[q], cosA[0][q]);
        sinA[0][q] = fma(ci0, S[q], sinA[0][q]);
        cosA[1][q] = fma(cr1, C[q], cosA[1][q]);
        sinA[1][q] = fma(ci1, S[q], sinA[1][q]);
        cosA[2][q] = fma(cr2, C[q], cosA[2][q]);
        sinA[2][q] = fma(ci2, S[q], sinA[2][q]);
        cosA[3][q] = fma(cr3, C[q], cosA[3][q]);
        sinA[3][q] = fma(ci3, S[q], sinA[3][q]);
      }
#pragma unroll
      for (int q = 0; q < NB; q++) { C[q] = nC[q]; S[q] = nS[q]; }
    }
  }

  // epilogue: fp32 quantize + argmax (both directions), single wave
#pragma unroll
  for (int p = 0; p < NP; p++) {
    float bv1 = -3.0e38f, bv2 = -3.0e38f;
    int bi1 = 0x7fffffff, bi2 = 0x7fffffff;
    double dc = (double)cK[0][p].x;
    double ny = (double)cK[360][p].x;
#pragma unroll
    for (int q = 0; q < NB; q++) {
      int n = t + 64 * q;
      if (n <= 360) {
        bool hasRev = (n >= 1) && (n <= 359);  // n=0 invalid; n=360 duplicate of fwd
        int idxF1 = n;                          // d0 index of pf_f
        int idxR1 = LN - n;                     // d0 index of pf_r
        int idxF2 = (n == 0) ? 0 : (LN - n);    // d1 index of pf_f
        int idxR2 = n;                          // d1 index of pf_r
        double sg = (n & 1) ? -ny : ny;
        double ca = cosA[p][q], sa = sinA[p][q];
        float pf_f = (float)((dc + sg + 2.0 * (ca - sa)) * (1.0 / 720.0));
        float pf_r = (float)((dc + sg + 2.0 * (ca + sa)) * (1.0 / 720.0));
        if (pf_f > bv1 || (pf_f == bv1 && idxF1 < bi1)) { bv1 = pf_f; bi1 = idxF1; }
        if (hasRev && (pf_r > bv1 || (pf_r == bv1 && idxR1 < bi1))) { bv1 = pf_r; bi1 = idxR1; }
        if (pf_f > bv2 || (pf_f == bv2 && idxF2 < bi2)) { bv2 = pf_f; bi2 = idxF2; }
        if (hasRev && (pf_r > bv2 || (pf_r == bv2 && idxR2 < bi2))) { bv2 = pf_r; bi2 = idxR2; }
      }
    }
    for (int off = 32; off >= 1; off >>= 1) {
      float ov = __shfl_down(bv1, off); int oi = __shfl_down(bi1, off);
      if (ov > bv1 || (ov == bv1 && oi < bi1)) { bv1 = ov; bi1 = oi; }
      float ov2 = __shfl_down(bv2, off); int oi2 = __shfl_down(bi2, off);
      if (ov2 > bv2 || (ov2 == bv2 && oi2 < bi2)) { bv2 = ov2; bi2 = oi2; }
    }
    if (t == 0) {
      int i = spair[p].x, j = spair[p].y;
      int o1 = (((b << 7) + i) << 7) + j;
      int o2 = (((b << 7) + j) << 7) + i;
      Mv[o1] = bv1; Mi[o1] = bi1;
      Mv[o2] = bv2; Mi[o2] = bi2;
    }
  }
}

// ---------------------------------------------------------------- top-8 (fp32, literal selection)
__global__ __launch_bounds__(64) void k_topk(const float* __restrict__ Mv, const int* __restrict__ Mi,
                                             int* __restrict__ lid, int* __restrict__ shf,
                                             float* __restrict__ rv) {
  int b = blockIdx.x >> 7, r = blockIdx.x & 127;
  if (threadIdx.x != 0) return;
  float sval[128]; int ssh[128];
  int base = (((b << 7) + r) << 7);
  for (int j = 0; j < 128; j++) {
    if (j == r) { sval[j] = -3.0e38f; ssh[j] = 0; continue; }
    float mvv = Mv[base + j]; int mii = Mi[base + j];
    sval[j] = mvv;
    ssh[j] = (mii > 360) ? (mii - 720) : mii;
  }
  for (int k = 0; k < 8; k++) {
    float best = -3.0e38f; int bj = 0;
    for (int j = 0; j < 128; j++)
      if (sval[j] > best) { best = sval[j]; bj = j; }
    int o = (((b << 7) + r) << 3) + k;
    lid[o] = bj; rv[o] = best; shf[o] = ssh[bj];
    sval[bj] = -3.0e38f;
  }
}

// ---------------------------------------------------------------- gather + DCT + bands (fp32, staged)
__global__ __launch_bounds__(256) void k_out(const float* __restrict__ x,
                                             const float* __restrict__ D,
                                             const float* __restrict__ Dt,
                                             const int* __restrict__ lid,
                                             const int* __restrict__ shf,
                                             const float* __restrict__ rv,
                                             float* __restrict__ out) {
  __shared__ float Xs[9][LN];
  __shared__ float pool[9216];   // phase1/2: xe[9*720]; phase3: obuf[256*36]
  __shared__ int s_lid[8], s_shf[8];
  __shared__ float s_r[8];
  int b = blockIdx.x >> 7, c = blockIdx.x & 127;
  int t = threadIdx.x;
  if (t < 8) {
    int q = (((b << 7) + c) << 3) + t;
    s_lid[t] = lid[q]; s_shf[t] = shf[q]; s_r[t] = rv[q];
  }
  float* xe = pool;
  for (int l = t; l < LN; l += 256) xe[l] = x[(b * LN + l) * CCH + c];
  __syncthreads();
  for (int p = 1; p <= 8; p++) {
    float r = s_r[p - 1];
    if (fabsf(r) < 0.1f) {
      for (int l = t; l < LN; l += 256) xe[p * LN + l] = xe[l];
    } else {
      float sg = (r < 0.f) ? -1.f : 1.f;
      int ld = s_lid[p - 1], sh = s_shf[p - 1];
      for (int l = t; l < LN; l += 256) {
        int tt = l - sh; tt = tt < 0 ? 0 : (tt > 719 ? 719 : tt);
        xe[p * LN + l] = sg * x[(b * LN + tt) * CCH + ld];
      }
    }
  }
  __syncthreads();

  // Phase 2: X[p,k] = sum_l D[k,l]*xe[p,l]. Reads via Dt[l*720+k] so lane k
  // is consecutive -> coalesced (D[k*720+l] had 2880B lane stride).
  {
    int k0 = t, k1 = t + 256, k2 = t + 512;
    int k2c = (k2 < LN) ? k2 : k0;
    float a0[9], a1[9], a2[9];
#pragma unroll
    for (int p = 0; p < 9; p++) { a0[p] = 0.f; a1[p] = 0.f; a2[p] = 0.f; }
    const float* DtRow = Dt;
    for (int l = 0; l < LN; l++) {
      float xl[9];
#pragma unroll
      for (int p = 0; p < 9; p++) xl[p] = xe[p * LN + l];
      float d0 = DtRow[k0], d1 = DtRow[k1], d2 = DtRow[k2c];
      DtRow += LN;
#pragma unroll
      for (int p = 0; p < 9; p++) {
        a0[p] += d0 * xl[p];
        a1[p] += d1 * xl[p];
        a2[p] += d2 * xl[p];
      }
    }
#pragma unroll
    for (int p = 0; p < 9; p++) {
      Xs[p][k0] = a0[p];
      Xs[p][k1] = a1[p];
      if (k2 < LN) Xs[p][k2] = a2[p];
    }
  }
  __syncthreads();

  // Phase 3: bands, chunked over n for coalesced output
  float* obuf = pool;
  size_t outbase = (size_t)((b << 7) + c) * (LN * 36);
  for (int n0 = 0; n0 < LN; n0 += 256) {
    int nt = t & 63;
    int f = t >> 6;
    int nloc = nt * 4;
    int nchunk = (LN - n0 < 256) ? (LN - n0) : 256;
    bool act = (nloc < nchunk);
    float a[36];
#pragma unroll
    for (int q = 0; q < 36; q++) a[q] = 0.f;
    if (act) {
      const float* Dp = D + (size_t)(f * 180) * LN + (n0 + nloc);
      for (int k = 0; k < 180; k++) {
        float4 d = *(const float4*)Dp;
        Dp += LN;
        int kk = f * 180 + k;
#pragma unroll
        for (int p = 0; p < 9; p++) {
          float xv = Xs[p][kk];
          a[p * 4 + 0] += d.x * xv;
          a[p * 4 + 1] += d.y * xv;
          a[p * 4 + 2] += d.z * xv;
          a[p * 4 + 3] += d.w * xv;
        }
      }
#pragma unroll
      for (int p = 0; p < 9; p++)
#pragma unroll
        for (int nn = 0; nn < 4; nn++)
          obuf[(nloc + nn) * 36 + p * 4 + f] = a[p * 4 + nn];
    }
    __syncthreads();
    int tot = nchunk * 36;
    for (int idx = t; idx < tot; idx += 256)
      out[outbase + (size_t)n0 * 36 + idx] = obuf[idx];
    __syncthreads();
  }
}

// ---------------------------------------------------------------- launch
extern "C" void kernel_launch(void* const* d_in, const int* in_sizes, int n_in,
                              void* d_out, int out_size, void* d_ws, size_t ws_size,
                              hipStream_t stream) {
  const float* x = (const float*)d_in[0];
  float* out = (float*)d_out;

  char* ws = (char*)d_ws;
  double* ct  = (double*)ws;                      // 720
  double* st  = ct + 720;                         // 720
  double* Cm  = st + 720;                         // 361*720
  double* Sm  = Cm + NBIN * LN;                   // 361*720
  float*  nRr = (float*)(Sm + NBIN * LN);         // 1024*361
  float*  nIr = nRr + 1024 * NBIN;                // 1024*361
  float*  Mv  = nIr + 1024 * NBIN;                // 8*128*128
  float*  rv  = Mv + 8 * 128 * 128;               // 8*128*8
  float*  D   = rv + 8 * 128 * 8;                 // 720*720 (16B-aligned)
  float*  Dt  = D + 720 * 720;                    // 720*720 transposed copy
  int*    Mi  = (int*)(Dt + 720 * 720);           // 8*128*128
  int*    lid = Mi + 8 * 128 * 128;               // 8*128*8
  int*    shf = lid + 8 * 128 * 8;                // 8*128*8
  int2*   ptab = (int2*)(shf + 8 * 128 * 8);      // 8128

  k_twiddle<<<3, 256, 0, stream>>>(ct, st);
  k_wmat<<<(NBIN * LN + 255) / 256, 256, 0, stream>>>(ct, st, Cm, Sm);
  k_ptab<<<(NPAIRS + 255) / 256, 256, 0, stream>>>(ptab);
  k_dctmat<<<(720 * 720 + 255) / 256, 256, 0, stream>>>(D, Dt);
  k_rfft<<<8 * 128, 256, 0, stream>>>(x, ct, st, nRr, nIr);
  k_pc<<<8 * NPG, 64, 0, stream>>>(nRr, nIr, Cm, Sm, ptab, Mv, Mi);
  k_topk<<<8 * 128, 64, 0, stream>>>(Mv, Mi, lid, shf, rv);
  k_out<<<8 * 128, 256, 0, stream>>>(x, D, Dt, lid, shf, rv, out);
}

// Round 7
// 1905.960 us; speedup vs baseline: 2.0039x; 2.0039x over previous
//
#include <hip/hip_runtime.h>
#include <math.h>

#define LN   720
#define NBIN 361
#define CCH  128
#define NPAIRS 8128   // 128*127/2
#define NP     8      // pairs per k_pc block (8128 = 8*1016 exactly)
#define NPG    1016   // 8128/8
#define NB     3      // bins per thread (128*3=384 >= 361)
#define TCOLS  384    // compact table columns (only n<384 ever read)

// ---------------------------------------------------------------- tables
__global__ void k_twiddle(double* __restrict__ ct, double* __restrict__ st) {
  int m = blockIdx.x * 256 + threadIdx.x;
  if (m < LN) {
    double a = 6.2831853071795864769252867665590057684 * (double)m / 720.0;
    ct[m] = cos(a);
    st[m] = sin(a);
  }
}

// Compact: Cm[k*384+n] = ct[(k*n)%720] for n<384 (only columns 0..383 are read
// by k_pc). 2 x 361*384*8B = 2.2MB -> fits a 4MB XCD L2. Values bit-identical.
__global__ void k_wmat(const double* __restrict__ ct, const double* __restrict__ st,
                       double* __restrict__ Cm, double* __restrict__ Sm) {
  int idx = blockIdx.x * 256 + threadIdx.x;
  if (idx < NBIN * TCOLS) {
    int k = idx / TCOLS, n = idx - k * TCOLS;
    int r = (int)(((long long)k * n) % LN);
    Cm[idx] = ct[r];
    Sm[idx] = st[r];
  }
}

__global__ void k_ptab(int2* __restrict__ ptab) {
  int p = blockIdx.x * 256 + threadIdx.x;
  if (p < NPAIRS) {
    int i = 0, rem = p;
    while (rem >= 127 - i) { rem -= 127 - i; i++; }
    ptab[p] = make_int2(i, i + 1 + rem);
  }
}

// D[k*720+l] and transposed Dt[l*720+k] (same values; Dt gives lane-coalesced
// phase-2 reads in k_out).
__global__ void k_dctmat(float* __restrict__ D, float* __restrict__ Dt) {
  int idx = blockIdx.x * 256 + threadIdx.x;
  if (idx < LN * LN) {
    int k = idx / LN, l = idx - k * LN;
    double ang = 3.1415926535897932384626433832795028842 * (double)((2 * l + 1) * k) / 1440.0;
    double v = cos(ang) * sqrt(2.0 / 720.0);
    if (k == 0) v *= 0.70710678118654752440084436210485;
    float f = (float)v;
    D[idx] = f;
    Dt[l * LN + k] = f;
  }
}

// ---------------------------------------------------------------- rfft (fp64 backbone) -> fp32-quantized nrf
__global__ __launch_bounds__(256) void k_rfft(const float* __restrict__ x,
                                              const double* __restrict__ ctg,
                                              const double* __restrict__ stg,
                                              float* __restrict__ nR,
                                              float* __restrict__ nI) {
  __shared__ double sd[LN];
  __shared__ double ctsP[768], stsP[768];
  int b = blockIdx.x >> 7, c = blockIdx.x & 127;
  int t = threadIdx.x;
  for (int m = t; m < LN; m += 256) {
    int a = m + (m >> 4);
    ctsP[a] = ctg[m]; stsP[a] = stg[m];
  }
  for (int l = t; l < LN; l += 256) sd[l] = (double)x[(b * LN + l) * CCH + c];
  __syncthreads();
  size_t gbase = (size_t)blockIdx.x * NBIN;
  for (int k = t; k < NBIN; k += 256) {
    double re = 0.0, im = 0.0;
    int idx = 0;
    for (int l = 0; l < LN; l++) {
      double s = sd[l];
      int a = idx + (idx >> 4);
      re += s * ctsP[a];
      im -= s * stsP[a];
      idx += k; if (idx >= LN) idx -= LN;
    }
    float reF = (float)re, imF = (float)im;        // complex64 quantization of rf
    float mag = hypotf(reF, imF);
    float d = fmaxf(mag, 1e-8f);
    nR[gbase + k] = __fdiv_rn(reF, d);
    nI[gbase + k] = __fdiv_rn(imF, d);
  }
}

// ---------------------------------------------------------------- phase correlation
// cross in strict fp32 (frozen invariant), irfft backbone fp64, k-ascending per
// accumulator. pc fp32-quantized before max/argmax; ties -> lowest index.
//
// Round 12: re-balance of round 11's failed W=1 config using the calibrated
// pipe model (FMA/SIMD floor 457us; LDS-broadcast ~ NW*NP/2 per iter; table
// loads ~ NW*NB; per-thread regs = 2*NP*NB fp64):
//  - NP=8 pairs, 2 waves (128 thr), NB=3 bins/thread -> acc = 48 doubles/thread
//    (half of round 11), LDS pipe ~304us, TA ~228us, VALU ~533us.
//  - compact fp64 tables [361][384] (2.2MB, L2-resident; old 4.2MB straddled
//    the 4MB XCD L2).
//  - launch_bounds(128,2): arg2>=3 made the allocator register-anorexic three
//    times (r1/r4/r6) -> never again. Cap 256, compiler takes what it needs.
//  - staging writes flat-contiguous (r6's cK[k][p] lane-stride-32B writes were
//    a 16-way bank conflict, 4.4M cycles).
// Math/order unchanged -> bit-identical Mv/Mi.
__global__ __launch_bounds__(128, 2) void k_pc(const float* __restrict__ nR,
                                               const float* __restrict__ nI,
                                               const double* __restrict__ Cm,
                                               const double* __restrict__ Sm,
                                               const int2* __restrict__ ptab,
                                               float* __restrict__ Mv, int* __restrict__ Mi) {
  __shared__ float2 cK[NBIN][NP];        // fp32 cross; pairs contiguous at fixed k
  __shared__ int2 spair[NP];
  __shared__ float wv[2][NP][2];
  __shared__ int   wi[2][NP][2];
  int b = blockIdx.x / NPG;
  int pg = blockIdx.x - b * NPG;
  int pbase = pg * NP;                   // always 8 full pairs (8128 = 8*1016)
  int t = threadIdx.x;
  if (t < NP) spair[t] = ptab[pbase + t];
  __syncthreads();

  // stage cross for the 8 pairs (strict fp32). Flat index v -> k=v>>3, p=v&7:
  // consecutive lanes write consecutive float2 -> contiguous b64, no big
  // bank conflicts.
  for (int v = t; v < NP * NBIN; v += 128) {
    int p = v & 7, k = v >> 3;
    int i = spair[p].x, j = spair[p].y;
    size_t ib = ((size_t)(b << 7) + i) * NBIN + k;
    size_t jb = ((size_t)(b << 7) + j) * NBIN + k;
    float aR = nR[ib], aI = nI[ib];
    float bR = nR[jb], bI = nI[jb];
    float xr = __fadd_rn(__fmul_rn(aR, bR), __fmul_rn(aI, bI));
    float xi = __fsub_rn(__fmul_rn(aI, bR), __fmul_rn(aR, bI));
    cK[k][p] = make_float2(xr, xi);
  }
  __syncthreads();

  // thread t owns bins n = t + 128q, q=0..2 (n>360 lanes compute discarded
  // garbage; compact tables have 384 columns so loads stay in-bounds).
  double cosA[NP][NB], sinA[NP][NB];
#pragma unroll
  for (int p = 0; p < NP; p++)
#pragma unroll
    for (int q = 0; q < NB; q++) { cosA[p][q] = 0.0; sinA[p][q] = 0.0; }

  {
    const double* Cr = Cm + (size_t)1 * TCOLS;
    const double* Sr = Sm + (size_t)1 * TCOLS;
    double C[NB], S[NB];
#pragma unroll
    for (int q = 0; q < NB; q++) { C[q] = Cr[t + 128 * q]; S[q] = Sr[t + 128 * q]; }
    for (int k = 1; k < 360; k++) {
      // prefetch next k's table row (row k+1 <= 360 exists)
      const double* Crn = Cm + (size_t)(k + 1) * TCOLS;
      const double* Srn = Sm + (size_t)(k + 1) * TCOLS;
      double nC[NB], nS[NB];
#pragma unroll
      for (int q = 0; q < NB; q++) { nC[q] = Crn[t + 128 * q]; nS[q] = Srn[t + 128 * q]; }
      // broadcast-read the 8 pairs' cross at k (4 x uniform ds_read_b128)
      float4 r0 = *(const float4*)&cK[k][0];
      float4 r1 = *(const float4*)&cK[k][2];
      float4 r2 = *(const float4*)&cK[k][4];
      float4 r3 = *(const float4*)&cK[k][6];
      double cr[NP], ci[NP];
      cr[0] = (double)r0.x; ci[0] = (double)r0.y;
      cr[1] = (double)r0.z; ci[1] = (double)r0.w;
      cr[2] = (double)r1.x; ci[2] = (double)r1.y;
      cr[3] = (double)r1.z; ci[3] = (double)r1.w;
      cr[4] = (double)r2.x; ci[4] = (double)r2.y;
      cr[5] = (double)r2.z; ci[5] = (double)r2.w;
      cr[6] = (double)r3.x; ci[6] = (double)r3.y;
      cr[7] = (double)r3.z; ci[7] = (double)r3.w;
#pragma unroll
      for (int q = 0; q < NB; q++) {
#pragma unroll
        for (int p = 0; p < NP; p++) {
          cosA[p][q] = fma(cr[p], C[q], cosA[p][q]);
          sinA[p][q] = fma(ci[p], S[q], sinA[p][q]);
        }
      }
#pragma unroll
      for (int q = 0; q < NB; q++) { C[q] = nC[q]; S[q] = nS[q]; }
    }
  }

  // epilogue: fp32 quantize + argmax (both directions), p-outer scalars,
  // wave-reduce then 2-way LDS merge.
  int lane = t & 63, w = t >> 6;
#pragma unroll
  for (int p = 0; p < NP; p++) {
    float bv1 = -3.0e38f, bv2 = -3.0e38f;
    int bi1 = 0x7fffffff, bi2 = 0x7fffffff;
    double dc = (double)cK[0][p].x;
    double ny = (double)cK[360][p].x;
#pragma unroll
    for (int q = 0; q < NB; q++) {
      int n = t + 128 * q;
      if (n <= 360) {
        bool hasRev = (n >= 1) && (n <= 359);  // n=0 invalid; n=360 duplicate of fwd
        int idxF1 = n;                          // d0 index of pf_f
        int idxR1 = LN - n;                     // d0 index of pf_r
        int idxF2 = (n == 0) ? 0 : (LN - n);    // d1 index of pf_f
        int idxR2 = n;                          // d1 index of pf_r
        double sg = (n & 1) ? -ny : ny;
        double ca = cosA[p][q], sa = sinA[p][q];
        float pf_f = (float)((dc + sg + 2.0 * (ca - sa)) * (1.0 / 720.0));
        float pf_r = (float)((dc + sg + 2.0 * (ca + sa)) * (1.0 / 720.0));
        if (pf_f > bv1 || (pf_f == bv1 && idxF1 < bi1)) { bv1 = pf_f; bi1 = idxF1; }
        if (hasRev && (pf_r > bv1 || (pf_r == bv1 && idxR1 < bi1))) { bv1 = pf_r; bi1 = idxR1; }
        if (pf_f > bv2 || (pf_f == bv2 && idxF2 < bi2)) { bv2 = pf_f; bi2 = idxF2; }
        if (hasRev && (pf_r > bv2 || (pf_r == bv2 && idxR2 < bi2))) { bv2 = pf_r; bi2 = idxR2; }
      }
    }
    for (int off = 32; off >= 1; off >>= 1) {
      float ov = __shfl_down(bv1, off); int oi = __shfl_down(bi1, off);
      if (ov > bv1 || (ov == bv1 && oi < bi1)) { bv1 = ov; bi1 = oi; }
      float ov2 = __shfl_down(bv2, off); int oi2 = __shfl_down(bi2, off);
      if (ov2 > bv2 || (ov2 == bv2 && oi2 < bi2)) { bv2 = ov2; bi2 = oi2; }
    }
    if (lane == 0) {
      wv[w][p][0] = bv1; wi[w][p][0] = bi1;
      wv[w][p][1] = bv2; wi[w][p][1] = bi2;
    }
  }
  __syncthreads();
  if (t < NP * 2) {
    int p = t >> 1, d = t & 1;
    float bv = wv[0][p][d]; int bi = wi[0][p][d];
    float ov = wv[1][p][d]; int oi = wi[1][p][d];
    if (ov > bv || (ov == bv && oi < bi)) { bv = ov; bi = oi; }
    int i = spair[p].x, j = spair[p].y;
    int o = d ? ((((b << 7) + j) << 7) + i) : ((((b << 7) + i) << 7) + j);
    Mv[o] = bv; Mi[o] = bi;
  }
}

// ---------------------------------------------------------------- top-8 (fp32, literal selection)
__global__ __launch_bounds__(64) void k_topk(const float* __restrict__ Mv, const int* __restrict__ Mi,
                                             int* __restrict__ lid, int* __restrict__ shf,
                                             float* __restrict__ rv) {
  int b = blockIdx.x >> 7, r = blockIdx.x & 127;
  if (threadIdx.x != 0) return;
  float sval[128]; int ssh[128];
  int base = (((b << 7) + r) << 7);
  for (int j = 0; j < 128; j++) {
    if (j == r) { sval[j] = -3.0e38f; ssh[j] = 0; continue; }
    float mvv = Mv[base + j]; int mii = Mi[base + j];
    sval[j] = mvv;
    ssh[j] = (mii > 360) ? (mii - 720) : mii;
  }
  for (int k = 0; k < 8; k++) {
    float best = -3.0e38f; int bj = 0;
    for (int j = 0; j < 128; j++)
      if (sval[j] > best) { best = sval[j]; bj = j; }
    int o = (((b << 7) + r) << 3) + k;
    lid[o] = bj; rv[o] = best; shf[o] = ssh[bj];
    sval[bj] = -3.0e38f;
  }
}

// ---------------------------------------------------------------- gather + DCT + bands (fp32, staged)
__global__ __launch_bounds__(256) void k_out(const float* __restrict__ x,
                                             const float* __restrict__ D,
                                             const float* __restrict__ Dt,
                                             const int* __restrict__ lid,
                                             const int* __restrict__ shf,
                                             const float* __restrict__ rv,
                                             float* __restrict__ out) {
  __shared__ float Xs[9][LN];
  __shared__ float pool[9216];   // phase1/2: xe[9*720]; phase3: obuf[256*36]
  __shared__ int s_lid[8], s_shf[8];
  __shared__ float s_r[8];
  int b = blockIdx.x >> 7, c = blockIdx.x & 127;
  int t = threadIdx.x;
  if (t < 8) {
    int q = (((b << 7) + c) << 3) + t;
    s_lid[t] = lid[q]; s_shf[t] = shf[q]; s_r[t] = rv[q];
  }
  float* xe = pool;
  for (int l = t; l < LN; l += 256) xe[l] = x[(b * LN + l) * CCH + c];
  __syncthreads();
  for (int p = 1; p <= 8; p++) {
    float r = s_r[p - 1];
    if (fabsf(r) < 0.1f) {
      for (int l = t; l < LN; l += 256) xe[p * LN + l] = xe[l];
    } else {
      float sg = (r < 0.f) ? -1.f : 1.f;
      int ld = s_lid[p - 1], sh = s_shf[p - 1];
      for (int l = t; l < LN; l += 256) {
        int tt = l - sh; tt = tt < 0 ? 0 : (tt > 719 ? 719 : tt);
        xe[p * LN + l] = sg * x[(b * LN + tt) * CCH + ld];
      }
    }
  }
  __syncthreads();

  // Phase 2: X[p,k] = sum_l D[k,l]*xe[p,l]. Reads via Dt[l*720+k] so lane k
  // is consecutive -> coalesced (D[k*720+l] had 2880B lane stride).
  {
    int k0 = t, k1 = t + 256, k2 = t + 512;
    int k2c = (k2 < LN) ? k2 : k0;
    float a0[9], a1[9], a2[9];
#pragma unroll
    for (int p = 0; p < 9; p++) { a0[p] = 0.f; a1[p] = 0.f; a2[p] = 0.f; }
    const float* DtRow = Dt;
    for (int l = 0; l < LN; l++) {
      float xl[9];
#pragma unroll
      for (int p = 0; p < 9; p++) xl[p] = xe[p * LN + l];
      float d0 = DtRow[k0], d1 = DtRow[k1], d2 = DtRow[k2c];
      DtRow += LN;
#pragma unroll
      for (int p = 0; p < 9; p++) {
        a0[p] += d0 * xl[p];
        a1[p] += d1 * xl[p];
        a2[p] += d2 * xl[p];
      }
    }
#pragma unroll
    for (int p = 0; p < 9; p++) {
      Xs[p][k0] = a0[p];
      Xs[p][k1] = a1[p];
      if (k2 < LN) Xs[p][k2] = a2[p];
    }
  }
  __syncthreads();

  // Phase 3: bands, chunked over n for coalesced output
  float* obuf = pool;
  size_t outbase = (size_t)((b << 7) + c) * (LN * 36);
  for (int n0 = 0; n0 < LN; n0 += 256) {
    int nt = t & 63;
    int f = t >> 6;
    int nloc = nt * 4;
    int nchunk = (LN - n0 < 256) ? (LN - n0) : 256;
    bool act = (nloc < nchunk);
    float a[36];
#pragma unroll
    for (int q = 0; q < 36; q++) a[q] = 0.f;
    if (act) {
      const float* Dp = D + (size_t)(f * 180) * LN + (n0 + nloc);
      for (int k = 0; k < 180; k++) {
        float4 d = *(const float4*)Dp;
        Dp += LN;
        int kk = f * 180 + k;
#pragma unroll
        for (int p = 0; p < 9; p++) {
          float xv = Xs[p][kk];
          a[p * 4 + 0] += d.x * xv;
          a[p * 4 + 1] += d.y * xv;
          a[p * 4 + 2] += d.z * xv;
          a[p * 4 + 3] += d.w * xv;
        }
      }
#pragma unroll
      for (int p = 0; p < 9; p++)
#pragma unroll
        for (int nn = 0; nn < 4; nn++)
          obuf[(nloc + nn) * 36 + p * 4 + f] = a[p * 4 + nn];
    }
    __syncthreads();
    int tot = nchunk * 36;
    for (int idx = t; idx < tot; idx += 256)
      out[outbase + (size_t)n0 * 36 + idx] = obuf[idx];
    __syncthreads();
  }
}

// ---------------------------------------------------------------- launch
extern "C" void kernel_launch(void* const* d_in, const int* in_sizes, int n_in,
                              void* d_out, int out_size, void* d_ws, size_t ws_size,
                              hipStream_t stream) {
  const float* x = (const float*)d_in[0];
  float* out = (float*)d_out;

  char* ws = (char*)d_ws;
  double* ct  = (double*)ws;                      // 720
  double* st  = ct + 720;                         // 720
  double* Cm  = st + 720;                         // 361*384 compact
  double* Sm  = Cm + NBIN * TCOLS;                // 361*384 compact
  float*  nRr = (float*)(Sm + NBIN * TCOLS);      // 1024*361
  float*  nIr = nRr + 1024 * NBIN;                // 1024*361
  float*  Mv  = nIr + 1024 * NBIN;                // 8*128*128
  float*  rv  = Mv + 8 * 128 * 128;               // 8*128*8
  float*  D   = rv + 8 * 128 * 8;                 // 720*720 (16B-aligned)
  float*  Dt  = D + 720 * 720;                    // 720*720 transposed copy
  int*    Mi  = (int*)(Dt + 720 * 720);           // 8*128*128
  int*    lid = Mi + 8 * 128 * 128;               // 8*128*8
  int*    shf = lid + 8 * 128 * 8;                // 8*128*8
  int2*   ptab = (int2*)(shf + 8 * 128 * 8);      // 8128

  k_twiddle<<<3, 256, 0, stream>>>(ct, st);
  k_wmat<<<(NBIN * TCOLS + 255) / 256, 256, 0, stream>>>(ct, st, Cm, Sm);
  k_ptab<<<(NPAIRS + 255) / 256, 256, 0, stream>>>(ptab);
  k_dctmat<<<(720 * 720 + 255) / 256, 256, 0, stream>>>(D, Dt);
  k_rfft<<<8 * 128, 256, 0, stream>>>(x, ct, st, nRr, nIr);
  k_pc<<<8 * NPG, 128, 0, stream>>>(nRr, nIr, Cm, Sm, ptab, Mv, Mi);
  k_topk<<<8 * 128, 64, 0, stream>>>(Mv, Mi, lid, shf, rv);
  k_out<<<8 * 128, 256, 0, stream>>>(x, D, Dt, lid, shf, rv, out);
}

// Round 8
// 1905.826 us; speedup vs baseline: 2.0040x; 1.0001x over previous
//
#include <hip/hip_runtime.h>
#include <math.h>

#define LN   720
#define NBIN 361
#define CCH  128
#define NPAIRS 8128   // 128*127/2
#define NP     8      // pairs per k_pc block (8128 = 8*1016 exactly)
#define NPG    1016   // 8128/8
#define NB     3      // bins per thread (128*3=384 >= 361)
#define TCOLS  384    // compact table columns (only n<384 ever read)

// ---------------------------------------------------------------- tables
__global__ void k_twiddle(double* __restrict__ ct, double* __restrict__ st) {
  int m = blockIdx.x * 256 + threadIdx.x;
  if (m < LN) {
    double a = 6.2831853071795864769252867665590057684 * (double)m / 720.0;
    ct[m] = cos(a);
    st[m] = sin(a);
  }
}

// Compact: Cm[k*384+n] = ct[(k*n)%720] for n<384 (only columns 0..383 are read
// by k_pc). 2 x 361*384*8B = 2.2MB -> fits a 4MB XCD L2. Values bit-identical.
__global__ void k_wmat(const double* __restrict__ ct, const double* __restrict__ st,
                       double* __restrict__ Cm, double* __restrict__ Sm) {
  int idx = blockIdx.x * 256 + threadIdx.x;
  if (idx < NBIN * TCOLS) {
    int k = idx / TCOLS, n = idx - k * TCOLS;
    int r = (int)(((long long)k * n) % LN);
    Cm[idx] = ct[r];
    Sm[idx] = st[r];
  }
}

__global__ void k_ptab(int2* __restrict__ ptab) {
  int p = blockIdx.x * 256 + threadIdx.x;
  if (p < NPAIRS) {
    int i = 0, rem = p;
    while (rem >= 127 - i) { rem -= 127 - i; i++; }
    ptab[p] = make_int2(i, i + 1 + rem);
  }
}

// D[k*720+l] and transposed Dt[l*720+k] (same values; Dt gives lane-coalesced
// phase-2 reads in k_out).
__global__ void k_dctmat(float* __restrict__ D, float* __restrict__ Dt) {
  int idx = blockIdx.x * 256 + threadIdx.x;
  if (idx < LN * LN) {
    int k = idx / LN, l = idx - k * LN;
    double ang = 3.1415926535897932384626433832795028842 * (double)((2 * l + 1) * k) / 1440.0;
    double v = cos(ang) * sqrt(2.0 / 720.0);
    if (k == 0) v *= 0.70710678118654752440084436210485;
    float f = (float)v;
    D[idx] = f;
    Dt[l * LN + k] = f;
  }
}

// ---------------------------------------------------------------- rfft (fp64 backbone) -> fp32-quantized nrf
__global__ __launch_bounds__(256) void k_rfft(const float* __restrict__ x,
                                              const double* __restrict__ ctg,
                                              const double* __restrict__ stg,
                                              float* __restrict__ nR,
                                              float* __restrict__ nI) {
  __shared__ double sd[LN];
  __shared__ double ctsP[768], stsP[768];
  int b = blockIdx.x >> 7, c = blockIdx.x & 127;
  int t = threadIdx.x;
  for (int m = t; m < LN; m += 256) {
    int a = m + (m >> 4);
    ctsP[a] = ctg[m]; stsP[a] = stg[m];
  }
  for (int l = t; l < LN; l += 256) sd[l] = (double)x[(b * LN + l) * CCH + c];
  __syncthreads();
  size_t gbase = (size_t)blockIdx.x * NBIN;
  for (int k = t; k < NBIN; k += 256) {
    double re = 0.0, im = 0.0;
    int idx = 0;
    for (int l = 0; l < LN; l++) {
      double s = sd[l];
      int a = idx + (idx >> 4);
      re += s * ctsP[a];
      im -= s * stsP[a];
      idx += k; if (idx >= LN) idx -= LN;
    }
    float reF = (float)re, imF = (float)im;        // complex64 quantization of rf
    float mag = hypotf(reF, imF);
    float d = fmaxf(mag, 1e-8f);
    nR[gbase + k] = __fdiv_rn(reF, d);
    nI[gbase + k] = __fdiv_rn(imF, d);
  }
}

// ---------------------------------------------------------------- phase correlation
// cross in strict fp32 (frozen invariant), irfft backbone fp64, k-ascending per
// accumulator. pc fp32-quantized before max/argmax; ties -> lowest index.
//
// Round 13 (on top of round 12): the 4 ds_read_b128 broadcast reads of cK[k]
// were consumed immediately -> ~120cy exposed LDS latency per iter at only
// ~2.5 waves/SIMD (VALUBusy 66%). Now BOTH the C/S table row AND the cK row
// are prefetched one k ahead, with a manual unroll-by-2 (explicit A/B register
// sets: no dynamic indexing, no swap moves). The prefetch issues before the
// 48-fma burst (~192cy) which fully covers L2 (~300cy, 1 iter ahead) and LDS
// (~120cy) latency. Scheduling-only change -> bit-identical output.
// VGPR note: compiler parks the 48 fp64 accumulators in AGPRs (gfx950 unified
// file, VALU-addressable, no memory traffic) -> arch VGPR_Count stays low.
__global__ __launch_bounds__(128, 2) void k_pc(const float* __restrict__ nR,
                                               const float* __restrict__ nI,
                                               const double* __restrict__ Cm,
                                               const double* __restrict__ Sm,
                                               const int2* __restrict__ ptab,
                                               float* __restrict__ Mv, int* __restrict__ Mi) {
  __shared__ float2 cK[NBIN][NP];        // fp32 cross; pairs contiguous at fixed k
  __shared__ int2 spair[NP];
  __shared__ float wv[2][NP][2];
  __shared__ int   wi[2][NP][2];
  int b = blockIdx.x / NPG;
  int pg = blockIdx.x - b * NPG;
  int pbase = pg * NP;                   // always 8 full pairs (8128 = 8*1016)
  int t = threadIdx.x;
  if (t < NP) spair[t] = ptab[pbase + t];
  __syncthreads();

  // stage cross for the 8 pairs (strict fp32). Flat index v -> k=v>>3, p=v&7:
  // consecutive lanes write consecutive float2 -> contiguous b64 writes.
  for (int v = t; v < NP * NBIN; v += 128) {
    int p = v & 7, k = v >> 3;
    int i = spair[p].x, j = spair[p].y;
    size_t ib = ((size_t)(b << 7) + i) * NBIN + k;
    size_t jb = ((size_t)(b << 7) + j) * NBIN + k;
    float aR = nR[ib], aI = nI[ib];
    float bR = nR[jb], bI = nI[jb];
    float xr = __fadd_rn(__fmul_rn(aR, bR), __fmul_rn(aI, bI));
    float xi = __fsub_rn(__fmul_rn(aI, bR), __fmul_rn(aR, bI));
    cK[k][p] = make_float2(xr, xi);
  }
  __syncthreads();

  // thread t owns bins n = t + 128q, q=0..2 (n>360 lanes compute discarded
  // garbage; compact tables have 384 columns so loads stay in-bounds).
  double cosA[NP][NB], sinA[NP][NB];
#pragma unroll
  for (int p = 0; p < NP; p++)
#pragma unroll
    for (int q = 0; q < NB; q++) { cosA[p][q] = 0.0; sinA[p][q] = 0.0; }

  {
    // --- software-pipelined main loop, manual unroll-2 (A/B sets) ---
    // A set holds data for k; B set for k+1.
    double CA[NB], SA[NB], CB[NB], SB[NB];
    float4 a0, a1, a2, a3, b0, b1, b2, b3;
    {
      const double* Cr = Cm + (size_t)1 * TCOLS;
      const double* Sr = Sm + (size_t)1 * TCOLS;
#pragma unroll
      for (int q = 0; q < NB; q++) { CA[q] = Cr[t + 128 * q]; SA[q] = Sr[t + 128 * q]; }
      a0 = *(const float4*)&cK[1][0];
      a1 = *(const float4*)&cK[1][2];
      a2 = *(const float4*)&cK[1][4];
      a3 = *(const float4*)&cK[1][6];
    }

#define PREFETCH(kk, Cd, Sd, r0, r1, r2, r3)                         \
    {                                                                \
      const double* Crn = Cm + (size_t)(kk) * TCOLS;                 \
      const double* Srn = Sm + (size_t)(kk) * TCOLS;                 \
      _Pragma("unroll")                                              \
      for (int q = 0; q < NB; q++) {                                 \
        Cd[q] = Crn[t + 128 * q]; Sd[q] = Srn[t + 128 * q];          \
      }                                                              \
      r0 = *(const float4*)&cK[kk][0];                               \
      r1 = *(const float4*)&cK[kk][2];                               \
      r2 = *(const float4*)&cK[kk][4];                               \
      r3 = *(const float4*)&cK[kk][6];                               \
    }

#define COMPUTE(Cs, Ss, r0, r1, r2, r3)                              \
    {                                                                \
      double cr[NP], ci[NP];                                         \
      cr[0] = (double)r0.x; ci[0] = (double)r0.y;                    \
      cr[1] = (double)r0.z; ci[1] = (double)r0.w;                    \
      cr[2] = (double)r1.x; ci[2] = (double)r1.y;                    \
      cr[3] = (double)r1.z; ci[3] = (double)r1.w;                    \
      cr[4] = (double)r2.x; ci[4] = (double)r2.y;                    \
      cr[5] = (double)r2.z; ci[5] = (double)r2.w;                    \
      cr[6] = (double)r3.x; ci[6] = (double)r3.y;                    \
      cr[7] = (double)r3.z; ci[7] = (double)r3.w;                    \
      _Pragma("unroll")                                              \
      for (int q = 0; q < NB; q++) {                                 \
        _Pragma("unroll")                                            \
        for (int p = 0; p < NP; p++) {                               \
          cosA[p][q] = fma(cr[p], Cs[q], cosA[p][q]);                \
          sinA[p][q] = fma(ci[p], Ss[q], sinA[p][q]);                \
        }                                                            \
      }                                                              \
    }

    for (int k = 1; k < 359; k += 2) {
      PREFETCH(k + 1, CB, SB, b0, b1, b2, b3);   // for iter k+1
      COMPUTE(CA, SA, a0, a1, a2, a3);           // iter k
      PREFETCH(k + 2, CA, SA, a0, a1, a2, a3);   // for iter k+2 (row 360 exists)
      COMPUTE(CB, SB, b0, b1, b2, b3);           // iter k+1
    }
    // tail: k = 359 (A set was prefetched by the last loop body)
    COMPUTE(CA, SA, a0, a1, a2, a3);
#undef PREFETCH
#undef COMPUTE
  }

  // epilogue: fp32 quantize + argmax (both directions), p-outer scalars,
  // wave-reduce then 2-way LDS merge.
  int lane = t & 63, w = t >> 6;
#pragma unroll
  for (int p = 0; p < NP; p++) {
    float bv1 = -3.0e38f, bv2 = -3.0e38f;
    int bi1 = 0x7fffffff, bi2 = 0x7fffffff;
    double dc = (double)cK[0][p].x;
    double ny = (double)cK[360][p].x;
#pragma unroll
    for (int q = 0; q < NB; q++) {
      int n = t + 128 * q;
      if (n <= 360) {
        bool hasRev = (n >= 1) && (n <= 359);  // n=0 invalid; n=360 duplicate of fwd
        int idxF1 = n;                          // d0 index of pf_f
        int idxR1 = LN - n;                     // d0 index of pf_r
        int idxF2 = (n == 0) ? 0 : (LN - n);    // d1 index of pf_f
        int idxR2 = n;                          // d1 index of pf_r
        double sg = (n & 1) ? -ny : ny;
        double ca = cosA[p][q], sa = sinA[p][q];
        float pf_f = (float)((dc + sg + 2.0 * (ca - sa)) * (1.0 / 720.0));
        float pf_r = (float)((dc + sg + 2.0 * (ca + sa)) * (1.0 / 720.0));
        if (pf_f > bv1 || (pf_f == bv1 && idxF1 < bi1)) { bv1 = pf_f; bi1 = idxF1; }
        if (hasRev && (pf_r > bv1 || (pf_r == bv1 && idxR1 < bi1))) { bv1 = pf_r; bi1 = idxR1; }
        if (pf_f > bv2 || (pf_f == bv2 && idxF2 < bi2)) { bv2 = pf_f; bi2 = idxF2; }
        if (hasRev && (pf_r > bv2 || (pf_r == bv2 && idxR2 < bi2))) { bv2 = pf_r; bi2 = idxR2; }
      }
    }
    for (int off = 32; off >= 1; off >>= 1) {
      float ov = __shfl_down(bv1, off); int oi = __shfl_down(bi1, off);
      if (ov > bv1 || (ov == bv1 && oi < bi1)) { bv1 = ov; bi1 = oi; }
      float ov2 = __shfl_down(bv2, off); int oi2 = __shfl_down(bi2, off);
      if (ov2 > bv2 || (ov2 == bv2 && oi2 < bi2)) { bv2 = ov2; bi2 = oi2; }
    }
    if (lane == 0) {
      wv[w][p][0] = bv1; wi[w][p][0] = bi1;
      wv[w][p][1] = bv2; wi[w][p][1] = bi2;
    }
  }
  __syncthreads();
  if (t < NP * 2) {
    int p = t >> 1, d = t & 1;
    float bv = wv[0][p][d]; int bi = wi[0][p][d];
    float ov = wv[1][p][d]; int oi = wi[1][p][d];
    if (ov > bv || (ov == bv && oi < bi)) { bv = ov; bi = oi; }
    int i = spair[p].x, j = spair[p].y;
    int o = d ? ((((b << 7) + j) << 7) + i) : ((((b << 7) + i) << 7) + j);
    Mv[o] = bv; Mi[o] = bi;
  }
}

// ---------------------------------------------------------------- top-8 (fp32, literal selection)
__global__ __launch_bounds__(64) void k_topk(const float* __restrict__ Mv, const int* __restrict__ Mi,
                                             int* __restrict__ lid, int* __restrict__ shf,
                                             float* __restrict__ rv) {
  int b = blockIdx.x >> 7, r = blockIdx.x & 127;
  if (threadIdx.x != 0) return;
  float sval[128]; int ssh[128];
  int base = (((b << 7) + r) << 7);
  for (int j = 0; j < 128; j++) {
    if (j == r) { sval[j] = -3.0e38f; ssh[j] = 0; continue; }
    float mvv = Mv[base + j]; int mii = Mi[base + j];
    sval[j] = mvv;
    ssh[j] = (mii > 360) ? (mii - 720) : mii;
  }
  for (int k = 0; k < 8; k++) {
    float best = -3.0e38f; int bj = 0;
    for (int j = 0; j < 128; j++)
      if (sval[j] > best) { best = sval[j]; bj = j; }
    int o = (((b << 7) + r) << 3) + k;
    lid[o] = bj; rv[o] = best; shf[o] = ssh[bj];
    sval[bj] = -3.0e38f;
  }
}

// ---------------------------------------------------------------- gather + DCT + bands (fp32, staged)
__global__ __launch_bounds__(256) void k_out(const float* __restrict__ x,
                                             const float* __restrict__ D,
                                             const float* __restrict__ Dt,
                                             const int* __restrict__ lid,
                                             const int* __restrict__ shf,
                                             const float* __restrict__ rv,
                                             float* __restrict__ out) {
  __shared__ float Xs[9][LN];
  __shared__ float pool[9216];   // phase1/2: xe[9*720]; phase3: obuf[256*36]
  __shared__ int s_lid[8], s_shf[8];
  __shared__ float s_r[8];
  int b = blockIdx.x >> 7, c = blockIdx.x & 127;
  int t = threadIdx.x;
  if (t < 8) {
    int q = (((b << 7) + c) << 3) + t;
    s_lid[t] = lid[q]; s_shf[t] = shf[q]; s_r[t] = rv[q];
  }
  float* xe = pool;
  for (int l = t; l < LN; l += 256) xe[l] = x[(b * LN + l) * CCH + c];
  __syncthreads();
  for (int p = 1; p <= 8; p++) {
    float r = s_r[p - 1];
    if (fabsf(r) < 0.1f) {
      for (int l = t; l < LN; l += 256) xe[p * LN + l] = xe[l];
    } else {
      float sg = (r < 0.f) ? -1.f : 1.f;
      int ld = s_lid[p - 1], sh = s_shf[p - 1];
      for (int l = t; l < LN; l += 256) {
        int tt = l - sh; tt = tt < 0 ? 0 : (tt > 719 ? 719 : tt);
        xe[p * LN + l] = sg * x[(b * LN + tt) * CCH + ld];
      }
    }
  }
  __syncthreads();

  // Phase 2: X[p,k] = sum_l D[k,l]*xe[p,l]. Reads via Dt[l*720+k] so lane k
  // is consecutive -> coalesced (D[k*720+l] had 2880B lane stride).
  {
    int k0 = t, k1 = t + 256, k2 = t + 512;
    int k2c = (k2 < LN) ? k2 : k0;
    float a0[9], a1[9], a2[9];
#pragma unroll
    for (int p = 0; p < 9; p++) { a0[p] = 0.f; a1[p] = 0.f; a2[p] = 0.f; }
    const float* DtRow = Dt;
    for (int l = 0; l < LN; l++) {
      float xl[9];
#pragma unroll
      for (int p = 0; p < 9; p++) xl[p] = xe[p * LN + l];
      float d0 = DtRow[k0], d1 = DtRow[k1], d2 = DtRow[k2c];
      DtRow += LN;
#pragma unroll
      for (int p = 0; p < 9; p++) {
        a0[p] += d0 * xl[p];
        a1[p] += d1 * xl[p];
        a2[p] += d2 * xl[p];
      }
    }
#pragma unroll
    for (int p = 0; p < 9; p++) {
      Xs[p][k0] = a0[p];
      Xs[p][k1] = a1[p];
      if (k2 < LN) Xs[p][k2] = a2[p];
    }
  }
  __syncthreads();

  // Phase 3: bands, chunked over n for coalesced output
  float* obuf = pool;
  size_t outbase = (size_t)((b << 7) + c) * (LN * 36);
  for (int n0 = 0; n0 < LN; n0 += 256) {
    int nt = t & 63;
    int f = t >> 6;
    int nloc = nt * 4;
    int nchunk = (LN - n0 < 256) ? (LN - n0) : 256;
    bool act = (nloc < nchunk);
    float a[36];
#pragma unroll
    for (int q = 0; q < 36; q++) a[q] = 0.f;
    if (act) {
      const float* Dp = D + (size_t)(f * 180) * LN + (n0 + nloc);
      for (int k = 0; k < 180; k++) {
        float4 d = *(const float4*)Dp;
        Dp += LN;
        int kk = f * 180 + k;
#pragma unroll
        for (int p = 0; p < 9; p++) {
          float xv = Xs[p][kk];
          a[p * 4 + 0] += d.x * xv;
          a[p * 4 + 1] += d.y * xv;
          a[p * 4 + 2] += d.z * xv;
          a[p * 4 + 3] += d.w * xv;
        }
      }
#pragma unroll
      for (int p = 0; p < 9; p++)
#pragma unroll
        for (int nn = 0; nn < 4; nn++)
          obuf[(nloc + nn) * 36 + p * 4 + f] = a[p * 4 + nn];
    }
    __syncthreads();
    int tot = nchunk * 36;
    for (int idx = t; idx < tot; idx += 256)
      out[outbase + (size_t)n0 * 36 + idx] = obuf[idx];
    __syncthreads();
  }
}

// ---------------------------------------------------------------- launch
extern "C" void kernel_launch(void* const* d_in, const int* in_sizes, int n_in,
                              void* d_out, int out_size, void* d_ws, size_t ws_size,
                              hipStream_t stream) {
  const float* x = (const float*)d_in[0];
  float* out = (float*)d_out;

  char* ws = (char*)d_ws;
  double* ct  = (double*)ws;                      // 720
  double* st  = ct + 720;                         // 720
  double* Cm  = st + 720;                         // 361*384 compact
  double* Sm  = Cm + NBIN * TCOLS;                // 361*384 compact
  float*  nRr = (float*)(Sm + NBIN * TCOLS);      // 1024*361
  float*  nIr = nRr + 1024 * NBIN;                // 1024*361
  float*  Mv  = nIr + 1024 * NBIN;                // 8*128*128
  float*  rv  = Mv + 8 * 128 * 128;               // 8*128*8
  float*  D   = rv + 8 * 128 * 8;                 // 720*720 (16B-aligned)
  float*  Dt  = D + 720 * 720;                    // 720*720 transposed copy
  int*    Mi  = (int*)(Dt + 720 * 720);           // 8*128*128
  int*    lid = Mi + 8 * 128 * 128;               // 8*128*8
  int*    shf = lid + 8 * 128 * 8;                // 8*128*8
  int2*   ptab = (int2*)(shf + 8 * 128 * 8);      // 8128

  k_twiddle<<<3, 256, 0, stream>>>(ct, st);
  k_wmat<<<(NBIN * TCOLS + 255) / 256, 256, 0, stream>>>(ct, st, Cm, Sm);
  k_ptab<<<(NPAIRS + 255) / 256, 256, 0, stream>>>(ptab);
  k_dctmat<<<(720 * 720 + 255) / 256, 256, 0, stream>>>(D, Dt);
  k_rfft<<<8 * 128, 256, 0, stream>>>(x, ct, st, nRr, nIr);
  k_pc<<<8 * NPG, 128, 0, stream>>>(nRr, nIr, Cm, Sm, ptab, Mv, Mi);
  k_topk<<<8 * 128, 64, 0, stream>>>(Mv, Mi, lid, shf, rv);
  k_out<<<8 * 128, 256, 0, stream>>>(x, D, Dt, lid, shf, rv, out);
}

// Round 9
// 1505.964 us; speedup vs baseline: 2.5361x; 1.2655x over previous
//
#include <hip/hip_runtime.h>
#include <math.h>

#define LN   720
#define NBIN 361
#define CCH  128
#define NPAIRS 8128   // 128*127/2
#define NP     8      // pairs per k_pc block (8128 = 8*1016 exactly)
#define NPG    1016   // 8128/8
#define NB     3      // bins per thread (128*3=384 >= 361)
#define TCOLS  384    // compact table columns (only n<384 ever read)
#define KROWS  184    // table rows (k=1..180 used; padded)

// ---------------------------------------------------------------- tables
__global__ void k_twiddle(double* __restrict__ ct, double* __restrict__ st) {
  int m = blockIdx.x * 256 + threadIdx.x;
  if (m < LN) {
    double a = 6.2831853071795864769252867665590057684 * (double)m / 720.0;
    ct[m] = cos(a);
    st[m] = sin(a);
  }
}

// Compact: Cm[k*384+n] = ct[(k*n)%720] for n<384, k<184 (k-fold only needs
// rows 1..180). 2 x 184*384*8B = 1.1MB -> deep L2 residency.
__global__ void k_wmat(const double* __restrict__ ct, const double* __restrict__ st,
                       double* __restrict__ Cm, double* __restrict__ Sm) {
  int idx = blockIdx.x * 256 + threadIdx.x;
  if (idx < KROWS * TCOLS) {
    int k = idx / TCOLS, n = idx - k * TCOLS;
    int r = (int)(((long long)k * n) % LN);
    Cm[idx] = ct[r];
    Sm[idx] = st[r];
  }
}

__global__ void k_ptab(int2* __restrict__ ptab) {
  int p = blockIdx.x * 256 + threadIdx.x;
  if (p < NPAIRS) {
    int i = 0, rem = p;
    while (rem >= 127 - i) { rem -= 127 - i; i++; }
    ptab[p] = make_int2(i, i + 1 + rem);
  }
}

// D[k*720+l] and transposed Dt[l*720+k] (same values; Dt gives lane-coalesced
// phase-2 reads in k_out).
__global__ void k_dctmat(float* __restrict__ D, float* __restrict__ Dt) {
  int idx = blockIdx.x * 256 + threadIdx.x;
  if (idx < LN * LN) {
    int k = idx / LN, l = idx - k * LN;
    double ang = 3.1415926535897932384626433832795028842 * (double)((2 * l + 1) * k) / 1440.0;
    double v = cos(ang) * sqrt(2.0 / 720.0);
    if (k == 0) v *= 0.70710678118654752440084436210485;
    float f = (float)v;
    D[idx] = f;
    Dt[l * LN + k] = f;
  }
}

// ---------------------------------------------------------------- rfft (fp64 backbone) -> fp32-quantized nrf
__global__ __launch_bounds__(256) void k_rfft(const float* __restrict__ x,
                                              const double* __restrict__ ctg,
                                              const double* __restrict__ stg,
                                              float* __restrict__ nR,
                                              float* __restrict__ nI) {
  __shared__ double sd[LN];
  __shared__ double ctsP[768], stsP[768];
  int b = blockIdx.x >> 7, c = blockIdx.x & 127;
  int t = threadIdx.x;
  for (int m = t; m < LN; m += 256) {
    int a = m + (m >> 4);
    ctsP[a] = ctg[m]; stsP[a] = stg[m];
  }
  for (int l = t; l < LN; l += 256) sd[l] = (double)x[(b * LN + l) * CCH + c];
  __syncthreads();
  size_t gbase = (size_t)blockIdx.x * NBIN;
  for (int k = t; k < NBIN; k += 256) {
    double re = 0.0, im = 0.0;
    int idx = 0;
    for (int l = 0; l < LN; l++) {
      double s = sd[l];
      int a = idx + (idx >> 4);
      re += s * ctsP[a];
      im -= s * stsP[a];
      idx += k; if (idx >= LN) idx -= LN;
    }
    float reF = (float)re, imF = (float)im;        // complex64 quantization of rf
    float mag = hypotf(reF, imF);
    float d = fmaxf(mag, 1e-8f);
    nR[gbase + k] = __fdiv_rn(reF, d);
    nI[gbase + k] = __fdiv_rn(imF, d);
  }
}

// ---------------------------------------------------------------- phase correlation
// cross in strict fp32 (frozen invariant), irfft backbone fp64. pc fp32-
// quantized before max/argmax; ties -> lowest index.
//
// Round 14: k <-> 360-k FOLD (halves accumulator FMA work).
//   cos(2pi(360-k)n/720) = (-1)^n cos(2pi kn/720)
//   sin(2pi(360-k)n/720) = -(-1)^n sin(2pi kn/720)
// With sigma = (-1)^n (uniform per thread: n = t+128q, parity = t&1):
//   cosA = sum_{k=1..179} (cr[k] + sigma*cr[360-k]) * C(k,n)   [+ k=180 tail]
//   sinA = sum_{k=1..179} (ci[k] - sigma*ci[360-k]) * S(k,n)   [+ k=180 tail]
// Combines are fp64 adds of fp32-valued doubles (<=1/2 ulp fp64) — same
// perturbation class as the round-8 split (accepted precedent). Epilogue and
// tie-breaks unchanged. Tables shrink to rows 1..180 (1.1MB, L2-resident).
// Round-8's unroll-2 reverted (it traded occupancy 1:1); simple 1-deep row
// prefetch with pointer stepping.
__global__ __launch_bounds__(128, 2) void k_pc(const float* __restrict__ nR,
                                               const float* __restrict__ nI,
                                               const double* __restrict__ Cm,
                                               const double* __restrict__ Sm,
                                               const int2* __restrict__ ptab,
                                               float* __restrict__ Mv, int* __restrict__ Mi) {
  __shared__ float2 cK[NBIN][NP];        // fp32 cross; pairs contiguous at fixed k
  __shared__ int2 spair[NP];
  __shared__ float wv[2][NP][2];
  __shared__ int   wi[2][NP][2];
  int b = blockIdx.x / NPG;
  int pg = blockIdx.x - b * NPG;
  int pbase = pg * NP;                   // always 8 full pairs (8128 = 8*1016)
  int t = threadIdx.x;
  if (t < NP) spair[t] = ptab[pbase + t];
  __syncthreads();

  // stage cross for the 8 pairs (strict fp32). Flat index v -> k=v>>3, p=v&7:
  // consecutive lanes write consecutive float2 -> contiguous b64 writes.
  for (int v = t; v < NP * NBIN; v += 128) {
    int p = v & 7, k = v >> 3;
    int i = spair[p].x, j = spair[p].y;
    size_t ib = ((size_t)(b << 7) + i) * NBIN + k;
    size_t jb = ((size_t)(b << 7) + j) * NBIN + k;
    float aR = nR[ib], aI = nI[ib];
    float bR = nR[jb], bI = nI[jb];
    float xr = __fadd_rn(__fmul_rn(aR, bR), __fmul_rn(aI, bI));
    float xi = __fsub_rn(__fmul_rn(aI, bR), __fmul_rn(aR, bI));
    cK[k][p] = make_float2(xr, xi);
  }
  __syncthreads();

  // thread t owns bins n = t + 128q, q=0..2 (n>360 lanes compute discarded
  // garbage; compact tables have 384 columns so loads stay in-bounds).
  double cosA[NP][NB], sinA[NP][NB];
#pragma unroll
  for (int p = 0; p < NP; p++)
#pragma unroll
    for (int q = 0; q < NB; q++) { cosA[p][q] = 0.0; sinA[p][q] = 0.0; }

  {
    double sig  = (t & 1) ? -1.0 : 1.0;
    double msig = -sig;
    const double* pC = Cm + (size_t)1 * TCOLS + t;
    const double* pS = Sm + (size_t)1 * TCOLS + t;
    double C0 = pC[0], C1 = pC[128], C2 = pC[256];
    double S0 = pS[0], S1 = pS[128], S2 = pS[256];
    const float4* laPtr = (const float4*)&cK[1][0];     // walks up (+64B/iter)
    const float4* lbPtr = (const float4*)&cK[359][0];   // walks down (-64B/iter)

    for (int k = 1; k <= 179; k++) {
      // prefetch next table row (rows up to 180 exist; used by tail)
      pC += TCOLS; pS += TCOLS;
      double nC0 = pC[0], nC1 = pC[128], nC2 = pC[256];
      double nS0 = pS[0], nS1 = pS[128], nS2 = pS[256];
      // cross at k (a*) and 360-k (b*)
      float4 a0 = laPtr[0], a1 = laPtr[1], a2 = laPtr[2], a3 = laPtr[3];
      float4 b0 = lbPtr[0], b1 = lbPtr[1], b2 = lbPtr[2], b3 = lbPtr[3];
      laPtr += 4; lbPtr -= 4;

#define FOLD2(pp0, ra, rb)                                            \
      {                                                               \
        double crA0 = (double)ra.x, ciA0 = (double)ra.y;              \
        double crB0 = (double)rb.x, ciB0 = (double)rb.y;              \
        double crC0 = fma(sig,  crB0, crA0);                          \
        double ciC0 = fma(msig, ciB0, ciA0);                          \
        cosA[pp0][0] = fma(crC0, C0, cosA[pp0][0]);                   \
        cosA[pp0][1] = fma(crC0, C1, cosA[pp0][1]);                   \
        cosA[pp0][2] = fma(crC0, C2, cosA[pp0][2]);                   \
        sinA[pp0][0] = fma(ciC0, S0, sinA[pp0][0]);                   \
        sinA[pp0][1] = fma(ciC0, S1, sinA[pp0][1]);                   \
        sinA[pp0][2] = fma(ciC0, S2, sinA[pp0][2]);                   \
        double crA1 = (double)ra.z, ciA1 = (double)ra.w;              \
        double crB1 = (double)rb.z, ciB1 = (double)rb.w;              \
        double crC1 = fma(sig,  crB1, crA1);                          \
        double ciC1 = fma(msig, ciB1, ciA1);                          \
        cosA[pp0+1][0] = fma(crC1, C0, cosA[pp0+1][0]);               \
        cosA[pp0+1][1] = fma(crC1, C1, cosA[pp0+1][1]);               \
        cosA[pp0+1][2] = fma(crC1, C2, cosA[pp0+1][2]);               \
        sinA[pp0+1][0] = fma(ciC1, S0, sinA[pp0+1][0]);               \
        sinA[pp0+1][1] = fma(ciC1, S1, sinA[pp0+1][1]);               \
        sinA[pp0+1][2] = fma(ciC1, S2, sinA[pp0+1][2]);               \
      }
      FOLD2(0, a0, b0)
      FOLD2(2, a1, b1)
      FOLD2(4, a2, b2)
      FOLD2(6, a3, b3)
#undef FOLD2
      C0 = nC0; C1 = nC1; C2 = nC2;
      S0 = nS0; S1 = nS1; S2 = nS2;
    }

    // tail k = 180 (self-paired; C0..S2 hold row 180 from the last prefetch)
    {
      float4 a0 = *(const float4*)&cK[180][0];
      float4 a1 = *(const float4*)&cK[180][2];
      float4 a2 = *(const float4*)&cK[180][4];
      float4 a3 = *(const float4*)&cK[180][6];
#define TAIL2(pp0, ra)                                                \
      {                                                               \
        double crA0 = (double)ra.x, ciA0 = (double)ra.y;              \
        cosA[pp0][0] = fma(crA0, C0, cosA[pp0][0]);                   \
        cosA[pp0][1] = fma(crA0, C1, cosA[pp0][1]);                   \
        cosA[pp0][2] = fma(crA0, C2, cosA[pp0][2]);                   \
        sinA[pp0][0] = fma(ciA0, S0, sinA[pp0][0]);                   \
        sinA[pp0][1] = fma(ciA0, S1, sinA[pp0][1]);                   \
        sinA[pp0][2] = fma(ciA0, S2, sinA[pp0][2]);                   \
        double crA1 = (double)ra.z, ciA1 = (double)ra.w;              \
        cosA[pp0+1][0] = fma(crA1, C0, cosA[pp0+1][0]);               \
        cosA[pp0+1][1] = fma(crA1, C1, cosA[pp0+1][1]);               \
        cosA[pp0+1][2] = fma(crA1, C2, cosA[pp0+1][2]);               \
        sinA[pp0+1][0] = fma(ciA1, S0, sinA[pp0+1][0]);               \
        sinA[pp0+1][1] = fma(ciA1, S1, sinA[pp0+1][1]);               \
        sinA[pp0+1][2] = fma(ciA1, S2, sinA[pp0+1][2]);               \
      }
      TAIL2(0, a0)
      TAIL2(2, a1)
      TAIL2(4, a2)
      TAIL2(6, a3)
#undef TAIL2
    }
  }

  // epilogue: fp32 quantize + argmax (both directions), p-outer scalars,
  // wave-reduce then 2-way LDS merge.
  int lane = t & 63, w = t >> 6;
#pragma unroll
  for (int p = 0; p < NP; p++) {
    float bv1 = -3.0e38f, bv2 = -3.0e38f;
    int bi1 = 0x7fffffff, bi2 = 0x7fffffff;
    double dc = (double)cK[0][p].x;
    double ny = (double)cK[360][p].x;
#pragma unroll
    for (int q = 0; q < NB; q++) {
      int n = t + 128 * q;
      if (n <= 360) {
        bool hasRev = (n >= 1) && (n <= 359);  // n=0 invalid; n=360 duplicate of fwd
        int idxF1 = n;                          // d0 index of pf_f
        int idxR1 = LN - n;                     // d0 index of pf_r
        int idxF2 = (n == 0) ? 0 : (LN - n);    // d1 index of pf_f
        int idxR2 = n;                          // d1 index of pf_r
        double sg = (n & 1) ? -ny : ny;
        double ca = cosA[p][q], sa = sinA[p][q];
        float pf_f = (float)((dc + sg + 2.0 * (ca - sa)) * (1.0 / 720.0));
        float pf_r = (float)((dc + sg + 2.0 * (ca + sa)) * (1.0 / 720.0));
        if (pf_f > bv1 || (pf_f == bv1 && idxF1 < bi1)) { bv1 = pf_f; bi1 = idxF1; }
        if (hasRev && (pf_r > bv1 || (pf_r == bv1 && idxR1 < bi1))) { bv1 = pf_r; bi1 = idxR1; }
        if (pf_f > bv2 || (pf_f == bv2 && idxF2 < bi2)) { bv2 = pf_f; bi2 = idxF2; }
        if (hasRev && (pf_r > bv2 || (pf_r == bv2 && idxR2 < bi2))) { bv2 = pf_r; bi2 = idxR2; }
      }
    }
    for (int off = 32; off >= 1; off >>= 1) {
      float ov = __shfl_down(bv1, off); int oi = __shfl_down(bi1, off);
      if (ov > bv1 || (ov == bv1 && oi < bi1)) { bv1 = ov; bi1 = oi; }
      float ov2 = __shfl_down(bv2, off); int oi2 = __shfl_down(bi2, off);
      if (ov2 > bv2 || (ov2 == bv2 && oi2 < bi2)) { bv2 = ov2; bi2 = oi2; }
    }
    if (lane == 0) {
      wv[w][p][0] = bv1; wi[w][p][0] = bi1;
      wv[w][p][1] = bv2; wi[w][p][1] = bi2;
    }
  }
  __syncthreads();
  if (t < NP * 2) {
    int p = t >> 1, d = t & 1;
    float bv = wv[0][p][d]; int bi = wi[0][p][d];
    float ov = wv[1][p][d]; int oi = wi[1][p][d];
    if (ov > bv || (ov == bv && oi < bi)) { bv = ov; bi = oi; }
    int i = spair[p].x, j = spair[p].y;
    int o = d ? ((((b << 7) + j) << 7) + i) : ((((b << 7) + i) << 7) + j);
    Mv[o] = bv; Mi[o] = bi;
  }
}

// ---------------------------------------------------------------- top-8 (fp32, literal selection)
__global__ __launch_bounds__(64) void k_topk(const float* __restrict__ Mv, const int* __restrict__ Mi,
                                             int* __restrict__ lid, int* __restrict__ shf,
                                             float* __restrict__ rv) {
  int b = blockIdx.x >> 7, r = blockIdx.x & 127;
  if (threadIdx.x != 0) return;
  float sval[128]; int ssh[128];
  int base = (((b << 7) + r) << 7);
  for (int j = 0; j < 128; j++) {
    if (j == r) { sval[j] = -3.0e38f; ssh[j] = 0; continue; }
    float mvv = Mv[base + j]; int mii = Mi[base + j];
    sval[j] = mvv;
    ssh[j] = (mii > 360) ? (mii - 720) : mii;
  }
  for (int k = 0; k < 8; k++) {
    float best = -3.0e38f; int bj = 0;
    for (int j = 0; j < 128; j++)
      if (sval[j] > best) { best = sval[j]; bj = j; }
    int o = (((b << 7) + r) << 3) + k;
    lid[o] = bj; rv[o] = best; shf[o] = ssh[bj];
    sval[bj] = -3.0e38f;
  }
}

// ---------------------------------------------------------------- gather + DCT + bands (fp32, staged)
__global__ __launch_bounds__(256) void k_out(const float* __restrict__ x,
                                             const float* __restrict__ D,
                                             const float* __restrict__ Dt,
                                             const int* __restrict__ lid,
                                             const int* __restrict__ shf,
                                             const float* __restrict__ rv,
                                             float* __restrict__ out) {
  __shared__ float Xs[9][LN];
  __shared__ float pool[9216];   // phase1/2: xe[9*720]; phase3: obuf[256*36]
  __shared__ int s_lid[8], s_shf[8];
  __shared__ float s_r[8];
  int b = blockIdx.x >> 7, c = blockIdx.x & 127;
  int t = threadIdx.x;
  if (t < 8) {
    int q = (((b << 7) + c) << 3) + t;
    s_lid[t] = lid[q]; s_shf[t] = shf[q]; s_r[t] = rv[q];
  }
  float* xe = pool;
  for (int l = t; l < LN; l += 256) xe[l] = x[(b * LN + l) * CCH + c];
  __syncthreads();
  for (int p = 1; p <= 8; p++) {
    float r = s_r[p - 1];
    if (fabsf(r) < 0.1f) {
      for (int l = t; l < LN; l += 256) xe[p * LN + l] = xe[l];
    } else {
      float sg = (r < 0.f) ? -1.f : 1.f;
      int ld = s_lid[p - 1], sh = s_shf[p - 1];
      for (int l = t; l < LN; l += 256) {
        int tt = l - sh; tt = tt < 0 ? 0 : (tt > 719 ? 719 : tt);
        xe[p * LN + l] = sg * x[(b * LN + tt) * CCH + ld];
      }
    }
  }
  __syncthreads();

  // Phase 2: X[p,k] = sum_l D[k,l]*xe[p,l]. Reads via Dt[l*720+k] so lane k
  // is consecutive -> coalesced (D[k*720+l] had 2880B lane stride).
  {
    int k0 = t, k1 = t + 256, k2 = t + 512;
    int k2c = (k2 < LN) ? k2 : k0;
    float a0[9], a1[9], a2[9];
#pragma unroll
    for (int p = 0; p < 9; p++) { a0[p] = 0.f; a1[p] = 0.f; a2[p] = 0.f; }
    const float* DtRow = Dt;
    for (int l = 0; l < LN; l++) {
      float xl[9];
#pragma unroll
      for (int p = 0; p < 9; p++) xl[p] = xe[p * LN + l];
      float d0 = DtRow[k0], d1 = DtRow[k1], d2 = DtRow[k2c];
      DtRow += LN;
#pragma unroll
      for (int p = 0; p < 9; p++) {
        a0[p] += d0 * xl[p];
        a1[p] += d1 * xl[p];
        a2[p] += d2 * xl[p];
      }
    }
#pragma unroll
    for (int p = 0; p < 9; p++) {
      Xs[p][k0] = a0[p];
      Xs[p][k1] = a1[p];
      if (k2 < LN) Xs[p][k2] = a2[p];
    }
  }
  __syncthreads();

  // Phase 3: bands, chunked over n for coalesced output
  float* obuf = pool;
  size_t outbase = (size_t)((b << 7) + c) * (LN * 36);
  for (int n0 = 0; n0 < LN; n0 += 256) {
    int nt = t & 63;
    int f = t >> 6;
    int nloc = nt * 4;
    int nchunk = (LN - n0 < 256) ? (LN - n0) : 256;
    bool act = (nloc < nchunk);
    float a[36];
#pragma unroll
    for (int q = 0; q < 36; q++) a[q] = 0.f;
    if (act) {
      const float* Dp = D + (size_t)(f * 180) * LN + (n0 + nloc);
      for (int k = 0; k < 180; k++) {
        float4 d = *(const float4*)Dp;
        Dp += LN;
        int kk = f * 180 + k;
#pragma unroll
        for (int p = 0; p < 9; p++) {
          float xv = Xs[p][kk];
          a[p * 4 + 0] += d.x * xv;
          a[p * 4 + 1] += d.y * xv;
          a[p * 4 + 2] += d.z * xv;
          a[p * 4 + 3] += d.w * xv;
        }
      }
#pragma unroll
      for (int p = 0; p < 9; p++)
#pragma unroll
        for (int nn = 0; nn < 4; nn++)
          obuf[(nloc + nn) * 36 + p * 4 + f] = a[p * 4 + nn];
    }
    __syncthreads();
    int tot = nchunk * 36;
    for (int idx = t; idx < tot; idx += 256)
      out[outbase + (size_t)n0 * 36 + idx] = obuf[idx];
    __syncthreads();
  }
}

// ---------------------------------------------------------------- launch
extern "C" void kernel_launch(void* const* d_in, const int* in_sizes, int n_in,
                              void* d_out, int out_size, void* d_ws, size_t ws_size,
                              hipStream_t stream) {
  const float* x = (const float*)d_in[0];
  float* out = (float*)d_out;

  char* ws = (char*)d_ws;
  double* ct  = (double*)ws;                      // 720
  double* st  = ct + 720;                         // 720
  double* Cm  = st + 720;                         // 184*384 compact (rows 1..180 used)
  double* Sm  = Cm + KROWS * TCOLS;               // 184*384 compact
  float*  nRr = (float*)(Sm + KROWS * TCOLS);     // 1024*361
  float*  nIr = nRr + 1024 * NBIN;                // 1024*361
  float*  Mv  = nIr + 1024 * NBIN;                // 8*128*128
  float*  rv  = Mv + 8 * 128 * 128;               // 8*128*8
  float*  D   = rv + 8 * 128 * 8;                 // 720*720 (16B-aligned)
  float*  Dt  = D + 720 * 720;                    // 720*720 transposed copy
  int*    Mi  = (int*)(Dt + 720 * 720);           // 8*128*128
  int*    lid = Mi + 8 * 128 * 128;               // 8*128*8
  int*    shf = lid + 8 * 128 * 8;                // 8*128*8
  int2*   ptab = (int2*)(shf + 8 * 128 * 8);      // 8128

  k_twiddle<<<3, 256, 0, stream>>>(ct, st);
  k_wmat<<<(KROWS * TCOLS + 255) / 256, 256, 0, stream>>>(ct, st, Cm, Sm);
  k_ptab<<<(NPAIRS + 255) / 256, 256, 0, stream>>>(ptab);
  k_dctmat<<<(720 * 720 + 255) / 256, 256, 0, stream>>>(D, Dt);
  k_rfft<<<8 * 128, 256, 0, stream>>>(x, ct, st, nRr, nIr);
  k_pc<<<8 * NPG, 128, 0, stream>>>(nRr, nIr, Cm, Sm, ptab, Mv, Mi);
  k_topk<<<8 * 128, 64, 0, stream>>>(Mv, Mi, lid, shf, rv);
  k_out<<<8 * 128, 256, 0, stream>>>(x, D, Dt, lid, shf, rv, out);
}

// Round 10
// 1503.741 us; speedup vs baseline: 2.5399x; 1.0015x over previous
//
#include <hip/hip_runtime.h>
#include <math.h>

#define LN   720
#define NBIN 361
#define CCH  128
#define NPAIRS 8128   // 128*127/2
#define NP     8      // pairs per k_pc block (8128 = 8*1016 exactly)
#define NPG    1016   // 8128/8
#define NB     3      // bins per thread (128*3=384 >= 361)
#define TCOLS  384    // compact table columns (only n<384 ever read)
#define KROWS  184    // table rows (k=1..181 read; padded)
#define CFROWS 184    // coeff rows (kk=0..179 used; padded for last prefetch)

// ---------------------------------------------------------------- tables
__global__ void k_twiddle(double* __restrict__ ct, double* __restrict__ st) {
  int m = blockIdx.x * 256 + threadIdx.x;
  if (m < LN) {
    double a = 6.2831853071795864769252867665590057684 * (double)m / 720.0;
    ct[m] = cos(a);
    st[m] = sin(a);
  }
}

// Compact: Cm[k*384+n] = ct[(k*n)%720] for n<384, k<184 (k-fold needs rows
// 1..181 incl. prefetch overrun). 2 x 184*384*8B = 1.1MB -> deep L2 residency.
__global__ void k_wmat(const double* __restrict__ ct, const double* __restrict__ st,
                       double* __restrict__ Cm, double* __restrict__ Sm) {
  int idx = blockIdx.x * 256 + threadIdx.x;
  if (idx < KROWS * TCOLS) {
    int k = idx / TCOLS, n = idx - k * TCOLS;
    int r = (int)(((long long)k * n) % LN);
    Cm[idx] = ct[r];
    Sm[idx] = st[r];
  }
}

__global__ void k_ptab(int2* __restrict__ ptab) {
  int p = blockIdx.x * 256 + threadIdx.x;
  if (p < NPAIRS) {
    int i = 0, rem = p;
    while (rem >= 127 - i) { rem -= 127 - i; i++; }
    ptab[p] = make_int2(i, i + 1 + rem);
  }
}

// D[k*720+l] and transposed Dt[l*720+k] (same values; Dt gives lane-coalesced
// phase-2 reads in k_out).
__global__ void k_dctmat(float* __restrict__ D, float* __restrict__ Dt) {
  int idx = blockIdx.x * 256 + threadIdx.x;
  if (idx < LN * LN) {
    int k = idx / LN, l = idx - k * LN;
    double ang = 3.1415926535897932384626433832795028842 * (double)((2 * l + 1) * k) / 1440.0;
    double v = cos(ang) * sqrt(2.0 / 720.0);
    if (k == 0) v *= 0.70710678118654752440084436210485;
    float f = (float)v;
    D[idx] = f;
    Dt[l * LN + k] = f;
  }
}

// ---------------------------------------------------------------- rfft (fp64 backbone) -> fp32-quantized nrf
__global__ __launch_bounds__(256) void k_rfft(const float* __restrict__ x,
                                              const double* __restrict__ ctg,
                                              const double* __restrict__ stg,
                                              float* __restrict__ nR,
                                              float* __restrict__ nI) {
  __shared__ double sd[LN];
  __shared__ double ctsP[768], stsP[768];
  int b = blockIdx.x >> 7, c = blockIdx.x & 127;
  int t = threadIdx.x;
  for (int m = t; m < LN; m += 256) {
    int a = m + (m >> 4);
    ctsP[a] = ctg[m]; stsP[a] = stg[m];
  }
  for (int l = t; l < LN; l += 256) sd[l] = (double)x[(b * LN + l) * CCH + c];
  __syncthreads();
  size_t gbase = (size_t)blockIdx.x * NBIN;
  for (int k = t; k < NBIN; k += 256) {
    double re = 0.0, im = 0.0;
    int idx = 0;
    for (int l = 0; l < LN; l++) {
      double s = sd[l];
      int a = idx + (idx >> 4);
      re += s * ctsP[a];
      im -= s * stsP[a];
      idx += k; if (idx >= LN) idx -= LN;
    }
    float reF = (float)re, imF = (float)im;        // complex64 quantization of rf
    float mag = hypotf(reF, imF);
    float d = fmaxf(mag, 1e-8f);
    nR[gbase + k] = __fdiv_rn(reF, d);
    nI[gbase + k] = __fdiv_rn(imF, d);
  }
}

// ---------------------------------------------------------------- phase correlation
// cross in strict fp32 (frozen invariant), irfft backbone fp64. pc fp32-
// quantized before max/argmax; ties -> lowest index.
//
// Round 15: hoist the fold-combines into staging. Round 14 recomputed the
// combined coefficients crC = crA +/- crB, ciC = ciA -/+ ciB in the k-loop:
// 16 fp64 fma + 32 cvt per iter, redundantly per thread. They are loop-
// invariant per (k, pair, parity). Now staging computes them ONCE in fp64 and
// stores two parity arrays E[kk][p], O[kk][p] (double2: crC, ciC); row 179
// (k=180) holds the raw self-paired tail so the loop runs k=1..180 uniformly.
// fma(+/-1.0, b, a) == a +/- b in fp64 -> staging is bit-identical to the
// in-loop combine; acc chain order unchanged -> bit-identical output.
// k-loop per iter: 8 broadcast ds_read_b128 + 12 table loads + 48 acc-fma.
// Unroll-2 A/B prefetch is now free: LDS (47KB -> 3 blocks/CU) caps occupancy,
// not VGPRs (round-8's unroll cost occupancy only because VGPRs were binding).
__global__ __launch_bounds__(128, 2) void k_pc(const float* __restrict__ nR,
                                               const float* __restrict__ nI,
                                               const double* __restrict__ Cm,
                                               const double* __restrict__ Sm,
                                               const int2* __restrict__ ptab,
                                               float* __restrict__ Mv, int* __restrict__ Mi) {
  __shared__ double2 eArr[CFROWS][NP];   // sigma=+1 coeffs: (crA+crB, ciA-ciB)
  __shared__ double2 oArr[CFROWS][NP];   // sigma=-1 coeffs: (crA-crB, ciA+ciB)
  __shared__ double sdc[NP], sny[NP];    // k=0 (dc) and k=360 (nyquist) Re terms
  __shared__ int2 spair[NP];
  __shared__ float wv[2][NP][2];
  __shared__ int   wi[2][NP][2];
  int b = blockIdx.x / NPG;
  int pg = blockIdx.x - b * NPG;
  int pbase = pg * NP;                   // always 8 full pairs (8128 = 8*1016)
  int t = threadIdx.x;
  if (t < NP) spair[t] = ptab[pbase + t];
  __syncthreads();

  // stage combined coefficients (strict fp32 cross, fp64 combine)
  for (int v = t; v < 180 * NP; v += 128) {
    int p = v & 7, kk = v >> 3;
    int k = kk + 1;                      // k = 1..180
    int i = spair[p].x, j = spair[p].y;
    size_t ib = ((size_t)(b << 7) + i) * NBIN;
    size_t jb = ((size_t)(b << 7) + j) * NBIN;
    float aR = nR[ib + k], aI = nI[ib + k];
    float bR = nR[jb + k], bI = nI[jb + k];
    float xr = __fadd_rn(__fmul_rn(aR, bR), __fmul_rn(aI, bI));
    float xi = __fsub_rn(__fmul_rn(aI, bR), __fmul_rn(aR, bI));
    double crA = (double)xr, ciA = (double)xi;
    if (k == 180) {
      // self-paired tail: raw coefficients for both parities
      eArr[kk][p] = make_double2(crA, ciA);
      oArr[kk][p] = make_double2(crA, ciA);
    } else {
      int kp = 360 - k;                  // fold partner
      float aR2 = nR[ib + kp], aI2 = nI[ib + kp];
      float bR2 = nR[jb + kp], bI2 = nI[jb + kp];
      float xr2 = __fadd_rn(__fmul_rn(aR2, bR2), __fmul_rn(aI2, bI2));
      float xi2 = __fsub_rn(__fmul_rn(aI2, bR2), __fmul_rn(aR2, bI2));
      double crB = (double)xr2, ciB = (double)xi2;
      eArr[kk][p] = make_double2(crA + crB, ciA - ciB);
      oArr[kk][p] = make_double2(crA - crB, ciA + ciB);
    }
  }
  if (t < NP) {
    int i = spair[t].x, j = spair[t].y;
    size_t ib = ((size_t)(b << 7) + i) * NBIN;
    size_t jb = ((size_t)(b << 7) + j) * NBIN;
    // dc (k=0)
    float aR = nR[ib], aI = nI[ib], bR = nR[jb], bI = nI[jb];
    sdc[t] = (double)__fadd_rn(__fmul_rn(aR, bR), __fmul_rn(aI, bI));
    // nyquist (k=360)
    float aR2 = nR[ib + 360], aI2 = nI[ib + 360];
    float bR2 = nR[jb + 360], bI2 = nI[jb + 360];
    sny[t] = (double)__fadd_rn(__fmul_rn(aR2, bR2), __fmul_rn(aI2, bI2));
  }
  __syncthreads();

  // thread t owns bins n = t + 128q, q=0..2 (n>360 lanes compute discarded
  // garbage; compact tables have 384 columns so loads stay in-bounds).
  double cosA[NP][NB], sinA[NP][NB];
#pragma unroll
  for (int p = 0; p < NP; p++)
#pragma unroll
    for (int q = 0; q < NB; q++) { cosA[p][q] = 0.0; sinA[p][q] = 0.0; }

  {
    const double2* __restrict__ myCf = (t & 1) ? &oArr[0][0] : &eArr[0][0];
    const double* pC = Cm + (size_t)TCOLS + t;   // table row k=1
    const double* pS = Sm + (size_t)TCOLS + t;
    double CA0 = pC[0], CA1 = pC[128], CA2 = pC[256];
    double SA0 = pS[0], SA1 = pS[128], SA2 = pS[256];
    double2 fA0 = myCf[0], fA1 = myCf[1], fA2 = myCf[2], fA3 = myCf[3];
    double2 fA4 = myCf[4], fA5 = myCf[5], fA6 = myCf[6], fA7 = myCf[7];

#define PAIR1(pp, f, Cx0, Cx1, Cx2, Sx0, Sx1, Sx2)                     \
    cosA[pp][0] = fma(f.x, Cx0, cosA[pp][0]);                          \
    cosA[pp][1] = fma(f.x, Cx1, cosA[pp][1]);                          \
    cosA[pp][2] = fma(f.x, Cx2, cosA[pp][2]);                          \
    sinA[pp][0] = fma(f.y, Sx0, sinA[pp][0]);                          \
    sinA[pp][1] = fma(f.y, Sx1, sinA[pp][1]);                          \
    sinA[pp][2] = fma(f.y, Sx2, sinA[pp][2]);

#define COMPUTE(Cx0, Cx1, Cx2, Sx0, Sx1, Sx2, f0, f1, f2, f3, f4, f5, f6, f7) \
    {                                                                  \
      PAIR1(0, f0, Cx0, Cx1, Cx2, Sx0, Sx1, Sx2)                       \
      PAIR1(1, f1, Cx0, Cx1, Cx2, Sx0, Sx1, Sx2)                       \
      PAIR1(2, f2, Cx0, Cx1, Cx2, Sx0, Sx1, Sx2)                       \
      PAIR1(3, f3, Cx0, Cx1, Cx2, Sx0, Sx1, Sx2)                       \
      PAIR1(4, f4, Cx0, Cx1, Cx2, Sx0, Sx1, Sx2)                       \
      PAIR1(5, f5, Cx0, Cx1, Cx2, Sx0, Sx1, Sx2)                       \
      PAIR1(6, f6, Cx0, Cx1, Cx2, Sx0, Sx1, Sx2)                       \
      PAIR1(7, f7, Cx0, Cx1, Cx2, Sx0, Sx1, Sx2)                       \
    }

    double CB0, CB1, CB2, SB0, SB1, SB2;
    double2 fB0, fB1, fB2, fB3, fB4, fB5, fB6, fB7;
    for (int k = 1; k <= 179; k += 2) {
      // prefetch B: table row k+1, coeff row kk=k
      pC += TCOLS; pS += TCOLS;
      CB0 = pC[0]; CB1 = pC[128]; CB2 = pC[256];
      SB0 = pS[0]; SB1 = pS[128]; SB2 = pS[256];
      {
        const double2* cb = myCf + (size_t)k * NP;
        fB0 = cb[0]; fB1 = cb[1]; fB2 = cb[2]; fB3 = cb[3];
        fB4 = cb[4]; fB5 = cb[5]; fB6 = cb[6]; fB7 = cb[7];
      }
      COMPUTE(CA0, CA1, CA2, SA0, SA1, SA2, fA0, fA1, fA2, fA3, fA4, fA5, fA6, fA7)
      // prefetch A: table row k+2 (row 181 exists), coeff row kk=k+1 (padded)
      pC += TCOLS; pS += TCOLS;
      CA0 = pC[0]; CA1 = pC[128]; CA2 = pC[256];
      SA0 = pS[0]; SA1 = pS[128]; SA2 = pS[256];
      {
        const double2* ca = myCf + (size_t)(k + 1) * NP;
        fA0 = ca[0]; fA1 = ca[1]; fA2 = ca[2]; fA3 = ca[3];
        fA4 = ca[4]; fA5 = ca[5]; fA6 = ca[6]; fA7 = ca[7];
      }
      COMPUTE(CB0, CB1, CB2, SB0, SB1, SB2, fB0, fB1, fB2, fB3, fB4, fB5, fB6, fB7)
    }
#undef COMPUTE
#undef PAIR1
  }

  // epilogue: fp32 quantize + argmax (both directions), p-outer scalars,
  // wave-reduce then 2-way LDS merge.
  int lane = t & 63, w = t >> 6;
#pragma unroll
  for (int p = 0; p < NP; p++) {
    float bv1 = -3.0e38f, bv2 = -3.0e38f;
    int bi1 = 0x7fffffff, bi2 = 0x7fffffff;
    double dc = sdc[p], ny = sny[p];
#pragma unroll
    for (int q = 0; q < NB; q++) {
      int n = t + 128 * q;
      if (n <= 360) {
        bool hasRev = (n >= 1) && (n <= 359);  // n=0 invalid; n=360 duplicate of fwd
        int idxF1 = n;                          // d0 index of pf_f
        int idxR1 = LN - n;                     // d0 index of pf_r
        int idxF2 = (n == 0) ? 0 : (LN - n);    // d1 index of pf_f
        int idxR2 = n;                          // d1 index of pf_r
        double sg = (n & 1) ? -ny : ny;
        double ca = cosA[p][q], sa = sinA[p][q];
        float pf_f = (float)((dc + sg + 2.0 * (ca - sa)) * (1.0 / 720.0));
        float pf_r = (float)((dc + sg + 2.0 * (ca + sa)) * (1.0 / 720.0));
        if (pf_f > bv1 || (pf_f == bv1 && idxF1 < bi1)) { bv1 = pf_f; bi1 = idxF1; }
        if (hasRev && (pf_r > bv1 || (pf_r == bv1 && idxR1 < bi1))) { bv1 = pf_r; bi1 = idxR1; }
        if (pf_f > bv2 || (pf_f == bv2 && idxF2 < bi2)) { bv2 = pf_f; bi2 = idxF2; }
        if (hasRev && (pf_r > bv2 || (pf_r == bv2 && idxR2 < bi2))) { bv2 = pf_r; bi2 = idxR2; }
      }
    }
    for (int off = 32; off >= 1; off >>= 1) {
      float ov = __shfl_down(bv1, off); int oi = __shfl_down(bi1, off);
      if (ov > bv1 || (ov == bv1 && oi < bi1)) { bv1 = ov; bi1 = oi; }
      float ov2 = __shfl_down(bv2, off); int oi2 = __shfl_down(bi2, off);
      if (ov2 > bv2 || (ov2 == bv2 && oi2 < bi2)) { bv2 = ov2; bi2 = oi2; }
    }
    if (lane == 0) {
      wv[w][p][0] = bv1; wi[w][p][0] = bi1;
      wv[w][p][1] = bv2; wi[w][p][1] = bi2;
    }
  }
  __syncthreads();
  if (t < NP * 2) {
    int p = t >> 1, d = t & 1;
    float bv = wv[0][p][d]; int bi = wi[0][p][d];
    float ov = wv[1][p][d]; int oi = wi[1][p][d];
    if (ov > bv || (ov == bv && oi < bi)) { bv = ov; bi = oi; }
    int i = spair[p].x, j = spair[p].y;
    int o = d ? ((((b << 7) + j) << 7) + i) : ((((b << 7) + i) << 7) + j);
    Mv[o] = bv; Mi[o] = bi;
  }
}

// ---------------------------------------------------------------- top-8 (fp32, literal selection)
__global__ __launch_bounds__(64) void k_topk(const float* __restrict__ Mv, const int* __restrict__ Mi,
                                             int* __restrict__ lid, int* __restrict__ shf,
                                             float* __restrict__ rv) {
  int b = blockIdx.x >> 7, r = blockIdx.x & 127;
  if (threadIdx.x != 0) return;
  float sval[128]; int ssh[128];
  int base = (((b << 7) + r) << 7);
  for (int j = 0; j < 128; j++) {
    if (j == r) { sval[j] = -3.0e38f; ssh[j] = 0; continue; }
    float mvv = Mv[base + j]; int mii = Mi[base + j];
    sval[j] = mvv;
    ssh[j] = (mii > 360) ? (mii - 720) : mii;
  }
  for (int k = 0; k < 8; k++) {
    float best = -3.0e38f; int bj = 0;
    for (int j = 0; j < 128; j++)
      if (sval[j] > best) { best = sval[j]; bj = j; }
    int o = (((b << 7) + r) << 3) + k;
    lid[o] = bj; rv[o] = best; shf[o] = ssh[bj];
    sval[bj] = -3.0e38f;
  }
}

// ---------------------------------------------------------------- gather + DCT + bands (fp32, staged)
__global__ __launch_bounds__(256) void k_out(const float* __restrict__ x,
                                             const float* __restrict__ D,
                                             const float* __restrict__ Dt,
                                             const int* __restrict__ lid,
                                             const int* __restrict__ shf,
                                             const float* __restrict__ rv,
                                             float* __restrict__ out) {
  __shared__ float Xs[9][LN];
  __shared__ float pool[9216];   // phase1/2: xe[9*720]; phase3: obuf[256*36]
  __shared__ int s_lid[8], s_shf[8];
  __shared__ float s_r[8];
  int b = blockIdx.x >> 7, c = blockIdx.x & 127;
  int t = threadIdx.x;
  if (t < 8) {
    int q = (((b << 7) + c) << 3) + t;
    s_lid[t] = lid[q]; s_shf[t] = shf[q]; s_r[t] = rv[q];
  }
  float* xe = pool;
  for (int l = t; l < LN; l += 256) xe[l] = x[(b * LN + l) * CCH + c];
  __syncthreads();
  for (int p = 1; p <= 8; p++) {
    float r = s_r[p - 1];
    if (fabsf(r) < 0.1f) {
      for (int l = t; l < LN; l += 256) xe[p * LN + l] = xe[l];
    } else {
      float sg = (r < 0.f) ? -1.f : 1.f;
      int ld = s_lid[p - 1], sh = s_shf[p - 1];
      for (int l = t; l < LN; l += 256) {
        int tt = l - sh; tt = tt < 0 ? 0 : (tt > 719 ? 719 : tt);
        xe[p * LN + l] = sg * x[(b * LN + tt) * CCH + ld];
      }
    }
  }
  __syncthreads();

  // Phase 2: X[p,k] = sum_l D[k,l]*xe[p,l]. Reads via Dt[l*720+k] so lane k
  // is consecutive -> coalesced (D[k*720+l] had 2880B lane stride).
  {
    int k0 = t, k1 = t + 256, k2 = t + 512;
    int k2c = (k2 < LN) ? k2 : k0;
    float a0[9], a1[9], a2[9];
#pragma unroll
    for (int p = 0; p < 9; p++) { a0[p] = 0.f; a1[p] = 0.f; a2[p] = 0.f; }
    const float* DtRow = Dt;
    for (int l = 0; l < LN; l++) {
      float xl[9];
#pragma unroll
      for (int p = 0; p < 9; p++) xl[p] = xe[p * LN + l];
      float d0 = DtRow[k0], d1 = DtRow[k1], d2 = DtRow[k2c];
      DtRow += LN;
#pragma unroll
      for (int p = 0; p < 9; p++) {
        a0[p] += d0 * xl[p];
        a1[p] += d1 * xl[p];
        a2[p] += d2 * xl[p];
      }
    }
#pragma unroll
    for (int p = 0; p < 9; p++) {
      Xs[p][k0] = a0[p];
      Xs[p][k1] = a1[p];
      if (k2 < LN) Xs[p][k2] = a2[p];
    }
  }
  __syncthreads();

  // Phase 3: bands, chunked over n for coalesced output
  float* obuf = pool;
  size_t outbase = (size_t)((b << 7) + c) * (LN * 36);
  for (int n0 = 0; n0 < LN; n0 += 256) {
    int nt = t & 63;
    int f = t >> 6;
    int nloc = nt * 4;
    int nchunk = (LN - n0 < 256) ? (LN - n0) : 256;
    bool act = (nloc < nchunk);
    float a[36];
#pragma unroll
    for (int q = 0; q < 36; q++) a[q] = 0.f;
    if (act) {
      const float* Dp = D + (size_t)(f * 180) * LN + (n0 + nloc);
      for (int k = 0; k < 180; k++) {
        float4 d = *(const float4*)Dp;
        Dp += LN;
        int kk = f * 180 + k;
#pragma unroll
        for (int p = 0; p < 9; p++) {
          float xv = Xs[p][kk];
          a[p * 4 + 0] += d.x * xv;
          a[p * 4 + 1] += d.y * xv;
          a[p * 4 + 2] += d.z * xv;
          a[p * 4 + 3] += d.w * xv;
        }
      }
#pragma unroll
      for (int p = 0; p < 9; p++)
#pragma unroll
        for (int nn = 0; nn < 4; nn++)
          obuf[(nloc + nn) * 36 + p * 4 + f] = a[p * 4 + nn];
    }
    __syncthreads();
    int tot = nchunk * 36;
    for (int idx = t; idx < tot; idx += 256)
      out[outbase + (size_t)n0 * 36 + idx] = obuf[idx];
    __syncthreads();
  }
}

// ---------------------------------------------------------------- launch
extern "C" void kernel_launch(void* const* d_in, const int* in_sizes, int n_in,
                              void* d_out, int out_size, void* d_ws, size_t ws_size,
                              hipStream_t stream) {
  const float* x = (const float*)d_in[0];
  float* out = (float*)d_out;

  char* ws = (char*)d_ws;
  double* ct  = (double*)ws;                      // 720
  double* st  = ct + 720;                         // 720
  double* Cm  = st + 720;                         // 184*384 compact (rows 1..181 used)
  double* Sm  = Cm + KROWS * TCOLS;               // 184*384 compact
  float*  nRr = (float*)(Sm + KROWS * TCOLS);     // 1024*361
  float*  nIr = nRr + 1024 * NBIN;                // 1024*361
  float*  Mv  = nIr + 1024 * NBIN;                // 8*128*128
  float*  rv  = Mv + 8 * 128 * 128;               // 8*128*8
  float*  D   = rv + 8 * 128 * 8;                 // 720*720 (16B-aligned)
  float*  Dt  = D + 720 * 720;                    // 720*720 transposed copy
  int*    Mi  = (int*)(Dt + 720 * 720);           // 8*128*128
  int*    lid = Mi + 8 * 128 * 128;               // 8*128*8
  int*    shf = lid + 8 * 128 * 8;                // 8*128*8
  int2*   ptab = (int2*)(shf + 8 * 128 * 8);      // 8128

  k_twiddle<<<3, 256, 0, stream>>>(ct, st);
  k_wmat<<<(KROWS * TCOLS + 255) / 256, 256, 0, stream>>>(ct, st, Cm, Sm);
  k_ptab<<<(NPAIRS + 255) / 256, 256, 0, stream>>>(ptab);
  k_dctmat<<<(720 * 720 + 255) / 256, 256, 0, stream>>>(D, Dt);
  k_rfft<<<8 * 128, 256, 0, stream>>>(x, ct, st, nRr, nIr);
  k_pc<<<8 * NPG, 128, 0, stream>>>(nRr, nIr, Cm, Sm, ptab, Mv, Mi);
  k_topk<<<8 * 128, 64, 0, stream>>>(Mv, Mi, lid, shf, rv);
  k_out<<<8 * 128, 256, 0, stream>>>(x, D, Dt, lid, shf, rv, out);
}

// Round 11
// 1490.044 us; speedup vs baseline: 2.5632x; 1.0092x over previous
//
#include <hip/hip_runtime.h>
#include <math.h>

#define LN   720
#define NBIN 361
#define CCH  128
#define NPAIRS 8128   // 128*127/2
#define NP     8      // pairs per k_pc block (8128 = 8*1016 exactly)
#define NPG    1016   // 8128/8
#define NB     3      // bins per thread (128*3=384 >= 361)
#define TCOLS  384    // compact table columns (only n<384 ever read)
#define KROWS  184    // table rows (k=1..181 read; padded)
#define CFROWS 184    // coeff rows (kk=0..179 used; padded for last prefetch)

// ---------------------------------------------------------------- tables
__global__ void k_twiddle(double* __restrict__ ct, double* __restrict__ st) {
  int m = blockIdx.x * 256 + threadIdx.x;
  if (m < LN) {
    double a = 6.2831853071795864769252867665590057684 * (double)m / 720.0;
    ct[m] = cos(a);
    st[m] = sin(a);
  }
}

// Compact: Cm[k*384+n] = ct[(k*n)%720] for n<384, k<184 (k-fold needs rows
// 1..181 incl. prefetch overrun). 2 x 184*384*8B = 1.1MB -> deep L2 residency.
__global__ void k_wmat(const double* __restrict__ ct, const double* __restrict__ st,
                       double* __restrict__ Cm, double* __restrict__ Sm) {
  int idx = blockIdx.x * 256 + threadIdx.x;
  if (idx < KROWS * TCOLS) {
    int k = idx / TCOLS, n = idx - k * TCOLS;
    int r = (int)(((long long)k * n) % LN);
    Cm[idx] = ct[r];
    Sm[idx] = st[r];
  }
}

__global__ void k_ptab(int2* __restrict__ ptab) {
  int p = blockIdx.x * 256 + threadIdx.x;
  if (p < NPAIRS) {
    int i = 0, rem = p;
    while (rem >= 127 - i) { rem -= 127 - i; i++; }
    ptab[p] = make_int2(i, i + 1 + rem);
  }
}

// D[k*720+l] and transposed Dt[l*720+k] (same values; Dt gives lane-coalesced
// phase-2 reads in k_out).
__global__ void k_dctmat(float* __restrict__ D, float* __restrict__ Dt) {
  int idx = blockIdx.x * 256 + threadIdx.x;
  if (idx < LN * LN) {
    int k = idx / LN, l = idx - k * LN;
    double ang = 3.1415926535897932384626433832795028842 * (double)((2 * l + 1) * k) / 1440.0;
    double v = cos(ang) * sqrt(2.0 / 720.0);
    if (k == 0) v *= 0.70710678118654752440084436210485;
    float f = (float)v;
    D[idx] = f;
    Dt[l * LN + k] = f;
  }
}

// ---------------------------------------------------------------- rfft (fp64 backbone) -> fp32-quantized nrf
__global__ __launch_bounds__(256) void k_rfft(const float* __restrict__ x,
                                              const double* __restrict__ ctg,
                                              const double* __restrict__ stg,
                                              float* __restrict__ nR,
                                              float* __restrict__ nI) {
  __shared__ double sd[LN];
  __shared__ double ctsP[768], stsP[768];
  int b = blockIdx.x >> 7, c = blockIdx.x & 127;
  int t = threadIdx.x;
  for (int m = t; m < LN; m += 256) {
    int a = m + (m >> 4);
    ctsP[a] = ctg[m]; stsP[a] = stg[m];
  }
  for (int l = t; l < LN; l += 256) sd[l] = (double)x[(b * LN + l) * CCH + c];
  __syncthreads();
  size_t gbase = (size_t)blockIdx.x * NBIN;
  for (int k = t; k < NBIN; k += 256) {
    double re = 0.0, im = 0.0;
    int idx = 0;
    for (int l = 0; l < LN; l++) {
      double s = sd[l];
      int a = idx + (idx >> 4);
      re += s * ctsP[a];
      im -= s * stsP[a];
      idx += k; if (idx >= LN) idx -= LN;
    }
    float reF = (float)re, imF = (float)im;        // complex64 quantization of rf
    float mag = hypotf(reF, imF);
    float d = fmaxf(mag, 1e-8f);
    nR[gbase + k] = __fdiv_rn(reF, d);
    nI[gbase + k] = __fdiv_rn(imF, d);
  }
}

// ---------------------------------------------------------------- phase correlation
// cross in strict fp32 (frozen invariant), irfft backbone fp64. pc fp32-
// quantized before max/argmax; ties -> lowest index.
//
// Round 16: bank-conflict shim. Round 15's separate eArr/oArr were 23552B
// apart (== 0 mod 128), so even lanes (eArr) and odd lanes (oArr) hit the
// SAME banks with different addresses in every coeff ds_read_b128 ->
// SQ_LDS_BANK_CONFLICT 1.4e8 (26% of CU time). Fix: one double2 (16B) of
// padding between the arrays -> odd-lane addresses shift 4 banks -> the two
// broadcast groups are bank-disjoint -> conflict-free. Pure LDS-placement
// change; staging/compute/order untouched -> bit-identical output.
__global__ __launch_bounds__(128, 2) void k_pc(const float* __restrict__ nR,
                                               const float* __restrict__ nI,
                                               const double* __restrict__ Cm,
                                               const double* __restrict__ Sm,
                                               const int2* __restrict__ ptab,
                                               float* __restrict__ Mv, int* __restrict__ Mi) {
  __shared__ double2 cfBuf[2 * CFROWS * NP + 1];  // [e | 16B shim | o]
  __shared__ double sdc[NP], sny[NP];    // k=0 (dc) and k=360 (nyquist) Re terms
  __shared__ int2 spair[NP];
  __shared__ float wv[2][NP][2];
  __shared__ int   wi[2][NP][2];
  double2* eB = cfBuf;
  double2* oB = cfBuf + CFROWS * NP + 1; // +1 double2 = +16B: bank-phase shift
  int b = blockIdx.x / NPG;
  int pg = blockIdx.x - b * NPG;
  int pbase = pg * NP;                   // always 8 full pairs (8128 = 8*1016)
  int t = threadIdx.x;
  if (t < NP) spair[t] = ptab[pbase + t];
  __syncthreads();

  // stage combined coefficients (strict fp32 cross, fp64 combine)
  for (int v = t; v < 180 * NP; v += 128) {
    int p = v & 7, kk = v >> 3;
    int k = kk + 1;                      // k = 1..180
    int i = spair[p].x, j = spair[p].y;
    size_t ib = ((size_t)(b << 7) + i) * NBIN;
    size_t jb = ((size_t)(b << 7) + j) * NBIN;
    float aR = nR[ib + k], aI = nI[ib + k];
    float bR = nR[jb + k], bI = nI[jb + k];
    float xr = __fadd_rn(__fmul_rn(aR, bR), __fmul_rn(aI, bI));
    float xi = __fsub_rn(__fmul_rn(aI, bR), __fmul_rn(aR, bI));
    double crA = (double)xr, ciA = (double)xi;
    if (k == 180) {
      // self-paired tail: raw coefficients for both parities
      eB[kk * NP + p] = make_double2(crA, ciA);
      oB[kk * NP + p] = make_double2(crA, ciA);
    } else {
      int kp = 360 - k;                  // fold partner
      float aR2 = nR[ib + kp], aI2 = nI[ib + kp];
      float bR2 = nR[jb + kp], bI2 = nI[jb + kp];
      float xr2 = __fadd_rn(__fmul_rn(aR2, bR2), __fmul_rn(aI2, bI2));
      float xi2 = __fsub_rn(__fmul_rn(aI2, bR2), __fmul_rn(aR2, bI2));
      double crB = (double)xr2, ciB = (double)xi2;
      eB[kk * NP + p] = make_double2(crA + crB, ciA - ciB);
      oB[kk * NP + p] = make_double2(crA - crB, ciA + ciB);
    }
  }
  if (t < NP) {
    int i = spair[t].x, j = spair[t].y;
    size_t ib = ((size_t)(b << 7) + i) * NBIN;
    size_t jb = ((size_t)(b << 7) + j) * NBIN;
    // dc (k=0)
    float aR = nR[ib], aI = nI[ib], bR = nR[jb], bI = nI[jb];
    sdc[t] = (double)__fadd_rn(__fmul_rn(aR, bR), __fmul_rn(aI, bI));
    // nyquist (k=360)
    float aR2 = nR[ib + 360], aI2 = nI[ib + 360];
    float bR2 = nR[jb + 360], bI2 = nI[jb + 360];
    sny[t] = (double)__fadd_rn(__fmul_rn(aR2, bR2), __fmul_rn(aI2, bI2));
  }
  __syncthreads();

  // thread t owns bins n = t + 128q, q=0..2 (n>360 lanes compute discarded
  // garbage; compact tables have 384 columns so loads stay in-bounds).
  double cosA[NP][NB], sinA[NP][NB];
#pragma unroll
  for (int p = 0; p < NP; p++)
#pragma unroll
    for (int q = 0; q < NB; q++) { cosA[p][q] = 0.0; sinA[p][q] = 0.0; }

  {
    const double2* __restrict__ myCf = (t & 1) ? oB : eB;
    const double* pC = Cm + (size_t)TCOLS + t;   // table row k=1
    const double* pS = Sm + (size_t)TCOLS + t;
    double CA0 = pC[0], CA1 = pC[128], CA2 = pC[256];
    double SA0 = pS[0], SA1 = pS[128], SA2 = pS[256];
    double2 fA0 = myCf[0], fA1 = myCf[1], fA2 = myCf[2], fA3 = myCf[3];
    double2 fA4 = myCf[4], fA5 = myCf[5], fA6 = myCf[6], fA7 = myCf[7];

#define PAIR1(pp, f, Cx0, Cx1, Cx2, Sx0, Sx1, Sx2)                     \
    cosA[pp][0] = fma(f.x, Cx0, cosA[pp][0]);                          \
    cosA[pp][1] = fma(f.x, Cx1, cosA[pp][1]);                          \
    cosA[pp][2] = fma(f.x, Cx2, cosA[pp][2]);                          \
    sinA[pp][0] = fma(f.y, Sx0, sinA[pp][0]);                          \
    sinA[pp][1] = fma(f.y, Sx1, sinA[pp][1]);                          \
    sinA[pp][2] = fma(f.y, Sx2, sinA[pp][2]);

#define COMPUTE(Cx0, Cx1, Cx2, Sx0, Sx1, Sx2, f0, f1, f2, f3, f4, f5, f6, f7) \
    {                                                                  \
      PAIR1(0, f0, Cx0, Cx1, Cx2, Sx0, Sx1, Sx2)                       \
      PAIR1(1, f1, Cx0, Cx1, Cx2, Sx0, Sx1, Sx2)                       \
      PAIR1(2, f2, Cx0, Cx1, Cx2, Sx0, Sx1, Sx2)                       \
      PAIR1(3, f3, Cx0, Cx1, Cx2, Sx0, Sx1, Sx2)                       \
      PAIR1(4, f4, Cx0, Cx1, Cx2, Sx0, Sx1, Sx2)                       \
      PAIR1(5, f5, Cx0, Cx1, Cx2, Sx0, Sx1, Sx2)                       \
      PAIR1(6, f6, Cx0, Cx1, Cx2, Sx0, Sx1, Sx2)                       \
      PAIR1(7, f7, Cx0, Cx1, Cx2, Sx0, Sx1, Sx2)                       \
    }

    double CB0, CB1, CB2, SB0, SB1, SB2;
    double2 fB0, fB1, fB2, fB3, fB4, fB5, fB6, fB7;
    for (int k = 1; k <= 179; k += 2) {
      // prefetch B: table row k+1, coeff row kk=k
      pC += TCOLS; pS += TCOLS;
      CB0 = pC[0]; CB1 = pC[128]; CB2 = pC[256];
      SB0 = pS[0]; SB1 = pS[128]; SB2 = pS[256];
      {
        const double2* cb = myCf + (size_t)k * NP;
        fB0 = cb[0]; fB1 = cb[1]; fB2 = cb[2]; fB3 = cb[3];
        fB4 = cb[4]; fB5 = cb[5]; fB6 = cb[6]; fB7 = cb[7];
      }
      COMPUTE(CA0, CA1, CA2, SA0, SA1, SA2, fA0, fA1, fA2, fA3, fA4, fA5, fA6, fA7)
      // prefetch A: table row k+2 (row 181 exists), coeff row kk=k+1 (padded)
      pC += TCOLS; pS += TCOLS;
      CA0 = pC[0]; CA1 = pC[128]; CA2 = pC[256];
      SA0 = pS[0]; SA1 = pS[128]; SA2 = pS[256];
      {
        const double2* ca = myCf + (size_t)(k + 1) * NP;
        fA0 = ca[0]; fA1 = ca[1]; fA2 = ca[2]; fA3 = ca[3];
        fA4 = ca[4]; fA5 = ca[5]; fA6 = ca[6]; fA7 = ca[7];
      }
      COMPUTE(CB0, CB1, CB2, SB0, SB1, SB2, fB0, fB1, fB2, fB3, fB4, fB5, fB6, fB7)
    }
#undef COMPUTE
#undef PAIR1
  }

  // epilogue: fp32 quantize + argmax (both directions), p-outer scalars,
  // wave-reduce then 2-way LDS merge.
  int lane = t & 63, w = t >> 6;
#pragma unroll
  for (int p = 0; p < NP; p++) {
    float bv1 = -3.0e38f, bv2 = -3.0e38f;
    int bi1 = 0x7fffffff, bi2 = 0x7fffffff;
    double dc = sdc[p], ny = sny[p];
#pragma unroll
    for (int q = 0; q < NB; q++) {
      int n = t + 128 * q;
      if (n <= 360) {
        bool hasRev = (n >= 1) && (n <= 359);  // n=0 invalid; n=360 duplicate of fwd
        int idxF1 = n;                          // d0 index of pf_f
        int idxR1 = LN - n;                     // d0 index of pf_r
        int idxF2 = (n == 0) ? 0 : (LN - n);    // d1 index of pf_f
        int idxR2 = n;                          // d1 index of pf_r
        double sg = (n & 1) ? -ny : ny;
        double ca = cosA[p][q], sa = sinA[p][q];
        float pf_f = (float)((dc + sg + 2.0 * (ca - sa)) * (1.0 / 720.0));
        float pf_r = (float)((dc + sg + 2.0 * (ca + sa)) * (1.0 / 720.0));
        if (pf_f > bv1 || (pf_f == bv1 && idxF1 < bi1)) { bv1 = pf_f; bi1 = idxF1; }
        if (hasRev && (pf_r > bv1 || (pf_r == bv1 && idxR1 < bi1))) { bv1 = pf_r; bi1 = idxR1; }
        if (pf_f > bv2 || (pf_f == bv2 && idxF2 < bi2)) { bv2 = pf_f; bi2 = idxF2; }
        if (hasRev && (pf_r > bv2 || (pf_r == bv2 && idxR2 < bi2))) { bv2 = pf_r; bi2 = idxR2; }
      }
    }
    for (int off = 32; off >= 1; off >>= 1) {
      float ov = __shfl_down(bv1, off); int oi = __shfl_down(bi1, off);
      if (ov > bv1 || (ov == bv1 && oi < bi1)) { bv1 = ov; bi1 = oi; }
      float ov2 = __shfl_down(bv2, off); int oi2 = __shfl_down(bi2, off);
      if (ov2 > bv2 || (ov2 == bv2 && oi2 < bi2)) { bv2 = ov2; bi2 = oi2; }
    }
    if (lane == 0) {
      wv[w][p][0] = bv1; wi[w][p][0] = bi1;
      wv[w][p][1] = bv2; wi[w][p][1] = bi2;
    }
  }
  __syncthreads();
  if (t < NP * 2) {
    int p = t >> 1, d = t & 1;
    float bv = wv[0][p][d]; int bi = wi[0][p][d];
    float ov = wv[1][p][d]; int oi = wi[1][p][d];
    if (ov > bv || (ov == bv && oi < bi)) { bv = ov; bi = oi; }
    int i = spair[p].x, j = spair[p].y;
    int o = d ? ((((b << 7) + j) << 7) + i) : ((((b << 7) + i) << 7) + j);
    Mv[o] = bv; Mi[o] = bi;
  }
}

// ---------------------------------------------------------------- top-8 (fp32, literal selection)
__global__ __launch_bounds__(64) void k_topk(const float* __restrict__ Mv, const int* __restrict__ Mi,
                                             int* __restrict__ lid, int* __restrict__ shf,
                                             float* __restrict__ rv) {
  int b = blockIdx.x >> 7, r = blockIdx.x & 127;
  if (threadIdx.x != 0) return;
  float sval[128]; int ssh[128];
  int base = (((b << 7) + r) << 7);
  for (int j = 0; j < 128; j++) {
    if (j == r) { sval[j] = -3.0e38f; ssh[j] = 0; continue; }
    float mvv = Mv[base + j]; int mii = Mi[base + j];
    sval[j] = mvv;
    ssh[j] = (mii > 360) ? (mii - 720) : mii;
  }
  for (int k = 0; k < 8; k++) {
    float best = -3.0e38f; int bj = 0;
    for (int j = 0; j < 128; j++)
      if (sval[j] > best) { best = sval[j]; bj = j; }
    int o = (((b << 7) + r) << 3) + k;
    lid[o] = bj; rv[o] = best; shf[o] = ssh[bj];
    sval[bj] = -3.0e38f;
  }
}

// ---------------------------------------------------------------- gather + DCT + bands (fp32, staged)
__global__ __launch_bounds__(256) void k_out(const float* __restrict__ x,
                                             const float* __restrict__ D,
                                             const float* __restrict__ Dt,
                                             const int* __restrict__ lid,
                                             const int* __restrict__ shf,
                                             const float* __restrict__ rv,
                                             float* __restrict__ out) {
  __shared__ float Xs[9][LN];
  __shared__ float pool[9216];   // phase1/2: xe[9*720]; phase3: obuf[256*36]
  __shared__ int s_lid[8], s_shf[8];
  __shared__ float s_r[8];
  int b = blockIdx.x >> 7, c = blockIdx.x & 127;
  int t = threadIdx.x;
  if (t < 8) {
    int q = (((b << 7) + c) << 3) + t;
    s_lid[t] = lid[q]; s_shf[t] = shf[q]; s_r[t] = rv[q];
  }
  float* xe = pool;
  for (int l = t; l < LN; l += 256) xe[l] = x[(b * LN + l) * CCH + c];
  __syncthreads();
  for (int p = 1; p <= 8; p++) {
    float r = s_r[p - 1];
    if (fabsf(r) < 0.1f) {
      for (int l = t; l < LN; l += 256) xe[p * LN + l] = xe[l];
    } else {
      float sg = (r < 0.f) ? -1.f : 1.f;
      int ld = s_lid[p - 1], sh = s_shf[p - 1];
      for (int l = t; l < LN; l += 256) {
        int tt = l - sh; tt = tt < 0 ? 0 : (tt > 719 ? 719 : tt);
        xe[p * LN + l] = sg * x[(b * LN + tt) * CCH + ld];
      }
    }
  }
  __syncthreads();

  // Phase 2: X[p,k] = sum_l D[k,l]*xe[p,l]. Reads via Dt[l*720+k] so lane k
  // is consecutive -> coalesced (D[k*720+l] had 2880B lane stride).
  {
    int k0 = t, k1 = t + 256, k2 = t + 512;
    int k2c = (k2 < LN) ? k2 : k0;
    float a0[9], a1[9], a2[9];
#pragma unroll
    for (int p = 0; p < 9; p++) { a0[p] = 0.f; a1[p] = 0.f; a2[p] = 0.f; }
    const float* DtRow = Dt;
    for (int l = 0; l < LN; l++) {
      float xl[9];
#pragma unroll
      for (int p = 0; p < 9; p++) xl[p] = xe[p * LN + l];
      float d0 = DtRow[k0], d1 = DtRow[k1], d2 = DtRow[k2c];
      DtRow += LN;
#pragma unroll
      for (int p = 0; p < 9; p++) {
        a0[p] += d0 * xl[p];
        a1[p] += d1 * xl[p];
        a2[p] += d2 * xl[p];
      }
    }
#pragma unroll
    for (int p = 0; p < 9; p++) {
      Xs[p][k0] = a0[p];
      Xs[p][k1] = a1[p];
      if (k2 < LN) Xs[p][k2] = a2[p];
    }
  }
  __syncthreads();

  // Phase 3: bands, chunked over n for coalesced output
  float* obuf = pool;
  size_t outbase = (size_t)((b << 7) + c) * (LN * 36);
  for (int n0 = 0; n0 < LN; n0 += 256) {
    int nt = t & 63;
    int f = t >> 6;
    int nloc = nt * 4;
    int nchunk = (LN - n0 < 256) ? (LN - n0) : 256;
    bool act = (nloc < nchunk);
    float a[36];
#pragma unroll
    for (int q = 0; q < 36; q++) a[q] = 0.f;
    if (act) {
      const float* Dp = D + (size_t)(f * 180) * LN + (n0 + nloc);
      for (int k = 0; k < 180; k++) {
        float4 d = *(const float4*)Dp;
        Dp += LN;
        int kk = f * 180 + k;
#pragma unroll
        for (int p = 0; p < 9; p++) {
          float xv = Xs[p][kk];
          a[p * 4 + 0] += d.x * xv;
          a[p * 4 + 1] += d.y * xv;
          a[p * 4 + 2] += d.z * xv;
          a[p * 4 + 3] += d.w * xv;
        }
      }
#pragma unroll
      for (int p = 0; p < 9; p++)
#pragma unroll
        for (int nn = 0; nn < 4; nn++)
          obuf[(nloc + nn) * 36 + p * 4 + f] = a[p * 4 + nn];
    }
    __syncthreads();
    int tot = nchunk * 36;
    for (int idx = t; idx < tot; idx += 256)
      out[outbase + (size_t)n0 * 36 + idx] = obuf[idx];
    __syncthreads();
  }
}

// ---------------------------------------------------------------- launch
extern "C" void kernel_launch(void* const* d_in, const int* in_sizes, int n_in,
                              void* d_out, int out_size, void* d_ws, size_t ws_size,
                              hipStream_t stream) {
  const float* x = (const float*)d_in[0];
  float* out = (float*)d_out;

  char* ws = (char*)d_ws;
  double* ct  = (double*)ws;                      // 720
  double* st  = ct + 720;                         // 720
  double* Cm  = st + 720;                         // 184*384 compact (rows 1..181 used)
  double* Sm  = Cm + KROWS * TCOLS;               // 184*384 compact
  float*  nRr = (float*)(Sm + KROWS * TCOLS);     // 1024*361
  float*  nIr = nRr + 1024 * NBIN;                // 1024*361
  float*  Mv  = nIr + 1024 * NBIN;                // 8*128*128
  float*  rv  = Mv + 8 * 128 * 128;               // 8*128*8
  float*  D   = rv + 8 * 128 * 8;                 // 720*720 (16B-aligned)
  float*  Dt  = D + 720 * 720;                    // 720*720 transposed copy
  int*    Mi  = (int*)(Dt + 720 * 720);           // 8*128*128
  int*    lid = Mi + 8 * 128 * 128;               // 8*128*8
  int*    shf = lid + 8 * 128 * 8;                // 8*128*8
  int2*   ptab = (int2*)(shf + 8 * 128 * 8);      // 8128

  k_twiddle<<<3, 256, 0, stream>>>(ct, st);
  k_wmat<<<(KROWS * TCOLS + 255) / 256, 256, 0, stream>>>(ct, st, Cm, Sm);
  k_ptab<<<(NPAIRS + 255) / 256, 256, 0, stream>>>(ptab);
  k_dctmat<<<(720 * 720 + 255) / 256, 256, 0, stream>>>(D, Dt);
  k_rfft<<<8 * 128, 256, 0, stream>>>(x, ct, st, nRr, nIr);
  k_pc<<<8 * NPG, 128, 0, stream>>>(nRr, nIr, Cm, Sm, ptab, Mv, Mi);
  k_topk<<<8 * 128, 64, 0, stream>>>(Mv, Mi, lid, shf, rv);
  k_out<<<8 * 128, 256, 0, stream>>>(x, D, Dt, lid, shf, rv, out);
}

// Round 12
// 1381.890 us; speedup vs baseline: 2.7638x; 1.0783x over previous
//
#include <hip/hip_runtime.h>
#include <math.h>

#define LN   720
#define NBIN 361
#define CCH  128
#define NPAIRS 8128   // 128*127/2
#define NP     8      // pairs per k_pc block (8128 = 8*1016 exactly)
#define NPG    1016   // 8128/8
#define NB     3      // bins per thread (128*3=384 >= 361)
#define TCOLS  384    // compact table columns (only n<384 ever read)
#define KROWS  184    // table rows (k=1..182 read incl. prefetch; padded)
#define CH     90     // coeff rows per chunk (2 chunks cover k=1..180)
#define CHPAD  92     // allocated rows per parity (2 pad rows for prefetch)

// ---------------------------------------------------------------- tables
__global__ void k_twiddle(double* __restrict__ ct, double* __restrict__ st) {
  int m = blockIdx.x * 256 + threadIdx.x;
  if (m < LN) {
    double a = 6.2831853071795864769252867665590057684 * (double)m / 720.0;
    ct[m] = cos(a);
    st[m] = sin(a);
  }
}

// Compact: Cm[k*384+n] = ct[(k*n)%720] for n<384, k<184 (k-fold needs rows
// 1..182 incl. prefetch overrun). 2 x 184*384*8B = 1.1MB -> deep L2 residency.
__global__ void k_wmat(const double* __restrict__ ct, const double* __restrict__ st,
                       double* __restrict__ Cm, double* __restrict__ Sm) {
  int idx = blockIdx.x * 256 + threadIdx.x;
  if (idx < KROWS * TCOLS) {
    int k = idx / TCOLS, n = idx - k * TCOLS;
    int r = (int)(((long long)k * n) % LN);
    Cm[idx] = ct[r];
    Sm[idx] = st[r];
  }
}

__global__ void k_ptab(int2* __restrict__ ptab) {
  int p = blockIdx.x * 256 + threadIdx.x;
  if (p < NPAIRS) {
    int i = 0, rem = p;
    while (rem >= 127 - i) { rem -= 127 - i; i++; }
    ptab[p] = make_int2(i, i + 1 + rem);
  }
}

// D[k*720+l] and transposed Dt[l*720+k] (same values; Dt gives lane-coalesced
// phase-2 reads in k_out).
__global__ void k_dctmat(float* __restrict__ D, float* __restrict__ Dt) {
  int idx = blockIdx.x * 256 + threadIdx.x;
  if (idx < LN * LN) {
    int k = idx / LN, l = idx - k * LN;
    double ang = 3.1415926535897932384626433832795028842 * (double)((2 * l + 1) * k) / 1440.0;
    double v = cos(ang) * sqrt(2.0 / 720.0);
    if (k == 0) v *= 0.70710678118654752440084436210485;
    float f = (float)v;
    D[idx] = f;
    Dt[l * LN + k] = f;
  }
}

// ---------------------------------------------------------------- rfft (fp64 backbone) -> fp32-quantized nrf
__global__ __launch_bounds__(256) void k_rfft(const float* __restrict__ x,
                                              const double* __restrict__ ctg,
                                              const double* __restrict__ stg,
                                              float* __restrict__ nR,
                                              float* __restrict__ nI) {
  __shared__ double sd[LN];
  __shared__ double ctsP[768], stsP[768];
  int b = blockIdx.x >> 7, c = blockIdx.x & 127;
  int t = threadIdx.x;
  for (int m = t; m < LN; m += 256) {
    int a = m + (m >> 4);
    ctsP[a] = ctg[m]; stsP[a] = stg[m];
  }
  for (int l = t; l < LN; l += 256) sd[l] = (double)x[(b * LN + l) * CCH + c];
  __syncthreads();
  size_t gbase = (size_t)blockIdx.x * NBIN;
  for (int k = t; k < NBIN; k += 256) {
    double re = 0.0, im = 0.0;
    int idx = 0;
    for (int l = 0; l < LN; l++) {
      double s = sd[l];
      int a = idx + (idx >> 4);
      re += s * ctsP[a];
      im -= s * stsP[a];
      idx += k; if (idx >= LN) idx -= LN;
    }
    float reF = (float)re, imF = (float)im;        // complex64 quantization of rf
    float mag = hypotf(reF, imF);
    float d = fmaxf(mag, 1e-8f);
    nR[gbase + k] = __fdiv_rn(reF, d);
    nI[gbase + k] = __fdiv_rn(imF, d);
  }
}

// ---------------------------------------------------------------- phase correlation
// cross in strict fp32 (frozen invariant), irfft backbone fp64. pc fp32-
// quantized before max/argmax; ties -> lowest index.
//
// Round 17: occupancy fix on top of round 16. The shim killed the conflicts
// (1.4e8 -> 0) but time stayed 855us: LDS 47.6KB -> 3 blocks/CU -> 1.33
// waves/SIMD -> VALUBusy 40% (latency-bound). Now the coeff buffer is staged
// in 2 chunks of 90 rows (k=1..90, 91..180), halving LDS to ~24KB -> 6
// blocks/CU -> 12 waves/CU. Chunks are consumed k-ascending; per-chunk
// prologue reloads the A-set; the 16B shim keeps its bank-phase shift
// (737*16 = 11792 = 16 mod 128). Data, combine math, and acc order unchanged
// -> bit-identical output. Cost: 2 extra barriers (negligible).
__global__ __launch_bounds__(128, 2) void k_pc(const float* __restrict__ nR,
                                               const float* __restrict__ nI,
                                               const double* __restrict__ Cm,
                                               const double* __restrict__ Sm,
                                               const int2* __restrict__ ptab,
                                               float* __restrict__ Mv, int* __restrict__ Mi) {
  __shared__ double2 cfBuf[2 * CHPAD * NP + 1];  // [e | 16B shim | o], one chunk
  __shared__ double sdc[NP], sny[NP];    // k=0 (dc) and k=360 (nyquist) Re terms
  __shared__ int2 spair[NP];
  __shared__ float wv[2][NP][2];
  __shared__ int   wi[2][NP][2];
  double2* eB = cfBuf;
  double2* oB = cfBuf + CHPAD * NP + 1;  // +16B: bank-phase shift (conflict-free)
  int b = blockIdx.x / NPG;
  int pg = blockIdx.x - b * NPG;
  int pbase = pg * NP;                   // always 8 full pairs (8128 = 8*1016)
  int t = threadIdx.x;
  if (t < NP) spair[t] = ptab[pbase + t];
  __syncthreads();

  // thread t owns bins n = t + 128q, q=0..2 (n>360 lanes compute discarded
  // garbage; compact tables have 384 columns so loads stay in-bounds).
  double cosA[NP][NB], sinA[NP][NB];
#pragma unroll
  for (int p = 0; p < NP; p++)
#pragma unroll
    for (int q = 0; q < NB; q++) { cosA[p][q] = 0.0; sinA[p][q] = 0.0; }

  for (int c = 0; c < 2; c++) {
    // ---- stage chunk c: coeff rows kk=0..89 <-> k = 1+90c .. 90+90c ----
    for (int v = t; v < CH * NP; v += 128) {
      int p = v & 7, kk = v >> 3;
      int k = kk + 1 + c * CH;
      int i = spair[p].x, j = spair[p].y;
      size_t ib = ((size_t)(b << 7) + i) * NBIN;
      size_t jb = ((size_t)(b << 7) + j) * NBIN;
      float aR = nR[ib + k], aI = nI[ib + k];
      float bR = nR[jb + k], bI = nI[jb + k];
      float xr = __fadd_rn(__fmul_rn(aR, bR), __fmul_rn(aI, bI));
      float xi = __fsub_rn(__fmul_rn(aI, bR), __fmul_rn(aR, bI));
      double crA = (double)xr, ciA = (double)xi;
      if (k == 180) {
        // self-paired tail: raw coefficients for both parities
        eB[kk * NP + p] = make_double2(crA, ciA);
        oB[kk * NP + p] = make_double2(crA, ciA);
      } else {
        int kp = 360 - k;                // fold partner
        float aR2 = nR[ib + kp], aI2 = nI[ib + kp];
        float bR2 = nR[jb + kp], bI2 = nI[jb + kp];
        float xr2 = __fadd_rn(__fmul_rn(aR2, bR2), __fmul_rn(aI2, bI2));
        float xi2 = __fsub_rn(__fmul_rn(aI2, bR2), __fmul_rn(aR2, bI2));
        double crB = (double)xr2, ciB = (double)xi2;
        eB[kk * NP + p] = make_double2(crA + crB, ciA - ciB);
        oB[kk * NP + p] = make_double2(crA - crB, ciA + ciB);
      }
    }
    if (c == 0 && t < NP) {
      int i = spair[t].x, j = spair[t].y;
      size_t ib = ((size_t)(b << 7) + i) * NBIN;
      size_t jb = ((size_t)(b << 7) + j) * NBIN;
      // dc (k=0)
      float aR = nR[ib], aI = nI[ib], bR = nR[jb], bI = nI[jb];
      sdc[t] = (double)__fadd_rn(__fmul_rn(aR, bR), __fmul_rn(aI, bI));
      // nyquist (k=360)
      float aR2 = nR[ib + 360], aI2 = nI[ib + 360];
      float bR2 = nR[jb + 360], bI2 = nI[jb + 360];
      sny[t] = (double)__fadd_rn(__fmul_rn(aR2, bR2), __fmul_rn(aI2, bI2));
    }
    __syncthreads();

    // ---- compute chunk c: k = k0 .. k0+89, k0 = 1+90c ----
    {
      const double2* __restrict__ myCf = (t & 1) ? oB : eB;
      const double* pC = Cm + (size_t)(1 + c * CH) * TCOLS + t;
      const double* pS = Sm + (size_t)(1 + c * CH) * TCOLS + t;
      double CA0 = pC[0], CA1 = pC[128], CA2 = pC[256];
      double SA0 = pS[0], SA1 = pS[128], SA2 = pS[256];
      double2 fA0 = myCf[0], fA1 = myCf[1], fA2 = myCf[2], fA3 = myCf[3];
      double2 fA4 = myCf[4], fA5 = myCf[5], fA6 = myCf[6], fA7 = myCf[7];

#define PAIR1(pp, f, Cx0, Cx1, Cx2, Sx0, Sx1, Sx2)                     \
      cosA[pp][0] = fma(f.x, Cx0, cosA[pp][0]);                        \
      cosA[pp][1] = fma(f.x, Cx1, cosA[pp][1]);                        \
      cosA[pp][2] = fma(f.x, Cx2, cosA[pp][2]);                        \
      sinA[pp][0] = fma(f.y, Sx0, sinA[pp][0]);                        \
      sinA[pp][1] = fma(f.y, Sx1, sinA[pp][1]);                        \
      sinA[pp][2] = fma(f.y, Sx2, sinA[pp][2]);

#define COMPUTE(Cx0, Cx1, Cx2, Sx0, Sx1, Sx2, f0, f1, f2, f3, f4, f5, f6, f7) \
      {                                                                \
        PAIR1(0, f0, Cx0, Cx1, Cx2, Sx0, Sx1, Sx2)                     \
        PAIR1(1, f1, Cx0, Cx1, Cx2, Sx0, Sx1, Sx2)                     \
        PAIR1(2, f2, Cx0, Cx1, Cx2, Sx0, Sx1, Sx2)                     \
        PAIR1(3, f3, Cx0, Cx1, Cx2, Sx0, Sx1, Sx2)                     \
        PAIR1(4, f4, Cx0, Cx1, Cx2, Sx0, Sx1, Sx2)                     \
        PAIR1(5, f5, Cx0, Cx1, Cx2, Sx0, Sx1, Sx2)                     \
        PAIR1(6, f6, Cx0, Cx1, Cx2, Sx0, Sx1, Sx2)                     \
        PAIR1(7, f7, Cx0, Cx1, Cx2, Sx0, Sx1, Sx2)                     \
      }

      double CB0, CB1, CB2, SB0, SB1, SB2;
      double2 fB0, fB1, fB2, fB3, fB4, fB5, fB6, fB7;
      for (int kk = 0; kk + 1 < CH; kk += 2) {
        // prefetch B: table row k0+kk+1, coeff local row kk+1
        pC += TCOLS; pS += TCOLS;
        CB0 = pC[0]; CB1 = pC[128]; CB2 = pC[256];
        SB0 = pS[0]; SB1 = pS[128]; SB2 = pS[256];
        {
          const double2* cb = myCf + (size_t)(kk + 1) * NP;
          fB0 = cb[0]; fB1 = cb[1]; fB2 = cb[2]; fB3 = cb[3];
          fB4 = cb[4]; fB5 = cb[5]; fB6 = cb[6]; fB7 = cb[7];
        }
        COMPUTE(CA0, CA1, CA2, SA0, SA1, SA2, fA0, fA1, fA2, fA3, fA4, fA5, fA6, fA7)
        // prefetch A: table row k0+kk+2 (<=182, rows exist), coeff row kk+2 (pad)
        pC += TCOLS; pS += TCOLS;
        CA0 = pC[0]; CA1 = pC[128]; CA2 = pC[256];
        SA0 = pS[0]; SA1 = pS[128]; SA2 = pS[256];
        {
          const double2* ca = myCf + (size_t)(kk + 2) * NP;
          fA0 = ca[0]; fA1 = ca[1]; fA2 = ca[2]; fA3 = ca[3];
          fA4 = ca[4]; fA5 = ca[5]; fA6 = ca[6]; fA7 = ca[7];
        }
        COMPUTE(CB0, CB1, CB2, SB0, SB1, SB2, fB0, fB1, fB2, fB3, fB4, fB5, fB6, fB7)
      }
#undef COMPUTE
#undef PAIR1
    }
    __syncthreads();   // chunk's coeffs fully consumed before restage
  }

  // epilogue: fp32 quantize + argmax (both directions), p-outer scalars,
  // wave-reduce then 2-way LDS merge.
  int lane = t & 63, w = t >> 6;
#pragma unroll
  for (int p = 0; p < NP; p++) {
    float bv1 = -3.0e38f, bv2 = -3.0e38f;
    int bi1 = 0x7fffffff, bi2 = 0x7fffffff;
    double dc = sdc[p], ny = sny[p];
#pragma unroll
    for (int q = 0; q < NB; q++) {
      int n = t + 128 * q;
      if (n <= 360) {
        bool hasRev = (n >= 1) && (n <= 359);  // n=0 invalid; n=360 duplicate of fwd
        int idxF1 = n;                          // d0 index of pf_f
        int idxR1 = LN - n;                     // d0 index of pf_r
        int idxF2 = (n == 0) ? 0 : (LN - n);    // d1 index of pf_f
        int idxR2 = n;                          // d1 index of pf_r
        double sg = (n & 1) ? -ny : ny;
        double ca = cosA[p][q], sa = sinA[p][q];
        float pf_f = (float)((dc + sg + 2.0 * (ca - sa)) * (1.0 / 720.0));
        float pf_r = (float)((dc + sg + 2.0 * (ca + sa)) * (1.0 / 720.0));
        if (pf_f > bv1 || (pf_f == bv1 && idxF1 < bi1)) { bv1 = pf_f; bi1 = idxF1; }
        if (hasRev && (pf_r > bv1 || (pf_r == bv1 && idxR1 < bi1))) { bv1 = pf_r; bi1 = idxR1; }
        if (pf_f > bv2 || (pf_f == bv2 && idxF2 < bi2)) { bv2 = pf_f; bi2 = idxF2; }
        if (hasRev && (pf_r > bv2 || (pf_r == bv2 && idxR2 < bi2))) { bv2 = pf_r; bi2 = idxR2; }
      }
    }
    for (int off = 32; off >= 1; off >>= 1) {
      float ov = __shfl_down(bv1, off); int oi = __shfl_down(bi1, off);
      if (ov > bv1 || (ov == bv1 && oi < bi1)) { bv1 = ov; bi1 = oi; }
      float ov2 = __shfl_down(bv2, off); int oi2 = __shfl_down(bi2, off);
      if (ov2 > bv2 || (ov2 == bv2 && oi2 < bi2)) { bv2 = ov2; bi2 = oi2; }
    }
    if (lane == 0) {
      wv[w][p][0] = bv1; wi[w][p][0] = bi1;
      wv[w][p][1] = bv2; wi[w][p][1] = bi2;
    }
  }
  __syncthreads();
  if (t < NP * 2) {
    int p = t >> 1, d = t & 1;
    float bv = wv[0][p][d]; int bi = wi[0][p][d];
    float ov = wv[1][p][d]; int oi = wi[1][p][d];
    if (ov > bv || (ov == bv && oi < bi)) { bv = ov; bi = oi; }
    int i = spair[p].x, j = spair[p].y;
    int o = d ? ((((b << 7) + j) << 7) + i) : ((((b << 7) + i) << 7) + j);
    Mv[o] = bv; Mi[o] = bi;
  }
}

// ---------------------------------------------------------------- top-8 (fp32, literal selection)
__global__ __launch_bounds__(64) void k_topk(const float* __restrict__ Mv, const int* __restrict__ Mi,
                                             int* __restrict__ lid, int* __restrict__ shf,
                                             float* __restrict__ rv) {
  int b = blockIdx.x >> 7, r = blockIdx.x & 127;
  if (threadIdx.x != 0) return;
  float sval[128]; int ssh[128];
  int base = (((b << 7) + r) << 7);
  for (int j = 0; j < 128; j++) {
    if (j == r) { sval[j] = -3.0e38f; ssh[j] = 0; continue; }
    float mvv = Mv[base + j]; int mii = Mi[base + j];
    sval[j] = mvv;
    ssh[j] = (mii > 360) ? (mii - 720) : mii;
  }
  for (int k = 0; k < 8; k++) {
    float best = -3.0e38f; int bj = 0;
    for (int j = 0; j < 128; j++)
      if (sval[j] > best) { best = sval[j]; bj = j; }
    int o = (((b << 7) + r) << 3) + k;
    lid[o] = bj; rv[o] = best; shf[o] = ssh[bj];
    sval[bj] = -3.0e38f;
  }
}

// ---------------------------------------------------------------- gather + DCT + bands (fp32, staged)
__global__ __launch_bounds__(256) void k_out(const float* __restrict__ x,
                                             const float* __restrict__ D,
                                             const float* __restrict__ Dt,
                                             const int* __restrict__ lid,
                                             const int* __restrict__ shf,
                                             const float* __restrict__ rv,
                                             float* __restrict__ out) {
  __shared__ float Xs[9][LN];
  __shared__ float pool[9216];   // phase1/2: xe[9*720]; phase3: obuf[256*36]
  __shared__ int s_lid[8], s_shf[8];
  __shared__ float s_r[8];
  int b = blockIdx.x >> 7, c = blockIdx.x & 127;
  int t = threadIdx.x;
  if (t < 8) {
    int q = (((b << 7) + c) << 3) + t;
    s_lid[t] = lid[q]; s_shf[t] = shf[q]; s_r[t] = rv[q];
  }
  float* xe = pool;
  for (int l = t; l < LN; l += 256) xe[l] = x[(b * LN + l) * CCH + c];
  __syncthreads();
  for (int p = 1; p <= 8; p++) {
    float r = s_r[p - 1];
    if (fabsf(r) < 0.1f) {
      for (int l = t; l < LN; l += 256) xe[p * LN + l] = xe[l];
    } else {
      float sg = (r < 0.f) ? -1.f : 1.f;
      int ld = s_lid[p - 1], sh = s_shf[p - 1];
      for (int l = t; l < LN; l += 256) {
        int tt = l - sh; tt = tt < 0 ? 0 : (tt > 719 ? 719 : tt);
        xe[p * LN + l] = sg * x[(b * LN + tt) * CCH + ld];
      }
    }
  }
  __syncthreads();

  // Phase 2: X[p,k] = sum_l D[k,l]*xe[p,l]. Reads via Dt[l*720+k] so lane k
  // is consecutive -> coalesced (D[k*720+l] had 2880B lane stride).
  {
    int k0 = t, k1 = t + 256, k2 = t + 512;
    int k2c = (k2 < LN) ? k2 : k0;
    float a0[9], a1[9], a2[9];
#pragma unroll
    for (int p = 0; p < 9; p++) { a0[p] = 0.f; a1[p] = 0.f; a2[p] = 0.f; }
    const float* DtRow = Dt;
    for (int l = 0; l < LN; l++) {
      float xl[9];
#pragma unroll
      for (int p = 0; p < 9; p++) xl[p] = xe[p * LN + l];
      float d0 = DtRow[k0], d1 = DtRow[k1], d2 = DtRow[k2c];
      DtRow += LN;
#pragma unroll
      for (int p = 0; p < 9; p++) {
        a0[p] += d0 * xl[p];
        a1[p] += d1 * xl[p];
        a2[p] += d2 * xl[p];
      }
    }
#pragma unroll
    for (int p = 0; p < 9; p++) {
      Xs[p][k0] = a0[p];
      Xs[p][k1] = a1[p];
      if (k2 < LN) Xs[p][k2] = a2[p];
    }
  }
  __syncthreads();

  // Phase 3: bands, chunked over n for coalesced output
  float* obuf = pool;
  size_t outbase = (size_t)((b << 7) + c) * (LN * 36);
  for (int n0 = 0; n0 < LN; n0 += 256) {
    int nt = t & 63;
    int f = t >> 6;
    int nloc = nt * 4;
    int nchunk = (LN - n0 < 256) ? (LN - n0) : 256;
    bool act = (nloc < nchunk);
    float a[36];
#pragma unroll
    for (int q = 0; q < 36; q++) a[q] = 0.f;
    if (act) {
      const float* Dp = D + (size_t)(f * 180) * LN + (n0 + nloc);
      for (int k = 0; k < 180; k++) {
        float4 d = *(const float4*)Dp;
        Dp += LN;
        int kk = f * 180 + k;
#pragma unroll
        for (int p = 0; p < 9; p++) {
          float xv = Xs[p][kk];
          a[p * 4 + 0] += d.x * xv;
          a[p * 4 + 1] += d.y * xv;
          a[p * 4 + 2] += d.z * xv;
          a[p * 4 + 3] += d.w * xv;
        }
      }
#pragma unroll
      for (int p = 0; p < 9; p++)
#pragma unroll
        for (int nn = 0; nn < 4; nn++)
          obuf[(nloc + nn) * 36 + p * 4 + f] = a[p * 4 + nn];
    }
    __syncthreads();
    int tot = nchunk * 36;
    for (int idx = t; idx < tot; idx += 256)
      out[outbase + (size_t)n0 * 36 + idx] = obuf[idx];
    __syncthreads();
  }
}

// ---------------------------------------------------------------- launch
extern "C" void kernel_launch(void* const* d_in, const int* in_sizes, int n_in,
                              void* d_out, int out_size, void* d_ws, size_t ws_size,
                              hipStream_t stream) {
  const float* x = (const float*)d_in[0];
  float* out = (float*)d_out;

  char* ws = (char*)d_ws;
  double* ct  = (double*)ws;                      // 720
  double* st  = ct + 720;                         // 720
  double* Cm  = st + 720;                         // 184*384 compact (rows 1..182 used)
  double* Sm  = Cm + KROWS * TCOLS;               // 184*384 compact
  float*  nRr = (float*)(Sm + KROWS * TCOLS);     // 1024*361
  float*  nIr = nRr + 1024 * NBIN;                // 1024*361
  float*  Mv  = nIr + 1024 * NBIN;                // 8*128*128
  float*  rv  = Mv + 8 * 128 * 128;               // 8*128*8
  float*  D   = rv + 8 * 128 * 8;                 // 720*720 (16B-aligned)
  float*  Dt  = D + 720 * 720;                    // 720*720 transposed copy
  int*    Mi  = (int*)(Dt + 720 * 720);           // 8*128*128
  int*    lid = Mi + 8 * 128 * 128;               // 8*128*8
  int*    shf = lid + 8 * 128 * 8;                // 8*128*8
  int2*   ptab = (int2*)(shf + 8 * 128 * 8);      // 8128

  k_twiddle<<<3, 256, 0, stream>>>(ct, st);
  k_wmat<<<(KROWS * TCOLS + 255) / 256, 256, 0, stream>>>(ct, st, Cm, Sm);
  k_ptab<<<(NPAIRS + 255) / 256, 256, 0, stream>>>(ptab);
  k_dctmat<<<(720 * 720 + 255) / 256, 256, 0, stream>>>(D, Dt);
  k_rfft<<<8 * 128, 256, 0, stream>>>(x, ct, st, nRr, nIr);
  k_pc<<<8 * NPG, 128, 0, stream>>>(nRr, nIr, Cm, Sm, ptab, Mv, Mi);
  k_topk<<<8 * 128, 64, 0, stream>>>(Mv, Mi, lid, shf, rv);
  k_out<<<8 * 128, 256, 0, stream>>>(x, D, Dt, lid, shf, rv, out);
}

// Round 13
// 1273.788 us; speedup vs baseline: 2.9984x; 1.0849x over previous
//
#include <hip/hip_runtime.h>
#include <math.h>

#define LN   720
#define NBIN 361
#define CCH  128
#define NPAIRS 8128   // 128*127/2
#define NP     8      // pairs per k_pc block (8128 = 8*1016 exactly)
#define NPG    1016   // 8128/8
#define NB     2      // bins per thread (192*2=384 >= 361)
#define TCOLS  384    // compact table columns (only n<384 ever read)
#define KROWS  184    // table rows (k=1..182 read incl. prefetch; padded)
#define CH     90     // coeff rows per chunk (2 chunks cover k=1..180)
#define CHPAD  92     // allocated rows per parity (2 pad rows for prefetch)

// ---------------------------------------------------------------- tables
__global__ void k_twiddle(double* __restrict__ ct, double* __restrict__ st) {
  int m = blockIdx.x * 256 + threadIdx.x;
  if (m < LN) {
    double a = 6.2831853071795864769252867665590057684 * (double)m / 720.0;
    ct[m] = cos(a);
    st[m] = sin(a);
  }
}

// Interleaved compact table: CSm[k*384+n] = (cos, sin) of 2*pi*k*n/720.
// Same values as the old separate Cm/Sm (built from the same ct/st lookup);
// double2 layout gives 16B/lane coalesced loads and halves load-instr count.
__global__ void k_wmat(const double* __restrict__ ct, const double* __restrict__ st,
                       double2* __restrict__ CSm) {
  int idx = blockIdx.x * 256 + threadIdx.x;
  if (idx < KROWS * TCOLS) {
    int k = idx / TCOLS, n = idx - k * TCOLS;
    int r = (int)(((long long)k * n) % LN);
    CSm[idx] = make_double2(ct[r], st[r]);
  }
}

__global__ void k_ptab(int2* __restrict__ ptab) {
  int p = blockIdx.x * 256 + threadIdx.x;
  if (p < NPAIRS) {
    int i = 0, rem = p;
    while (rem >= 127 - i) { rem -= 127 - i; i++; }
    ptab[p] = make_int2(i, i + 1 + rem);
  }
}

// D[k*720+l] and transposed Dt[l*720+k] (same values; Dt gives lane-coalesced
// phase-2 reads in k_out).
__global__ void k_dctmat(float* __restrict__ D, float* __restrict__ Dt) {
  int idx = blockIdx.x * 256 + threadIdx.x;
  if (idx < LN * LN) {
    int k = idx / LN, l = idx - k * LN;
    double ang = 3.1415926535897932384626433832795028842 * (double)((2 * l + 1) * k) / 1440.0;
    double v = cos(ang) * sqrt(2.0 / 720.0);
    if (k == 0) v *= 0.70710678118654752440084436210485;
    float f = (float)v;
    D[idx] = f;
    Dt[l * LN + k] = f;
  }
}

// ---------------------------------------------------------------- rfft (fp64 backbone) -> fp32-quantized nrf
__global__ __launch_bounds__(256) void k_rfft(const float* __restrict__ x,
                                              const double* __restrict__ ctg,
                                              const double* __restrict__ stg,
                                              float* __restrict__ nR,
                                              float* __restrict__ nI) {
  __shared__ double sd[LN];
  __shared__ double ctsP[768], stsP[768];
  int b = blockIdx.x >> 7, c = blockIdx.x & 127;
  int t = threadIdx.x;
  for (int m = t; m < LN; m += 256) {
    int a = m + (m >> 4);
    ctsP[a] = ctg[m]; stsP[a] = stg[m];
  }
  for (int l = t; l < LN; l += 256) sd[l] = (double)x[(b * LN + l) * CCH + c];
  __syncthreads();
  size_t gbase = (size_t)blockIdx.x * NBIN;
  for (int k = t; k < NBIN; k += 256) {
    double re = 0.0, im = 0.0;
    int idx = 0;
    for (int l = 0; l < LN; l++) {
      double s = sd[l];
      int a = idx + (idx >> 4);
      re += s * ctsP[a];
      im -= s * stsP[a];
      idx += k; if (idx >= LN) idx -= LN;
    }
    float reF = (float)re, imF = (float)im;        // complex64 quantization of rf
    float mag = hypotf(reF, imF);
    float d = fmaxf(mag, 1e-8f);
    nR[gbase + k] = __fdiv_rn(reF, d);
    nI[gbase + k] = __fdiv_rn(imF, d);
  }
}

// ---------------------------------------------------------------- phase correlation
// cross in strict fp32 (frozen invariant), irfft backbone fp64. pc fp32-
// quantized before max/argmax; ties -> lowest index.
//
// Round 18: occupancy via smaller per-thread tile. Round 12 was register-
// limited (108 VGPR + 96 acc regs in the unified file ~ 204/wave -> 2
// waves/SIMD, VALUBusy 48%). Now 192 threads (3 waves), NB=2 bins/thread
// (n = t, t+192) -> acc = 8 pairs x 2 bins x 2 = 32 doubles = 64 regs.
// Coeff prefetch dropped (demand broadcast reads; TLP hides LDS latency).
// Tables interleaved as double2(C,S): same bytes, half the load instrs,
// 16B/lane coalesced; 1-deep rolling prefetch. Staging (2 chunks, shim),
// coeff values, k-ascending chain order, and tie-breaks unchanged -> each
// (pair,bin) chain identical arithmetic -> bit-identical output.
__global__ __launch_bounds__(192, 2) void k_pc(const float* __restrict__ nR,
                                               const float* __restrict__ nI,
                                               const double2* __restrict__ CSm,
                                               const int2* __restrict__ ptab,
                                               float* __restrict__ Mv, int* __restrict__ Mi) {
  __shared__ double2 cfBuf[2 * CHPAD * NP + 1];  // [e | 16B shim | o], one chunk
  __shared__ double sdc[NP], sny[NP];    // k=0 (dc) and k=360 (nyquist) Re terms
  __shared__ int2 spair[NP];
  __shared__ float wv[3][NP][2];
  __shared__ int   wi[3][NP][2];
  double2* eB = cfBuf;
  double2* oB = cfBuf + CHPAD * NP + 1;  // +16B: bank-phase shift (conflict-free)
  int b = blockIdx.x / NPG;
  int pg = blockIdx.x - b * NPG;
  int pbase = pg * NP;                   // always 8 full pairs (8128 = 8*1016)
  int t = threadIdx.x;
  if (t < NP) spair[t] = ptab[pbase + t];
  __syncthreads();

  // thread t owns bins n = t and n = t+192 (n>360 lanes compute discarded
  // garbage; tables have 384 columns so loads stay in-bounds).
  double cosA[NP][NB], sinA[NP][NB];
#pragma unroll
  for (int p = 0; p < NP; p++)
#pragma unroll
    for (int q = 0; q < NB; q++) { cosA[p][q] = 0.0; sinA[p][q] = 0.0; }

  for (int c = 0; c < 2; c++) {
    // ---- stage chunk c: coeff rows kk=0..89 <-> k = 1+90c .. 90+90c ----
    for (int v = t; v < CH * NP; v += 192) {
      int p = v & 7, kk = v >> 3;
      int k = kk + 1 + c * CH;
      int i = spair[p].x, j = spair[p].y;
      size_t ib = ((size_t)(b << 7) + i) * NBIN;
      size_t jb = ((size_t)(b << 7) + j) * NBIN;
      float aR = nR[ib + k], aI = nI[ib + k];
      float bR = nR[jb + k], bI = nI[jb + k];
      float xr = __fadd_rn(__fmul_rn(aR, bR), __fmul_rn(aI, bI));
      float xi = __fsub_rn(__fmul_rn(aI, bR), __fmul_rn(aR, bI));
      double crA = (double)xr, ciA = (double)xi;
      if (k == 180) {
        // self-paired tail: raw coefficients for both parities
        eB[kk * NP + p] = make_double2(crA, ciA);
        oB[kk * NP + p] = make_double2(crA, ciA);
      } else {
        int kp = 360 - k;                // fold partner
        float aR2 = nR[ib + kp], aI2 = nI[ib + kp];
        float bR2 = nR[jb + kp], bI2 = nI[jb + kp];
        float xr2 = __fadd_rn(__fmul_rn(aR2, bR2), __fmul_rn(aI2, bI2));
        float xi2 = __fsub_rn(__fmul_rn(aI2, bR2), __fmul_rn(aR2, bI2));
        double crB = (double)xr2, ciB = (double)xi2;
        eB[kk * NP + p] = make_double2(crA + crB, ciA - ciB);
        oB[kk * NP + p] = make_double2(crA - crB, ciA + ciB);
      }
    }
    if (c == 0 && t < NP) {
      int i = spair[t].x, j = spair[t].y;
      size_t ib = ((size_t)(b << 7) + i) * NBIN;
      size_t jb = ((size_t)(b << 7) + j) * NBIN;
      // dc (k=0)
      float aR = nR[ib], aI = nI[ib], bR = nR[jb], bI = nI[jb];
      sdc[t] = (double)__fadd_rn(__fmul_rn(aR, bR), __fmul_rn(aI, bI));
      // nyquist (k=360)
      float aR2 = nR[ib + 360], aI2 = nI[ib + 360];
      float bR2 = nR[jb + 360], bI2 = nI[jb + 360];
      sny[t] = (double)__fadd_rn(__fmul_rn(aR2, bR2), __fmul_rn(aI2, bI2));
    }
    __syncthreads();

    // ---- compute chunk c: k = k0 .. k0+89, k0 = 1+90c ----
    {
      const double2* __restrict__ myCf = (t & 1) ? oB : eB;
      const double2* pCS = CSm + (size_t)(1 + c * CH) * TCOLS + t;
      double2 cs0 = pCS[0], cs1 = pCS[192];
      for (int kk = 0; kk < CH; kk++) {
        // rolling 1-deep table prefetch (rows <= 181 exist)
        pCS += TCOLS;
        double2 ncs0 = pCS[0], ncs1 = pCS[192];
        // demand broadcast coeff reads (uniform addr per parity group)
        const double2* cf = myCf + (size_t)kk * NP;
        double2 f0 = cf[0], f1 = cf[1], f2 = cf[2], f3 = cf[3];
        double2 f4 = cf[4], f5 = cf[5], f6 = cf[6], f7 = cf[7];
#define PAIR1(pp, f)                                                   \
        cosA[pp][0] = fma(f.x, cs0.x, cosA[pp][0]);                    \
        cosA[pp][1] = fma(f.x, cs1.x, cosA[pp][1]);                    \
        sinA[pp][0] = fma(f.y, cs0.y, sinA[pp][0]);                    \
        sinA[pp][1] = fma(f.y, cs1.y, sinA[pp][1]);
        PAIR1(0, f0) PAIR1(1, f1) PAIR1(2, f2) PAIR1(3, f3)
        PAIR1(4, f4) PAIR1(5, f5) PAIR1(6, f6) PAIR1(7, f7)
#undef PAIR1
        cs0 = ncs0; cs1 = ncs1;
      }
    }
    __syncthreads();   // chunk's coeffs fully consumed before restage
  }

  // epilogue: fp32 quantize + argmax (both directions), p-outer scalars,
  // wave-reduce then 3-way LDS merge.
  int lane = t & 63, w = t >> 6;
#pragma unroll
  for (int p = 0; p < NP; p++) {
    float bv1 = -3.0e38f, bv2 = -3.0e38f;
    int bi1 = 0x7fffffff, bi2 = 0x7fffffff;
    double dc = sdc[p], ny = sny[p];
#pragma unroll
    for (int q = 0; q < NB; q++) {
      int n = t + 192 * q;
      if (n <= 360) {
        bool hasRev = (n >= 1) && (n <= 359);  // n=0 invalid; n=360 duplicate of fwd
        int idxF1 = n;                          // d0 index of pf_f
        int idxR1 = LN - n;                     // d0 index of pf_r
        int idxF2 = (n == 0) ? 0 : (LN - n);    // d1 index of pf_f
        int idxR2 = n;                          // d1 index of pf_r
        double sg = (n & 1) ? -ny : ny;
        double ca = cosA[p][q], sa = sinA[p][q];
        float pf_f = (float)((dc + sg + 2.0 * (ca - sa)) * (1.0 / 720.0));
        float pf_r = (float)((dc + sg + 2.0 * (ca + sa)) * (1.0 / 720.0));
        if (pf_f > bv1 || (pf_f == bv1 && idxF1 < bi1)) { bv1 = pf_f; bi1 = idxF1; }
        if (hasRev && (pf_r > bv1 || (pf_r == bv1 && idxR1 < bi1))) { bv1 = pf_r; bi1 = idxR1; }
        if (pf_f > bv2 || (pf_f == bv2 && idxF2 < bi2)) { bv2 = pf_f; bi2 = idxF2; }
        if (hasRev && (pf_r > bv2 || (pf_r == bv2 && idxR2 < bi2))) { bv2 = pf_r; bi2 = idxR2; }
      }
    }
    for (int off = 32; off >= 1; off >>= 1) {
      float ov = __shfl_down(bv1, off); int oi = __shfl_down(bi1, off);
      if (ov > bv1 || (ov == bv1 && oi < bi1)) { bv1 = ov; bi1 = oi; }
      float ov2 = __shfl_down(bv2, off); int oi2 = __shfl_down(bi2, off);
      if (ov2 > bv2 || (ov2 == bv2 && oi2 < bi2)) { bv2 = ov2; bi2 = oi2; }
    }
    if (lane == 0) {
      wv[w][p][0] = bv1; wi[w][p][0] = bi1;
      wv[w][p][1] = bv2; wi[w][p][1] = bi2;
    }
  }
  __syncthreads();
  if (t < NP * 2) {
    int p = t >> 1, d = t & 1;
    float bv = wv[0][p][d]; int bi = wi[0][p][d];
    for (int ww = 1; ww < 3; ww++) {
      float ov = wv[ww][p][d]; int oi = wi[ww][p][d];
      if (ov > bv || (ov == bv && oi < bi)) { bv = ov; bi = oi; }
    }
    int i = spair[p].x, j = spair[p].y;
    int o = d ? ((((b << 7) + j) << 7) + i) : ((((b << 7) + i) << 7) + j);
    Mv[o] = bv; Mi[o] = bi;
  }
}

// ---------------------------------------------------------------- top-8 (fp32, literal selection)
__global__ __launch_bounds__(64) void k_topk(const float* __restrict__ Mv, const int* __restrict__ Mi,
                                             int* __restrict__ lid, int* __restrict__ shf,
                                             float* __restrict__ rv) {
  int b = blockIdx.x >> 7, r = blockIdx.x & 127;
  if (threadIdx.x != 0) return;
  float sval[128]; int ssh[128];
  int base = (((b << 7) + r) << 7);
  for (int j = 0; j < 128; j++) {
    if (j == r) { sval[j] = -3.0e38f; ssh[j] = 0; continue; }
    float mvv = Mv[base + j]; int mii = Mi[base + j];
    sval[j] = mvv;
    ssh[j] = (mii > 360) ? (mii - 720) : mii;
  }
  for (int k = 0; k < 8; k++) {
    float best = -3.0e38f; int bj = 0;
    for (int j = 0; j < 128; j++)
      if (sval[j] > best) { best = sval[j]; bj = j; }
    int o = (((b << 7) + r) << 3) + k;
    lid[o] = bj; rv[o] = best; shf[o] = ssh[bj];
    sval[bj] = -3.0e38f;
  }
}

// ---------------------------------------------------------------- gather + DCT + bands (fp32, staged)
__global__ __launch_bounds__(256) void k_out(const float* __restrict__ x,
                                             const float* __restrict__ D,
                                             const float* __restrict__ Dt,
                                             const int* __restrict__ lid,
                                             const int* __restrict__ shf,
                                             const float* __restrict__ rv,
                                             float* __restrict__ out) {
  __shared__ float Xs[9][LN];
  __shared__ float pool[9216];   // phase1/2: xe[9*720]; phase3: obuf[256*36]
  __shared__ int s_lid[8], s_shf[8];
  __shared__ float s_r[8];
  int b = blockIdx.x >> 7, c = blockIdx.x & 127;
  int t = threadIdx.x;
  if (t < 8) {
    int q = (((b << 7) + c) << 3) + t;
    s_lid[t] = lid[q]; s_shf[t] = shf[q]; s_r[t] = rv[q];
  }
  float* xe = pool;
  for (int l = t; l < LN; l += 256) xe[l] = x[(b * LN + l) * CCH + c];
  __syncthreads();
  for (int p = 1; p <= 8; p++) {
    float r = s_r[p - 1];
    if (fabsf(r) < 0.1f) {
      for (int l = t; l < LN; l += 256) xe[p * LN + l] = xe[l];
    } else {
      float sg = (r < 0.f) ? -1.f : 1.f;
      int ld = s_lid[p - 1], sh = s_shf[p - 1];
      for (int l = t; l < LN; l += 256) {
        int tt = l - sh; tt = tt < 0 ? 0 : (tt > 719 ? 719 : tt);
        xe[p * LN + l] = sg * x[(b * LN + tt) * CCH + ld];
      }
    }
  }
  __syncthreads();

  // Phase 2: X[p,k] = sum_l D[k,l]*xe[p,l]. Reads via Dt[l*720+k] so lane k
  // is consecutive -> coalesced (D[k*720+l] had 2880B lane stride).
  {
    int k0 = t, k1 = t + 256, k2 = t + 512;
    int k2c = (k2 < LN) ? k2 : k0;
    float a0[9], a1[9], a2[9];
#pragma unroll
    for (int p = 0; p < 9; p++) { a0[p] = 0.f; a1[p] = 0.f; a2[p] = 0.f; }
    const float* DtRow = Dt;
    for (int l = 0; l < LN; l++) {
      float xl[9];
#pragma unroll
      for (int p = 0; p < 9; p++) xl[p] = xe[p * LN + l];
      float d0 = DtRow[k0], d1 = DtRow[k1], d2 = DtRow[k2c];
      DtRow += LN;
#pragma unroll
      for (int p = 0; p < 9; p++) {
        a0[p] += d0 * xl[p];
        a1[p] += d1 * xl[p];
        a2[p] += d2 * xl[p];
      }
    }
#pragma unroll
    for (int p = 0; p < 9; p++) {
      Xs[p][k0] = a0[p];
      Xs[p][k1] = a1[p];
      if (k2 < LN) Xs[p][k2] = a2[p];
    }
  }
  __syncthreads();

  // Phase 3: bands, chunked over n for coalesced output
  float* obuf = pool;
  size_t outbase = (size_t)((b << 7) + c) * (LN * 36);
  for (int n0 = 0; n0 < LN; n0 += 256) {
    int nt = t & 63;
    int f = t >> 6;
    int nloc = nt * 4;
    int nchunk = (LN - n0 < 256) ? (LN - n0) : 256;
    bool act = (nloc < nchunk);
    float a[36];
#pragma unroll
    for (int q = 0; q < 36; q++) a[q] = 0.f;
    if (act) {
      const float* Dp = D + (size_t)(f * 180) * LN + (n0 + nloc);
      for (int k = 0; k < 180; k++) {
        float4 d = *(const float4*)Dp;
        Dp += LN;
        int kk = f * 180 + k;
#pragma unroll
        for (int p = 0; p < 9; p++) {
          float xv = Xs[p][kk];
          a[p * 4 + 0] += d.x * xv;
          a[p * 4 + 1] += d.y * xv;
          a[p * 4 + 2] += d.z * xv;
          a[p * 4 + 3] += d.w * xv;
        }
      }
#pragma unroll
      for (int p = 0; p < 9; p++)
#pragma unroll
        for (int nn = 0; nn < 4; nn++)
          obuf[(nloc + nn) * 36 + p * 4 + f] = a[p * 4 + nn];
    }
    __syncthreads();
    int tot = nchunk * 36;
    for (int idx = t; idx < tot; idx += 256)
      out[outbase + (size_t)n0 * 36 + idx] = obuf[idx];
    __syncthreads();
  }
}

// ---------------------------------------------------------------- launch
extern "C" void kernel_launch(void* const* d_in, const int* in_sizes, int n_in,
                              void* d_out, int out_size, void* d_ws, size_t ws_size,
                              hipStream_t stream) {
  const float* x = (const float*)d_in[0];
  float* out = (float*)d_out;

  char* ws = (char*)d_ws;
  double* ct  = (double*)ws;                      // 720
  double* st  = ct + 720;                         // 720
  double2* CSm = (double2*)(st + 720);            // 184*384 interleaved (C,S)
  float*  nRr = (float*)(CSm + KROWS * TCOLS);    // 1024*361
  float*  nIr = nRr + 1024 * NBIN;                // 1024*361
  float*  Mv  = nIr + 1024 * NBIN;                // 8*128*128
  float*  rv  = Mv + 8 * 128 * 128;               // 8*128*8
  float*  D   = rv + 8 * 128 * 8;                 // 720*720 (16B-aligned)
  float*  Dt  = D + 720 * 720;                    // 720*720 transposed copy
  int*    Mi  = (int*)(Dt + 720 * 720);           // 8*128*128
  int*    lid = Mi + 8 * 128 * 128;               // 8*128*8
  int*    shf = lid + 8 * 128 * 8;                // 8*128*8
  int2*   ptab = (int2*)(shf + 8 * 128 * 8);      // 8128

  k_twiddle<<<3, 256, 0, stream>>>(ct, st);
  k_wmat<<<(KROWS * TCOLS + 255) / 256, 256, 0, stream>>>(ct, st, CSm);
  k_ptab<<<(NPAIRS + 255) / 256, 256, 0, stream>>>(ptab);
  k_dctmat<<<(720 * 720 + 255) / 256, 256, 0, stream>>>(D, Dt);
  k_rfft<<<8 * 128, 256, 0, stream>>>(x, ct, st, nRr, nIr);
  k_pc<<<8 * NPG, 192, 0, stream>>>(nRr, nIr, CSm, ptab, Mv, Mi);
  k_topk<<<8 * 128, 64, 0, stream>>>(Mv, Mi, lid, shf, rv);
  k_out<<<8 * 128, 256, 0, stream>>>(x, D, Dt, lid, shf, rv, out);
}

// Round 14
// 1252.256 us; speedup vs baseline: 3.0499x; 1.0172x over previous
//
#include <hip/hip_runtime.h>
#include <math.h>

#define LN   720
#define NBIN 361
#define CCH  128
#define NPAIRS 8128   // 128*127/2
#define NP     8      // pairs per k_pc block (8128 = 8*1016 exactly)
#define NPG    1016   // 8128/8
#define NB     2      // bins per thread (192*2=384 >= 361)
#define TCOLS  384    // compact table columns (only n<384 ever read)
#define KROWS  184    // table rows (k=1..182 read incl. prefetch; padded)
#define CH     90     // coeff rows per chunk (2 chunks cover k=1..180)
#define CHPAD  92     // allocated rows per parity (2 pad rows for prefetch)

// ---------------------------------------------------------------- tables
__global__ void k_twiddle(double* __restrict__ ct, double* __restrict__ st) {
  int m = blockIdx.x * 256 + threadIdx.x;
  if (m < LN) {
    double a = 6.2831853071795864769252867665590057684 * (double)m / 720.0;
    ct[m] = cos(a);
    st[m] = sin(a);
  }
}

// Interleaved compact table: CSm[k*384+n] = (cos, sin) of 2*pi*k*n/720.
__global__ void k_wmat(const double* __restrict__ ct, const double* __restrict__ st,
                       double2* __restrict__ CSm) {
  int idx = blockIdx.x * 256 + threadIdx.x;
  if (idx < KROWS * TCOLS) {
    int k = idx / TCOLS, n = idx - k * TCOLS;
    int r = (int)(((long long)k * n) % LN);
    CSm[idx] = make_double2(ct[r], st[r]);
  }
}

__global__ void k_ptab(int2* __restrict__ ptab) {
  int p = blockIdx.x * 256 + threadIdx.x;
  if (p < NPAIRS) {
    int i = 0, rem = p;
    while (rem >= 127 - i) { rem -= 127 - i; i++; }
    ptab[p] = make_int2(i, i + 1 + rem);
  }
}

// D[k*720+l] and transposed Dt[l*720+k] (same values; Dt gives lane-coalesced
// phase-2 reads in k_out).
__global__ void k_dctmat(float* __restrict__ D, float* __restrict__ Dt) {
  int idx = blockIdx.x * 256 + threadIdx.x;
  if (idx < LN * LN) {
    int k = idx / LN, l = idx - k * LN;
    double ang = 3.1415926535897932384626433832795028842 * (double)((2 * l + 1) * k) / 1440.0;
    double v = cos(ang) * sqrt(2.0 / 720.0);
    if (k == 0) v *= 0.70710678118654752440084436210485;
    float f = (float)v;
    D[idx] = f;
    Dt[l * LN + k] = f;
  }
}

// ---------------------------------------------------------------- rfft (fp64 backbone) -> fp32-quantized nrf
__global__ __launch_bounds__(256) void k_rfft(const float* __restrict__ x,
                                              const double* __restrict__ ctg,
                                              const double* __restrict__ stg,
                                              float* __restrict__ nR,
                                              float* __restrict__ nI) {
  __shared__ double sd[LN];
  __shared__ double ctsP[768], stsP[768];
  int b = blockIdx.x >> 7, c = blockIdx.x & 127;
  int t = threadIdx.x;
  for (int m = t; m < LN; m += 256) {
    int a = m + (m >> 4);
    ctsP[a] = ctg[m]; stsP[a] = stg[m];
  }
  for (int l = t; l < LN; l += 256) sd[l] = (double)x[(b * LN + l) * CCH + c];
  __syncthreads();
  size_t gbase = (size_t)blockIdx.x * NBIN;
  for (int k = t; k < NBIN; k += 256) {
    double re = 0.0, im = 0.0;
    int idx = 0;
    for (int l = 0; l < LN; l++) {
      double s = sd[l];
      int a = idx + (idx >> 4);
      re += s * ctsP[a];
      im -= s * stsP[a];
      idx += k; if (idx >= LN) idx -= LN;
    }
    float reF = (float)re, imF = (float)im;        // complex64 quantization of rf
    float mag = hypotf(reF, imF);
    float d = fmaxf(mag, 1e-8f);
    nR[gbase + k] = __fdiv_rn(reF, d);
    nI[gbase + k] = __fdiv_rn(imF, d);
  }
}

// ---------------------------------------------------------------- phase correlation
// (unchanged from round 18 / 578us config: 192 thr, NB=2, 2-chunk staged
// parity coeffs with 16B shim, double2 tables, bit-identical output)
__global__ __launch_bounds__(192, 2) void k_pc(const float* __restrict__ nR,
                                               const float* __restrict__ nI,
                                               const double2* __restrict__ CSm,
                                               const int2* __restrict__ ptab,
                                               float* __restrict__ Mv, int* __restrict__ Mi) {
  __shared__ double2 cfBuf[2 * CHPAD * NP + 1];  // [e | 16B shim | o], one chunk
  __shared__ double sdc[NP], sny[NP];    // k=0 (dc) and k=360 (nyquist) Re terms
  __shared__ int2 spair[NP];
  __shared__ float wv[3][NP][2];
  __shared__ int   wi[3][NP][2];
  double2* eB = cfBuf;
  double2* oB = cfBuf + CHPAD * NP + 1;  // +16B: bank-phase shift (conflict-free)
  int b = blockIdx.x / NPG;
  int pg = blockIdx.x - b * NPG;
  int pbase = pg * NP;                   // always 8 full pairs (8128 = 8*1016)
  int t = threadIdx.x;
  if (t < NP) spair[t] = ptab[pbase + t];
  __syncthreads();

  double cosA[NP][NB], sinA[NP][NB];
#pragma unroll
  for (int p = 0; p < NP; p++)
#pragma unroll
    for (int q = 0; q < NB; q++) { cosA[p][q] = 0.0; sinA[p][q] = 0.0; }

  for (int c = 0; c < 2; c++) {
    // ---- stage chunk c: coeff rows kk=0..89 <-> k = 1+90c .. 90+90c ----
    for (int v = t; v < CH * NP; v += 192) {
      int p = v & 7, kk = v >> 3;
      int k = kk + 1 + c * CH;
      int i = spair[p].x, j = spair[p].y;
      size_t ib = ((size_t)(b << 7) + i) * NBIN;
      size_t jb = ((size_t)(b << 7) + j) * NBIN;
      float aR = nR[ib + k], aI = nI[ib + k];
      float bR = nR[jb + k], bI = nI[jb + k];
      float xr = __fadd_rn(__fmul_rn(aR, bR), __fmul_rn(aI, bI));
      float xi = __fsub_rn(__fmul_rn(aI, bR), __fmul_rn(aR, bI));
      double crA = (double)xr, ciA = (double)xi;
      if (k == 180) {
        eB[kk * NP + p] = make_double2(crA, ciA);
        oB[kk * NP + p] = make_double2(crA, ciA);
      } else {
        int kp = 360 - k;                // fold partner
        float aR2 = nR[ib + kp], aI2 = nI[ib + kp];
        float bR2 = nR[jb + kp], bI2 = nI[jb + kp];
        float xr2 = __fadd_rn(__fmul_rn(aR2, bR2), __fmul_rn(aI2, bI2));
        float xi2 = __fsub_rn(__fmul_rn(aI2, bR2), __fmul_rn(aR2, bI2));
        double crB = (double)xr2, ciB = (double)xi2;
        eB[kk * NP + p] = make_double2(crA + crB, ciA - ciB);
        oB[kk * NP + p] = make_double2(crA - crB, ciA + ciB);
      }
    }
    if (c == 0 && t < NP) {
      int i = spair[t].x, j = spair[t].y;
      size_t ib = ((size_t)(b << 7) + i) * NBIN;
      size_t jb = ((size_t)(b << 7) + j) * NBIN;
      float aR = nR[ib], aI = nI[ib], bR = nR[jb], bI = nI[jb];
      sdc[t] = (double)__fadd_rn(__fmul_rn(aR, bR), __fmul_rn(aI, bI));
      float aR2 = nR[ib + 360], aI2 = nI[ib + 360];
      float bR2 = nR[jb + 360], bI2 = nI[jb + 360];
      sny[t] = (double)__fadd_rn(__fmul_rn(aR2, bR2), __fmul_rn(aI2, bI2));
    }
    __syncthreads();

    // ---- compute chunk c ----
    {
      const double2* __restrict__ myCf = (t & 1) ? oB : eB;
      const double2* pCS = CSm + (size_t)(1 + c * CH) * TCOLS + t;
      double2 cs0 = pCS[0], cs1 = pCS[192];
      for (int kk = 0; kk < CH; kk++) {
        pCS += TCOLS;
        double2 ncs0 = pCS[0], ncs1 = pCS[192];
        const double2* cf = myCf + (size_t)kk * NP;
        double2 f0 = cf[0], f1 = cf[1], f2 = cf[2], f3 = cf[3];
        double2 f4 = cf[4], f5 = cf[5], f6 = cf[6], f7 = cf[7];
#define PAIR1(pp, f)                                                   \
        cosA[pp][0] = fma(f.x, cs0.x, cosA[pp][0]);                    \
        cosA[pp][1] = fma(f.x, cs1.x, cosA[pp][1]);                    \
        sinA[pp][0] = fma(f.y, cs0.y, sinA[pp][0]);                    \
        sinA[pp][1] = fma(f.y, cs1.y, sinA[pp][1]);
        PAIR1(0, f0) PAIR1(1, f1) PAIR1(2, f2) PAIR1(3, f3)
        PAIR1(4, f4) PAIR1(5, f5) PAIR1(6, f6) PAIR1(7, f7)
#undef PAIR1
        cs0 = ncs0; cs1 = ncs1;
      }
    }
    __syncthreads();   // chunk's coeffs fully consumed before restage
  }

  // epilogue: fp32 quantize + argmax (both directions)
  int lane = t & 63, w = t >> 6;
#pragma unroll
  for (int p = 0; p < NP; p++) {
    float bv1 = -3.0e38f, bv2 = -3.0e38f;
    int bi1 = 0x7fffffff, bi2 = 0x7fffffff;
    double dc = sdc[p], ny = sny[p];
#pragma unroll
    for (int q = 0; q < NB; q++) {
      int n = t + 192 * q;
      if (n <= 360) {
        bool hasRev = (n >= 1) && (n <= 359);
        int idxF1 = n;
        int idxR1 = LN - n;
        int idxF2 = (n == 0) ? 0 : (LN - n);
        int idxR2 = n;
        double sg = (n & 1) ? -ny : ny;
        double ca = cosA[p][q], sa = sinA[p][q];
        float pf_f = (float)((dc + sg + 2.0 * (ca - sa)) * (1.0 / 720.0));
        float pf_r = (float)((dc + sg + 2.0 * (ca + sa)) * (1.0 / 720.0));
        if (pf_f > bv1 || (pf_f == bv1 && idxF1 < bi1)) { bv1 = pf_f; bi1 = idxF1; }
        if (hasRev && (pf_r > bv1 || (pf_r == bv1 && idxR1 < bi1))) { bv1 = pf_r; bi1 = idxR1; }
        if (pf_f > bv2 || (pf_f == bv2 && idxF2 < bi2)) { bv2 = pf_f; bi2 = idxF2; }
        if (hasRev && (pf_r > bv2 || (pf_r == bv2 && idxR2 < bi2))) { bv2 = pf_r; bi2 = idxR2; }
      }
    }
    for (int off = 32; off >= 1; off >>= 1) {
      float ov = __shfl_down(bv1, off); int oi = __shfl_down(bi1, off);
      if (ov > bv1 || (ov == bv1 && oi < bi1)) { bv1 = ov; bi1 = oi; }
      float ov2 = __shfl_down(bv2, off); int oi2 = __shfl_down(bi2, off);
      if (ov2 > bv2 || (ov2 == bv2 && oi2 < bi2)) { bv2 = ov2; bi2 = oi2; }
    }
    if (lane == 0) {
      wv[w][p][0] = bv1; wi[w][p][0] = bi1;
      wv[w][p][1] = bv2; wi[w][p][1] = bi2;
    }
  }
  __syncthreads();
  if (t < NP * 2) {
    int p = t >> 1, d = t & 1;
    float bv = wv[0][p][d]; int bi = wi[0][p][d];
    for (int ww = 1; ww < 3; ww++) {
      float ov = wv[ww][p][d]; int oi = wi[ww][p][d];
      if (ov > bv || (ov == bv && oi < bi)) { bv = ov; bi = oi; }
    }
    int i = spair[p].x, j = spair[p].y;
    int o = d ? ((((b << 7) + j) << 7) + i) : ((((b << 7) + i) << 7) + j);
    Mv[o] = bv; Mi[o] = bi;
  }
}

// ---------------------------------------------------------------- top-8
// Round 19: wave-parallel selection. Old version used 1 of 64 threads for
// 128 serial uncoalesced loads + 1024 serial compares. Now each lane owns
// candidates j = lane, lane+64 (coalesced loads); 8 rounds of shfl-argmax
// with (val desc, idx asc) tie-break == the serial ascending-scan-strict-'>'
// semantics -> identical lid/shf/rv.
__global__ __launch_bounds__(64) void k_topk(const float* __restrict__ Mv, const int* __restrict__ Mi,
                                             int* __restrict__ lid, int* __restrict__ shf,
                                             float* __restrict__ rv) {
  int b = blockIdx.x >> 7, r = blockIdx.x & 127;
  int lane = threadIdx.x;
  int base = (((b << 7) + r) << 7);
  float v0, v1; int s0, s1;
  {
    int j0 = lane, j1 = lane + 64;
    if (j0 == r) { v0 = -3.0e38f; s0 = 0; }
    else { v0 = Mv[base + j0]; int m = Mi[base + j0]; s0 = (m > 360) ? m - 720 : m; }
    if (j1 == r) { v1 = -3.0e38f; s1 = 0; }
    else { v1 = Mv[base + j1]; int m = Mi[base + j1]; s1 = (m > 360) ? m - 720 : m; }
  }
  for (int k = 0; k < 8; k++) {
    float bv; int bj, bs;
    if (v0 >= v1) { bv = v0; bj = lane; bs = s0; }      // j0 < j1: ties -> lower j
    else          { bv = v1; bj = lane + 64; bs = s1; }
    for (int off = 32; off >= 1; off >>= 1) {
      float ov = __shfl_down(bv, off);
      int oj = __shfl_down(bj, off);
      int os = __shfl_down(bs, off);
      if (ov > bv || (ov == bv && oj < bj)) { bv = ov; bj = oj; bs = os; }
    }
    bv = __shfl(bv, 0); bj = __shfl(bj, 0); bs = __shfl(bs, 0);
    if (lane == 0) {
      int o = (((b << 7) + r) << 3) + k;
      lid[o] = bj; rv[o] = bv; shf[o] = bs;
    }
    if (bj == lane) v0 = -3.0e38f;
    if (bj == lane + 64) v1 = -3.0e38f;
  }
}

// ---------------------------------------------------------------- gather + DCT + bands (fp32, staged)
// Round 19: LDS 62.8KB -> 51.9KB (pool shrunk to xe's 6480 floats; phase-3
// output staging chunked at 128 n, 2 n per thread via float2 D loads).
// Per-output-element fma chains keep the exact k-ascending order ->
// bit-identical output. Occupancy 2 -> 3 blocks/CU.
__global__ __launch_bounds__(256) void k_out(const float* __restrict__ x,
                                             const float* __restrict__ D,
                                             const float* __restrict__ Dt,
                                             const int* __restrict__ lid,
                                             const int* __restrict__ shf,
                                             const float* __restrict__ rv,
                                             float* __restrict__ out) {
  __shared__ float Xs[9][LN];
  __shared__ float pool[6480];   // phase1/2: xe[9*720]; phase3: obuf[128*36]
  __shared__ int s_lid[8], s_shf[8];
  __shared__ float s_r[8];
  int b = blockIdx.x >> 7, c = blockIdx.x & 127;
  int t = threadIdx.x;
  if (t < 8) {
    int q = (((b << 7) + c) << 3) + t;
    s_lid[t] = lid[q]; s_shf[t] = shf[q]; s_r[t] = rv[q];
  }
  float* xe = pool;
  for (int l = t; l < LN; l += 256) xe[l] = x[(b * LN + l) * CCH + c];
  __syncthreads();
  for (int p = 1; p <= 8; p++) {
    float r = s_r[p - 1];
    if (fabsf(r) < 0.1f) {
      for (int l = t; l < LN; l += 256) xe[p * LN + l] = xe[l];
    } else {
      float sg = (r < 0.f) ? -1.f : 1.f;
      int ld = s_lid[p - 1], sh = s_shf[p - 1];
      for (int l = t; l < LN; l += 256) {
        int tt = l - sh; tt = tt < 0 ? 0 : (tt > 719 ? 719 : tt);
        xe[p * LN + l] = sg * x[(b * LN + tt) * CCH + ld];
      }
    }
  }
  __syncthreads();

  // Phase 2: X[p,k] = sum_l D[k,l]*xe[p,l] via coalesced Dt reads.
  {
    int k0 = t, k1 = t + 256, k2 = t + 512;
    int k2c = (k2 < LN) ? k2 : k0;
    float a0[9], a1[9], a2[9];
#pragma unroll
    for (int p = 0; p < 9; p++) { a0[p] = 0.f; a1[p] = 0.f; a2[p] = 0.f; }
    const float* DtRow = Dt;
    for (int l = 0; l < LN; l++) {
      float xl[9];
#pragma unroll
      for (int p = 0; p < 9; p++) xl[p] = xe[p * LN + l];
      float d0 = DtRow[k0], d1 = DtRow[k1], d2 = DtRow[k2c];
      DtRow += LN;
#pragma unroll
      for (int p = 0; p < 9; p++) {
        a0[p] += d0 * xl[p];
        a1[p] += d1 * xl[p];
        a2[p] += d2 * xl[p];
      }
    }
#pragma unroll
    for (int p = 0; p < 9; p++) {
      Xs[p][k0] = a0[p];
      Xs[p][k1] = a1[p];
      if (k2 < LN) Xs[p][k2] = a2[p];
    }
  }
  __syncthreads();

  // Phase 3: bands, chunked at 128 n (2 n per thread, float2 D loads)
  float* obuf = pool;
  size_t outbase = (size_t)((b << 7) + c) * (LN * 36);
  for (int n0 = 0; n0 < LN; n0 += 128) {
    int np_ = t & 63;          // n-pair index within chunk
    int f = t >> 6;            // band
    int nloc = np_ * 2;
    int nchunk = (LN - n0 < 128) ? (LN - n0) : 128;
    bool act = (nloc < nchunk);
    float a[18];
#pragma unroll
    for (int q = 0; q < 18; q++) a[q] = 0.f;
    if (act) {
      const float* Dp = D + (size_t)(f * 180) * LN + (n0 + nloc);
      for (int k = 0; k < 180; k++) {
        float2 d = *(const float2*)Dp;
        Dp += LN;
        int kk = f * 180 + k;
#pragma unroll
        for (int p = 0; p < 9; p++) {
          float xv = Xs[p][kk];
          a[p * 2 + 0] += d.x * xv;
          a[p * 2 + 1] += d.y * xv;
        }
      }
#pragma unroll
      for (int p = 0; p < 9; p++) {
        obuf[(nloc + 0) * 36 + p * 4 + f] = a[p * 2 + 0];
        obuf[(nloc + 1) * 36 + p * 4 + f] = a[p * 2 + 1];
      }
    }
    __syncthreads();
    int tot = nchunk * 36;
    for (int idx = t; idx < tot; idx += 256)
      out[outbase + (size_t)n0 * 36 + idx] = obuf[idx];
    __syncthreads();
  }
}

// ---------------------------------------------------------------- launch
extern "C" void kernel_launch(void* const* d_in, const int* in_sizes, int n_in,
                              void* d_out, int out_size, void* d_ws, size_t ws_size,
                              hipStream_t stream) {
  const float* x = (const float*)d_in[0];
  float* out = (float*)d_out;

  char* ws = (char*)d_ws;
  double* ct  = (double*)ws;                      // 720
  double* st  = ct + 720;                         // 720
  double2* CSm = (double2*)(st + 720);            // 184*384 interleaved (C,S)
  float*  nRr = (float*)(CSm + KROWS * TCOLS);    // 1024*361
  float*  nIr = nRr + 1024 * NBIN;                // 1024*361
  float*  Mv  = nIr + 1024 * NBIN;                // 8*128*128
  float*  rv  = Mv + 8 * 128 * 128;               // 8*128*8
  float*  D   = rv + 8 * 128 * 8;                 // 720*720 (16B-aligned)
  float*  Dt  = D + 720 * 720;                    // 720*720 transposed copy
  int*    Mi  = (int*)(Dt + 720 * 720);           // 8*128*128
  int*    lid = Mi + 8 * 128 * 128;               // 8*128*8
  int*    shf = lid + 8 * 128 * 8;                // 8*128*8
  int2*   ptab = (int2*)(shf + 8 * 128 * 8);      // 8128

  k_twiddle<<<3, 256, 0, stream>>>(ct, st);
  k_wmat<<<(KROWS * TCOLS + 255) / 256, 256, 0, stream>>>(ct, st, CSm);
  k_ptab<<<(NPAIRS + 255) / 256, 256, 0, stream>>>(ptab);
  k_dctmat<<<(720 * 720 + 255) / 256, 256, 0, stream>>>(D, Dt);
  k_rfft<<<8 * 128, 256, 0, stream>>>(x, ct, st, nRr, nIr);
  k_pc<<<8 * NPG, 192, 0, stream>>>(nRr, nIr, CSm, ptab, Mv, Mi);
  k_topk<<<8 * 128, 64, 0, stream>>>(Mv, Mi, lid, shf, rv);
  k_out<<<8 * 128, 256, 0, stream>>>(x, D, Dt, lid, shf, rv, out);
}

// Round 15
// 1161.645 us; speedup vs baseline: 3.2878x; 1.0780x over previous
//
#include <hip/hip_runtime.h>
#include <math.h>

#define LN   720
#define NBIN 361
#define CCH  128
#define NPAIRS 8128   // 128*127/2
#define NP     8      // pairs per k_pc block (8128 = 8*1016 exactly)
#define NPG    1016   // 8128/8
#define NB     2      // bins per thread (192*2=384 >= 361)
#define TCOLS  384    // compact table columns (only n<384 ever read)
#define KROWS  184    // table rows (k=1..182 read incl. prefetch; padded)
#define CH     90     // coeff rows per chunk (2 chunks cover k=1..180)
#define CHPAD  92     // allocated rows per parity (2 pad rows for prefetch)

// ---------------------------------------------------------------- tables
__global__ void k_twiddle(double* __restrict__ ct, double* __restrict__ st) {
  int m = blockIdx.x * 256 + threadIdx.x;
  if (m < LN) {
    double a = 6.2831853071795864769252867665590057684 * (double)m / 720.0;
    ct[m] = cos(a);
    st[m] = sin(a);
  }
}

// Interleaved compact table: CSm[k*384+n] = (cos, sin) of 2*pi*k*n/720.
__global__ void k_wmat(const double* __restrict__ ct, const double* __restrict__ st,
                       double2* __restrict__ CSm) {
  int idx = blockIdx.x * 256 + threadIdx.x;
  if (idx < KROWS * TCOLS) {
    int k = idx / TCOLS, n = idx - k * TCOLS;
    int r = (int)(((long long)k * n) % LN);
    CSm[idx] = make_double2(ct[r], st[r]);
  }
}

__global__ void k_ptab(int2* __restrict__ ptab) {
  int p = blockIdx.x * 256 + threadIdx.x;
  if (p < NPAIRS) {
    int i = 0, rem = p;
    while (rem >= 127 - i) { rem -= 127 - i; i++; }
    ptab[p] = make_int2(i, i + 1 + rem);
  }
}

// D[k*720+l] and transposed Dt[l*720+k] (same values; Dt gives lane-coalesced
// phase-2 reads in k_out).
__global__ void k_dctmat(float* __restrict__ D, float* __restrict__ Dt) {
  int idx = blockIdx.x * 256 + threadIdx.x;
  if (idx < LN * LN) {
    int k = idx / LN, l = idx - k * LN;
    double ang = 3.1415926535897932384626433832795028842 * (double)((2 * l + 1) * k) / 1440.0;
    double v = cos(ang) * sqrt(2.0 / 720.0);
    if (k == 0) v *= 0.70710678118654752440084436210485;
    float f = (float)v;
    D[idx] = f;
    Dt[l * LN + k] = f;
  }
}

// ---------------------------------------------------------------- rfft (fp64 backbone) -> fp32-quantized nrf
// Round 20: l <-> 720-l fold. re(k) = x0 + (-1)^k x360 + sum_{l=1..359}
// (x[l]+x[720-l]) cos(2pi k l/720); im(k) = -sum (x[l]-x[720-l]) sin(...).
// (u,v) staged interleaved as double2 -> per wave-iter 1 b128 + 4 scattered
// trig reads serving TWO bins (192 thr, k = t and t+192), 360 iters, no
// masked second pass: wave-LDS-reads/block 17.3K -> 5.4K, fma halved.
// Reorder + ct[720-r]->ct[r] (+-1 ulp) happen in the fp64 backbone BEFORE the
// fp32 quantize — the accepted round-9 perturbation class.
__global__ __launch_bounds__(192) void k_rfft(const float* __restrict__ x,
                                              const double* __restrict__ ctg,
                                              const double* __restrict__ stg,
                                              float* __restrict__ nR,
                                              float* __restrict__ nI) {
  __shared__ double sd[LN];
  __shared__ double2 uv[360];          // uv[l] = (x[l]+x[720-l], x[l]-x[720-l])
  __shared__ double ctsP[768], stsP[768];
  int b = blockIdx.x >> 7, c = blockIdx.x & 127;
  int t = threadIdx.x;
  for (int m = t; m < LN; m += 192) {
    int a = m + (m >> 4);
    ctsP[a] = ctg[m]; stsP[a] = stg[m];
  }
  for (int l = t; l < LN; l += 192) sd[l] = (double)x[(b * LN + l) * CCH + c];
  __syncthreads();
  for (int l = 1 + t; l < 360; l += 192) {
    double aa = sd[l], bb = sd[LN - l];
    uv[l] = make_double2(aa + bb, aa - bb);
  }
  __syncthreads();
  double sd0 = sd[0], sd360 = sd[360];
  size_t gbase = (size_t)blockIdx.x * NBIN;
  int k0 = t, k1 = t + 192;
  double re0 = sd0, im0 = 0.0, re1 = sd0, im1 = 0.0;
  int idx0 = 0, idx1 = 0;
  for (int l = 1; l < 360; l++) {
    idx0 += k0; if (idx0 >= LN) idx0 -= LN;
    idx1 += k1; if (idx1 >= LN) idx1 -= LN;
    double2 w = uv[l];
    int a0 = idx0 + (idx0 >> 4), a1 = idx1 + (idx1 >> 4);
    re0 = fma(w.x, ctsP[a0], re0);
    im0 = fma(-w.y, stsP[a0], im0);
    re1 = fma(w.x, ctsP[a1], re1);
    im1 = fma(-w.y, stsP[a1], im1);
  }
  re0 += (k0 & 1) ? -sd360 : sd360;
  re1 += (k1 & 1) ? -sd360 : sd360;
  {
    float reF = (float)re0, imF = (float)im0;   // complex64 quantization of rf
    float mag = hypotf(reF, imF);
    float d = fmaxf(mag, 1e-8f);
    nR[gbase + k0] = __fdiv_rn(reF, d);
    nI[gbase + k0] = __fdiv_rn(imF, d);
  }
  if (k1 < NBIN) {
    float reF = (float)re1, imF = (float)im1;
    float mag = hypotf(reF, imF);
    float d = fmaxf(mag, 1e-8f);
    nR[gbase + k1] = __fdiv_rn(reF, d);
    nI[gbase + k1] = __fdiv_rn(imF, d);
  }
}

// ---------------------------------------------------------------- phase correlation
// (unchanged 578us config: 192 thr, NB=2, 2-chunk staged parity coeffs with
// 16B shim, double2 tables, bit-identical output)
__global__ __launch_bounds__(192, 2) void k_pc(const float* __restrict__ nR,
                                               const float* __restrict__ nI,
                                               const double2* __restrict__ CSm,
                                               const int2* __restrict__ ptab,
                                               float* __restrict__ Mv, int* __restrict__ Mi) {
  __shared__ double2 cfBuf[2 * CHPAD * NP + 1];  // [e | 16B shim | o], one chunk
  __shared__ double sdc[NP], sny[NP];    // k=0 (dc) and k=360 (nyquist) Re terms
  __shared__ int2 spair[NP];
  __shared__ float wv[3][NP][2];
  __shared__ int   wi[3][NP][2];
  double2* eB = cfBuf;
  double2* oB = cfBuf + CHPAD * NP + 1;  // +16B: bank-phase shift (conflict-free)
  int b = blockIdx.x / NPG;
  int pg = blockIdx.x - b * NPG;
  int pbase = pg * NP;                   // always 8 full pairs (8128 = 8*1016)
  int t = threadIdx.x;
  if (t < NP) spair[t] = ptab[pbase + t];
  __syncthreads();

  double cosA[NP][NB], sinA[NP][NB];
#pragma unroll
  for (int p = 0; p < NP; p++)
#pragma unroll
    for (int q = 0; q < NB; q++) { cosA[p][q] = 0.0; sinA[p][q] = 0.0; }

  for (int c = 0; c < 2; c++) {
    // ---- stage chunk c: coeff rows kk=0..89 <-> k = 1+90c .. 90+90c ----
    for (int v = t; v < CH * NP; v += 192) {
      int p = v & 7, kk = v >> 3;
      int k = kk + 1 + c * CH;
      int i = spair[p].x, j = spair[p].y;
      size_t ib = ((size_t)(b << 7) + i) * NBIN;
      size_t jb = ((size_t)(b << 7) + j) * NBIN;
      float aR = nR[ib + k], aI = nI[ib + k];
      float bR = nR[jb + k], bI = nI[jb + k];
      float xr = __fadd_rn(__fmul_rn(aR, bR), __fmul_rn(aI, bI));
      float xi = __fsub_rn(__fmul_rn(aI, bR), __fmul_rn(aR, bI));
      double crA = (double)xr, ciA = (double)xi;
      if (k == 180) {
        eB[kk * NP + p] = make_double2(crA, ciA);
        oB[kk * NP + p] = make_double2(crA, ciA);
      } else {
        int kp = 360 - k;                // fold partner
        float aR2 = nR[ib + kp], aI2 = nI[ib + kp];
        float bR2 = nR[jb + kp], bI2 = nI[jb + kp];
        float xr2 = __fadd_rn(__fmul_rn(aR2, bR2), __fmul_rn(aI2, bI2));
        float xi2 = __fsub_rn(__fmul_rn(aI2, bR2), __fmul_rn(aR2, bI2));
        double crB = (double)xr2, ciB = (double)xi2;
        eB[kk * NP + p] = make_double2(crA + crB, ciA - ciB);
        oB[kk * NP + p] = make_double2(crA - crB, ciA + ciB);
      }
    }
    if (c == 0 && t < NP) {
      int i = spair[t].x, j = spair[t].y;
      size_t ib = ((size_t)(b << 7) + i) * NBIN;
      size_t jb = ((size_t)(b << 7) + j) * NBIN;
      float aR = nR[ib], aI = nI[ib], bR = nR[jb], bI = nI[jb];
      sdc[t] = (double)__fadd_rn(__fmul_rn(aR, bR), __fmul_rn(aI, bI));
      float aR2 = nR[ib + 360], aI2 = nI[ib + 360];
      float bR2 = nR[jb + 360], bI2 = nI[jb + 360];
      sny[t] = (double)__fadd_rn(__fmul_rn(aR2, bR2), __fmul_rn(aI2, bI2));
    }
    __syncthreads();

    // ---- compute chunk c ----
    {
      const double2* __restrict__ myCf = (t & 1) ? oB : eB;
      const double2* pCS = CSm + (size_t)(1 + c * CH) * TCOLS + t;
      double2 cs0 = pCS[0], cs1 = pCS[192];
      for (int kk = 0; kk < CH; kk++) {
        pCS += TCOLS;
        double2 ncs0 = pCS[0], ncs1 = pCS[192];
        const double2* cf = myCf + (size_t)kk * NP;
        double2 f0 = cf[0], f1 = cf[1], f2 = cf[2], f3 = cf[3];
        double2 f4 = cf[4], f5 = cf[5], f6 = cf[6], f7 = cf[7];
#define PAIR1(pp, f)                                                   \
        cosA[pp][0] = fma(f.x, cs0.x, cosA[pp][0]);                    \
        cosA[pp][1] = fma(f.x, cs1.x, cosA[pp][1]);                    \
        sinA[pp][0] = fma(f.y, cs0.y, sinA[pp][0]);                    \
        sinA[pp][1] = fma(f.y, cs1.y, sinA[pp][1]);
        PAIR1(0, f0) PAIR1(1, f1) PAIR1(2, f2) PAIR1(3, f3)
        PAIR1(4, f4) PAIR1(5, f5) PAIR1(6, f6) PAIR1(7, f7)
#undef PAIR1
        cs0 = ncs0; cs1 = ncs1;
      }
    }
    __syncthreads();   // chunk's coeffs fully consumed before restage
  }

  // epilogue: fp32 quantize + argmax (both directions)
  int lane = t & 63, w = t >> 6;
#pragma unroll
  for (int p = 0; p < NP; p++) {
    float bv1 = -3.0e38f, bv2 = -3.0e38f;
    int bi1 = 0x7fffffff, bi2 = 0x7fffffff;
    double dc = sdc[p], ny = sny[p];
#pragma unroll
    for (int q = 0; q < NB; q++) {
      int n = t + 192 * q;
      if (n <= 360) {
        bool hasRev = (n >= 1) && (n <= 359);
        int idxF1 = n;
        int idxR1 = LN - n;
        int idxF2 = (n == 0) ? 0 : (LN - n);
        int idxR2 = n;
        double sg = (n & 1) ? -ny : ny;
        double ca = cosA[p][q], sa = sinA[p][q];
        float pf_f = (float)((dc + sg + 2.0 * (ca - sa)) * (1.0 / 720.0));
        float pf_r = (float)((dc + sg + 2.0 * (ca + sa)) * (1.0 / 720.0));
        if (pf_f > bv1 || (pf_f == bv1 && idxF1 < bi1)) { bv1 = pf_f; bi1 = idxF1; }
        if (hasRev && (pf_r > bv1 || (pf_r == bv1 && idxR1 < bi1))) { bv1 = pf_r; bi1 = idxR1; }
        if (pf_f > bv2 || (pf_f == bv2 && idxF2 < bi2)) { bv2 = pf_f; bi2 = idxF2; }
        if (hasRev && (pf_r > bv2 || (pf_r == bv2 && idxR2 < bi2))) { bv2 = pf_r; bi2 = idxR2; }
      }
    }
    for (int off = 32; off >= 1; off >>= 1) {
      float ov = __shfl_down(bv1, off); int oi = __shfl_down(bi1, off);
      if (ov > bv1 || (ov == bv1 && oi < bi1)) { bv1 = ov; bi1 = oi; }
      float ov2 = __shfl_down(bv2, off); int oi2 = __shfl_down(bi2, off);
      if (ov2 > bv2 || (ov2 == bv2 && oi2 < bi2)) { bv2 = ov2; bi2 = oi2; }
    }
    if (lane == 0) {
      wv[w][p][0] = bv1; wi[w][p][0] = bi1;
      wv[w][p][1] = bv2; wi[w][p][1] = bi2;
    }
  }
  __syncthreads();
  if (t < NP * 2) {
    int p = t >> 1, d = t & 1;
    float bv = wv[0][p][d]; int bi = wi[0][p][d];
    for (int ww = 1; ww < 3; ww++) {
      float ov = wv[ww][p][d]; int oi = wi[ww][p][d];
      if (ov > bv || (ov == bv && oi < bi)) { bv = ov; bi = oi; }
    }
    int i = spair[p].x, j = spair[p].y;
    int o = d ? ((((b << 7) + j) << 7) + i) : ((((b << 7) + i) << 7) + j);
    Mv[o] = bv; Mi[o] = bi;
  }
}

// ---------------------------------------------------------------- top-8 (wave-parallel, round-19 version)
__global__ __launch_bounds__(64) void k_topk(const float* __restrict__ Mv, const int* __restrict__ Mi,
                                             int* __restrict__ lid, int* __restrict__ shf,
                                             float* __restrict__ rv) {
  int b = blockIdx.x >> 7, r = blockIdx.x & 127;
  int lane = threadIdx.x;
  int base = (((b << 7) + r) << 7);
  float v0, v1; int s0, s1;
  {
    int j0 = lane, j1 = lane + 64;
    if (j0 == r) { v0 = -3.0e38f; s0 = 0; }
    else { v0 = Mv[base + j0]; int m = Mi[base + j0]; s0 = (m > 360) ? m - 720 : m; }
    if (j1 == r) { v1 = -3.0e38f; s1 = 0; }
    else { v1 = Mv[base + j1]; int m = Mi[base + j1]; s1 = (m > 360) ? m - 720 : m; }
  }
  for (int k = 0; k < 8; k++) {
    float bv; int bj, bs;
    if (v0 >= v1) { bv = v0; bj = lane; bs = s0; }      // j0 < j1: ties -> lower j
    else          { bv = v1; bj = lane + 64; bs = s1; }
    for (int off = 32; off >= 1; off >>= 1) {
      float ov = __shfl_down(bv, off);
      int oj = __shfl_down(bj, off);
      int os = __shfl_down(bs, off);
      if (ov > bv || (ov == bv && oj < bj)) { bv = ov; bj = oj; bs = os; }
    }
    bv = __shfl(bv, 0); bj = __shfl(bj, 0); bs = __shfl(bs, 0);
    if (lane == 0) {
      int o = (((b << 7) + r) << 3) + k;
      lid[o] = bj; rv[o] = bv; shf[o] = bs;
    }
    if (bj == lane) v0 = -3.0e38f;
    if (bj == lane + 64) v1 = -3.0e38f;
  }
}

// ---------------------------------------------------------------- gather + DCT + bands (fp32, staged)
// Round 20: packed [row][12] layouts (48B rows, 16B-aligned) for xe and Xs so
// the 9 scalar broadcast LDS reads per inner iter become 2 x b128 + 1 x b32
// (3x fewer LDS instructions in BOTH hot loops). Values and fma order
// unchanged -> bit-identical output. LDS 51.9 -> 69.1KB (2 blocks/CU) —
// acceptable: these phases are LDS-pipe bound, not latency bound (round 14
// proved extra occupancy doesn't help).
__global__ __launch_bounds__(256) void k_out(const float* __restrict__ x,
                                             const float* __restrict__ D,
                                             const float* __restrict__ Dt,
                                             const int* __restrict__ lid,
                                             const int* __restrict__ shf,
                                             const float* __restrict__ rv,
                                             float* __restrict__ out) {
  __shared__ __align__(16) float XsP[8640];   // Xs[k][12], p<9 used
  __shared__ __align__(16) float pool[8640];  // ph1/2: xep[l][12]; ph3: obuf[128*36]
  __shared__ int s_lid[8], s_shf[8];
  __shared__ float s_r[8];
  int b = blockIdx.x >> 7, c = blockIdx.x & 127;
  int t = threadIdx.x;
  if (t < 8) {
    int q = (((b << 7) + c) << 3) + t;
    s_lid[t] = lid[q]; s_shf[t] = shf[q]; s_r[t] = rv[q];
  }
  float* xep = pool;
  for (int l = t; l < LN; l += 256) xep[l * 12] = x[(b * LN + l) * CCH + c];
  __syncthreads();
  for (int p = 1; p <= 8; p++) {
    float r = s_r[p - 1];
    if (fabsf(r) < 0.1f) {
      for (int l = t; l < LN; l += 256) xep[l * 12 + p] = xep[l * 12];
    } else {
      float sg = (r < 0.f) ? -1.f : 1.f;
      int ld = s_lid[p - 1], sh = s_shf[p - 1];
      for (int l = t; l < LN; l += 256) {
        int tt = l - sh; tt = tt < 0 ? 0 : (tt > 719 ? 719 : tt);
        xep[l * 12 + p] = sg * x[(b * LN + tt) * CCH + ld];
      }
    }
  }
  __syncthreads();

  // Phase 2: X[p,k] = sum_l D[k,l]*xe[p,l] via coalesced Dt reads; xe row
  // fetched as 2 x b128 + 1 x b32 (values/order identical to scalar reads).
  {
    int k0 = t, k1 = t + 256, k2 = t + 512;
    int k2c = (k2 < LN) ? k2 : k0;
    float a0[9], a1[9], a2[9];
#pragma unroll
    for (int p = 0; p < 9; p++) { a0[p] = 0.f; a1[p] = 0.f; a2[p] = 0.f; }
    const float* DtRow = Dt;
    for (int l = 0; l < LN; l++) {
      const float4* row = (const float4*)&xep[l * 12];
      float4 q0 = row[0], q1 = row[1];
      float x8 = xep[l * 12 + 8];
      float xl[9] = {q0.x, q0.y, q0.z, q0.w, q1.x, q1.y, q1.z, q1.w, x8};
      float d0 = DtRow[k0], d1 = DtRow[k1], d2 = DtRow[k2c];
      DtRow += LN;
#pragma unroll
      for (int p = 0; p < 9; p++) {
        a0[p] += d0 * xl[p];
        a1[p] += d1 * xl[p];
        a2[p] += d2 * xl[p];
      }
    }
#pragma unroll
    for (int p = 0; p < 9; p++) {
      XsP[k0 * 12 + p] = a0[p];
      XsP[k1 * 12 + p] = a1[p];
      if (k2 < LN) XsP[k2 * 12 + p] = a2[p];
    }
  }
  __syncthreads();

  // Phase 3: bands, chunked at 128 n (2 n per thread, float2 D loads);
  // Xs row fetched as 2 x b128 + 1 x b32.
  float* obuf = pool;
  size_t outbase = (size_t)((b << 7) + c) * (LN * 36);
  for (int n0 = 0; n0 < LN; n0 += 128) {
    int np_ = t & 63;          // n-pair index within chunk
    int f = t >> 6;            // band
    int nloc = np_ * 2;
    int nchunk = (LN - n0 < 128) ? (LN - n0) : 128;
    bool act = (nloc < nchunk);
    float a[18];
#pragma unroll
    for (int q = 0; q < 18; q++) a[q] = 0.f;
    if (act) {
      const float* Dp = D + (size_t)(f * 180) * LN + (n0 + nloc);
      for (int k = 0; k < 180; k++) {
        float2 d = *(const float2*)Dp;
        Dp += LN;
        int kk = f * 180 + k;
        const float4* xr = (const float4*)&XsP[kk * 12];
        float4 u0 = xr[0], u1 = xr[1];
        float u8 = XsP[kk * 12 + 8];
        float xv[9] = {u0.x, u0.y, u0.z, u0.w, u1.x, u1.y, u1.z, u1.w, u8};
#pragma unroll
        for (int p = 0; p < 9; p++) {
          a[p * 2 + 0] += d.x * xv[p];
          a[p * 2 + 1] += d.y * xv[p];
        }
      }
#pragma unroll
      for (int p = 0; p < 9; p++) {
        obuf[(nloc + 0) * 36 + p * 4 + f] = a[p * 2 + 0];
        obuf[(nloc + 1) * 36 + p * 4 + f] = a[p * 2 + 1];
      }
    }
    __syncthreads();
    int tot = nchunk * 36;
    for (int idx = t; idx < tot; idx += 256)
      out[outbase + (size_t)n0 * 36 + idx] = obuf[idx];
    __syncthreads();
  }
}

// ---------------------------------------------------------------- launch
extern "C" void kernel_launch(void* const* d_in, const int* in_sizes, int n_in,
                              void* d_out, int out_size, void* d_ws, size_t ws_size,
                              hipStream_t stream) {
  const float* x = (const float*)d_in[0];
  float* out = (float*)d_out;

  char* ws = (char*)d_ws;
  double* ct  = (double*)ws;                      // 720
  double* st  = ct + 720;                         // 720
  double2* CSm = (double2*)(st + 720);            // 184*384 interleaved (C,S)
  float*  nRr = (float*)(CSm + KROWS * TCOLS);    // 1024*361
  float*  nIr = nRr + 1024 * NBIN;                // 1024*361
  float*  Mv  = nIr + 1024 * NBIN;                // 8*128*128
  float*  rv  = Mv + 8 * 128 * 128;               // 8*128*8
  float*  D   = rv + 8 * 128 * 8;                 // 720*720 (16B-aligned)
  float*  Dt  = D + 720 * 720;                    // 720*720 transposed copy
  int*    Mi  = (int*)(Dt + 720 * 720);           // 8*128*128
  int*    lid = Mi + 8 * 128 * 128;               // 8*128*8
  int*    shf = lid + 8 * 128 * 8;                // 8*128*8
  int2*   ptab = (int2*)(shf + 8 * 128 * 8);      // 8128

  k_twiddle<<<3, 256, 0, stream>>>(ct, st);
  k_wmat<<<(KROWS * TCOLS + 255) / 256, 256, 0, stream>>>(ct, st, CSm);
  k_ptab<<<(NPAIRS + 255) / 256, 256, 0, stream>>>(ptab);
  k_dctmat<<<(720 * 720 + 255) / 256, 256, 0, stream>>>(D, Dt);
  k_rfft<<<8 * 128, 192, 0, stream>>>(x, ct, st, nRr, nIr);
  k_pc<<<8 * NPG, 192, 0, stream>>>(nRr, nIr, CSm, ptab, Mv, Mi);
  k_topk<<<8 * 128, 64, 0, stream>>>(Mv, Mi, lid, shf, rv);
  k_out<<<8 * 128, 256, 0, stream>>>(x, D, Dt, lid, shf, rv, out);
}

// Round 16
// 920.833 us; speedup vs baseline: 4.1477x; 1.2615x over previous
//
#include <hip/hip_runtime.h>
#include <math.h>

#define LN   720
#define NBIN 361
#define CCH  128
#define NPAIRS 8128   // 128*127/2
#define NP     8      // pairs per k_pc block (8128 = 8*1016 exactly)
#define NPG    1016   // 8128/8
#define NB     2      // bins per thread (192*2=384 >= 361)
#define TCOLS  384    // compact table columns (only n<384 ever read)
#define KROWS  184    // table rows (k=1..182 read incl. prefetch; padded)
#define CH     90     // coeff rows per chunk (2 chunks cover k=1..180)
#define CHPAD  92     // allocated rows per parity (2 pad rows for prefetch)

// ---------------------------------------------------------------- tables
__global__ void k_twiddle(double* __restrict__ ct, double* __restrict__ st) {
  int m = blockIdx.x * 256 + threadIdx.x;
  if (m < LN) {
    double a = 6.2831853071795864769252867665590057684 * (double)m / 720.0;
    ct[m] = cos(a);
    st[m] = sin(a);
  }
}

// Interleaved compact table: CSm[k*384+n] = (cos, sin) of 2*pi*k*n/720.
__global__ void k_wmat(const double* __restrict__ ct, const double* __restrict__ st,
                       double2* __restrict__ CSm) {
  int idx = blockIdx.x * 256 + threadIdx.x;
  if (idx < KROWS * TCOLS) {
    int k = idx / TCOLS, n = idx - k * TCOLS;
    int r = (int)(((long long)k * n) % LN);
    CSm[idx] = make_double2(ct[r], st[r]);
  }
}

__global__ void k_ptab(int2* __restrict__ ptab) {
  int p = blockIdx.x * 256 + threadIdx.x;
  if (p < NPAIRS) {
    int i = 0, rem = p;
    while (rem >= 127 - i) { rem -= 127 - i; i++; }
    ptab[p] = make_int2(i, i + 1 + rem);
  }
}

// D[k*720+l] and transposed Dt[l*720+k].
__global__ void k_dctmat(float* __restrict__ D, float* __restrict__ Dt) {
  int idx = blockIdx.x * 256 + threadIdx.x;
  if (idx < LN * LN) {
    int k = idx / LN, l = idx - k * LN;
    double ang = 3.1415926535897932384626433832795028842 * (double)((2 * l + 1) * k) / 1440.0;
    double v = cos(ang) * sqrt(2.0 / 720.0);
    if (k == 0) v *= 0.70710678118654752440084436210485;
    float f = (float)v;
    D[idx] = f;
    Dt[l * LN + k] = f;
  }
}

// ---------------------------------------------------------------- x transpose
// xT[(b*128+c)*720 + l] = x[(b*720+l)*128 + c] — makes k_rfft staging and
// k_out gathers lane-contiguous (x's c-stride-128 reads were 512B-stride
// uncoalesced per lane). Tile 16l x 64c via LDS, all dims divide evenly.
__global__ __launch_bounds__(256) void k_xT(const float* __restrict__ x,
                                            float* __restrict__ xT) {
  __shared__ float tile[16][65];
  int bx = blockIdx.x;
  int b = bx / 90, rem = bx - b * 90;
  int lt = rem >> 1, ctile = rem & 1;
  int l0 = lt * 16, c0 = ctile * 64;
  int t = threadIdx.x;
  int col = t & 63, r0 = t >> 6;
#pragma unroll
  for (int i = 0; i < 4; i++) {
    int r = r0 + i * 4;
    tile[r][col] = x[(size_t)(b * LN + l0 + r) * CCH + c0 + col];
  }
  __syncthreads();
  int ll = t & 15, cc0 = t >> 4;
#pragma unroll
  for (int i = 0; i < 4; i++) {
    int cc = cc0 + i * 16;
    xT[(size_t)(b * CCH + c0 + cc) * LN + l0 + ll] = tile[ll][cc];
  }
}

// ---------------------------------------------------------------- rfft (fp64 backbone) -> fp32-quantized nrf
// Round 20 fold kept; round 21: coalesced sd loads from xT + interleaved
// double2 trig LDS (2 b128 reads/iter instead of 4 b64). Same values, same
// fma order -> bit-identical to round 20's k_rfft.
__global__ __launch_bounds__(192) void k_rfft(const float* __restrict__ xT,
                                              const double* __restrict__ ctg,
                                              const double* __restrict__ stg,
                                              float* __restrict__ nR,
                                              float* __restrict__ nI) {
  __shared__ double sd[LN];
  __shared__ double2 uv[360];          // uv[l] = (x[l]+x[720-l], x[l]-x[720-l])
  __shared__ double2 csP[768];         // interleaved (ct, st), padded idx
  int b = blockIdx.x >> 7, c = blockIdx.x & 127;
  int t = threadIdx.x;
  for (int m = t; m < LN; m += 192) {
    int a = m + (m >> 4);
    csP[a] = make_double2(ctg[m], stg[m]);
  }
  size_t cbase = (size_t)(b * CCH + c) * LN;
  for (int l = t; l < LN; l += 192) sd[l] = (double)xT[cbase + l];
  __syncthreads();
  for (int l = 1 + t; l < 360; l += 192) {
    double aa = sd[l], bb = sd[LN - l];
    uv[l] = make_double2(aa + bb, aa - bb);
  }
  __syncthreads();
  double sd0 = sd[0], sd360 = sd[360];
  size_t gbase = (size_t)blockIdx.x * NBIN;
  int k0 = t, k1 = t + 192;
  double re0 = sd0, im0 = 0.0, re1 = sd0, im1 = 0.0;
  int idx0 = 0, idx1 = 0;
  for (int l = 1; l < 360; l++) {
    idx0 += k0; if (idx0 >= LN) idx0 -= LN;
    idx1 += k1; if (idx1 >= LN) idx1 -= LN;
    double2 w = uv[l];
    int a0 = idx0 + (idx0 >> 4), a1 = idx1 + (idx1 >> 4);
    double2 w2a = csP[a0];
    double2 w2b = csP[a1];
    re0 = fma(w.x, w2a.x, re0);
    im0 = fma(-w.y, w2a.y, im0);
    re1 = fma(w.x, w2b.x, re1);
    im1 = fma(-w.y, w2b.y, im1);
  }
  re0 += (k0 & 1) ? -sd360 : sd360;
  re1 += (k1 & 1) ? -sd360 : sd360;
  {
    float reF = (float)re0, imF = (float)im0;   // complex64 quantization of rf
    float mag = hypotf(reF, imF);
    float d = fmaxf(mag, 1e-8f);
    nR[gbase + k0] = __fdiv_rn(reF, d);
    nI[gbase + k0] = __fdiv_rn(imF, d);
  }
  if (k1 < NBIN) {
    float reF = (float)re1, imF = (float)im1;
    float mag = hypotf(reF, imF);
    float d = fmaxf(mag, 1e-8f);
    nR[gbase + k1] = __fdiv_rn(reF, d);
    nI[gbase + k1] = __fdiv_rn(imF, d);
  }
}

// ---------------------------------------------------------------- phase correlation
// (unchanged 574us config: 192 thr, NB=2, 2-chunk staged parity coeffs with
// 16B shim, double2 tables, bit-identical output)
__global__ __launch_bounds__(192, 2) void k_pc(const float* __restrict__ nR,
                                               const float* __restrict__ nI,
                                               const double2* __restrict__ CSm,
                                               const int2* __restrict__ ptab,
                                               float* __restrict__ Mv, int* __restrict__ Mi) {
  __shared__ double2 cfBuf[2 * CHPAD * NP + 1];  // [e | 16B shim | o], one chunk
  __shared__ double sdc[NP], sny[NP];    // k=0 (dc) and k=360 (nyquist) Re terms
  __shared__ int2 spair[NP];
  __shared__ float wv[3][NP][2];
  __shared__ int   wi[3][NP][2];
  double2* eB = cfBuf;
  double2* oB = cfBuf + CHPAD * NP + 1;  // +16B: bank-phase shift (conflict-free)
  int b = blockIdx.x / NPG;
  int pg = blockIdx.x - b * NPG;
  int pbase = pg * NP;                   // always 8 full pairs (8128 = 8*1016)
  int t = threadIdx.x;
  if (t < NP) spair[t] = ptab[pbase + t];
  __syncthreads();

  double cosA[NP][NB], sinA[NP][NB];
#pragma unroll
  for (int p = 0; p < NP; p++)
#pragma unroll
    for (int q = 0; q < NB; q++) { cosA[p][q] = 0.0; sinA[p][q] = 0.0; }

  for (int c = 0; c < 2; c++) {
    // ---- stage chunk c: coeff rows kk=0..89 <-> k = 1+90c .. 90+90c ----
    for (int v = t; v < CH * NP; v += 192) {
      int p = v & 7, kk = v >> 3;
      int k = kk + 1 + c * CH;
      int i = spair[p].x, j = spair[p].y;
      size_t ib = ((size_t)(b << 7) + i) * NBIN;
      size_t jb = ((size_t)(b << 7) + j) * NBIN;
      float aR = nR[ib + k], aI = nI[ib + k];
      float bR = nR[jb + k], bI = nI[jb + k];
      float xr = __fadd_rn(__fmul_rn(aR, bR), __fmul_rn(aI, bI));
      float xi = __fsub_rn(__fmul_rn(aI, bR), __fmul_rn(aR, bI));
      double crA = (double)xr, ciA = (double)xi;
      if (k == 180) {
        eB[kk * NP + p] = make_double2(crA, ciA);
        oB[kk * NP + p] = make_double2(crA, ciA);
      } else {
        int kp = 360 - k;                // fold partner
        float aR2 = nR[ib + kp], aI2 = nI[ib + kp];
        float bR2 = nR[jb + kp], bI2 = nI[jb + kp];
        float xr2 = __fadd_rn(__fmul_rn(aR2, bR2), __fmul_rn(aI2, bI2));
        float xi2 = __fsub_rn(__fmul_rn(aI2, bR2), __fmul_rn(aR2, bI2));
        double crB = (double)xr2, ciB = (double)xi2;
        eB[kk * NP + p] = make_double2(crA + crB, ciA - ciB);
        oB[kk * NP + p] = make_double2(crA - crB, ciA + ciB);
      }
    }
    if (c == 0 && t < NP) {
      int i = spair[t].x, j = spair[t].y;
      size_t ib = ((size_t)(b << 7) + i) * NBIN;
      size_t jb = ((size_t)(b << 7) + j) * NBIN;
      float aR = nR[ib], aI = nI[ib], bR = nR[jb], bI = nI[jb];
      sdc[t] = (double)__fadd_rn(__fmul_rn(aR, bR), __fmul_rn(aI, bI));
      float aR2 = nR[ib + 360], aI2 = nI[ib + 360];
      float bR2 = nR[jb + 360], bI2 = nI[jb + 360];
      sny[t] = (double)__fadd_rn(__fmul_rn(aR2, bR2), __fmul_rn(aI2, bI2));
    }
    __syncthreads();

    // ---- compute chunk c ----
    {
      const double2* __restrict__ myCf = (t & 1) ? oB : eB;
      const double2* pCS = CSm + (size_t)(1 + c * CH) * TCOLS + t;
      double2 cs0 = pCS[0], cs1 = pCS[192];
      for (int kk = 0; kk < CH; kk++) {
        pCS += TCOLS;
        double2 ncs0 = pCS[0], ncs1 = pCS[192];
        const double2* cf = myCf + (size_t)kk * NP;
        double2 f0 = cf[0], f1 = cf[1], f2 = cf[2], f3 = cf[3];
        double2 f4 = cf[4], f5 = cf[5], f6 = cf[6], f7 = cf[7];
#define PAIR1(pp, f)                                                   \
        cosA[pp][0] = fma(f.x, cs0.x, cosA[pp][0]);                    \
        cosA[pp][1] = fma(f.x, cs1.x, cosA[pp][1]);                    \
        sinA[pp][0] = fma(f.y, cs0.y, sinA[pp][0]);                    \
        sinA[pp][1] = fma(f.y, cs1.y, sinA[pp][1]);
        PAIR1(0, f0) PAIR1(1, f1) PAIR1(2, f2) PAIR1(3, f3)
        PAIR1(4, f4) PAIR1(5, f5) PAIR1(6, f6) PAIR1(7, f7)
#undef PAIR1
        cs0 = ncs0; cs1 = ncs1;
      }
    }
    __syncthreads();   // chunk's coeffs fully consumed before restage
  }

  // epilogue: fp32 quantize + argmax (both directions)
  int lane = t & 63, w = t >> 6;
#pragma unroll
  for (int p = 0; p < NP; p++) {
    float bv1 = -3.0e38f, bv2 = -3.0e38f;
    int bi1 = 0x7fffffff, bi2 = 0x7fffffff;
    double dc = sdc[p], ny = sny[p];
#pragma unroll
    for (int q = 0; q < NB; q++) {
      int n = t + 192 * q;
      if (n <= 360) {
        bool hasRev = (n >= 1) && (n <= 359);
        int idxF1 = n;
        int idxR1 = LN - n;
        int idxF2 = (n == 0) ? 0 : (LN - n);
        int idxR2 = n;
        double sg = (n & 1) ? -ny : ny;
        double ca = cosA[p][q], sa = sinA[p][q];
        float pf_f = (float)((dc + sg + 2.0 * (ca - sa)) * (1.0 / 720.0));
        float pf_r = (float)((dc + sg + 2.0 * (ca + sa)) * (1.0 / 720.0));
        if (pf_f > bv1 || (pf_f == bv1 && idxF1 < bi1)) { bv1 = pf_f; bi1 = idxF1; }
        if (hasRev && (pf_r > bv1 || (pf_r == bv1 && idxR1 < bi1))) { bv1 = pf_r; bi1 = idxR1; }
        if (pf_f > bv2 || (pf_f == bv2 && idxF2 < bi2)) { bv2 = pf_f; bi2 = idxF2; }
        if (hasRev && (pf_r > bv2 || (pf_r == bv2 && idxR2 < bi2))) { bv2 = pf_r; bi2 = idxR2; }
      }
    }
    for (int off = 32; off >= 1; off >>= 1) {
      float ov = __shfl_down(bv1, off); int oi = __shfl_down(bi1, off);
      if (ov > bv1 || (ov == bv1 && oi < bi1)) { bv1 = ov; bi1 = oi; }
      float ov2 = __shfl_down(bv2, off); int oi2 = __shfl_down(bi2, off);
      if (ov2 > bv2 || (ov2 == bv2 && oi2 < bi2)) { bv2 = ov2; bi2 = oi2; }
    }
    if (lane == 0) {
      wv[w][p][0] = bv1; wi[w][p][0] = bi1;
      wv[w][p][1] = bv2; wi[w][p][1] = bi2;
    }
  }
  __syncthreads();
  if (t < NP * 2) {
    int p = t >> 1, d = t & 1;
    float bv = wv[0][p][d]; int bi = wi[0][p][d];
    for (int ww = 1; ww < 3; ww++) {
      float ov = wv[ww][p][d]; int oi = wi[ww][p][d];
      if (ov > bv || (ov == bv && oi < bi)) { bv = ov; bi = oi; }
    }
    int i = spair[p].x, j = spair[p].y;
    int o = d ? ((((b << 7) + j) << 7) + i) : ((((b << 7) + i) << 7) + j);
    Mv[o] = bv; Mi[o] = bi;
  }
}

// ---------------------------------------------------------------- top-8 (wave-parallel)
__global__ __launch_bounds__(64) void k_topk(const float* __restrict__ Mv, const int* __restrict__ Mi,
                                             int* __restrict__ lid, int* __restrict__ shf,
                                             float* __restrict__ rv) {
  int b = blockIdx.x >> 7, r = blockIdx.x & 127;
  int lane = threadIdx.x;
  int base = (((b << 7) + r) << 7);
  float v0, v1; int s0, s1;
  {
    int j0 = lane, j1 = lane + 64;
    if (j0 == r) { v0 = -3.0e38f; s0 = 0; }
    else { v0 = Mv[base + j0]; int m = Mi[base + j0]; s0 = (m > 360) ? m - 720 : m; }
    if (j1 == r) { v1 = -3.0e38f; s1 = 0; }
    else { v1 = Mv[base + j1]; int m = Mi[base + j1]; s1 = (m > 360) ? m - 720 : m; }
  }
  for (int k = 0; k < 8; k++) {
    float bv; int bj, bs;
    if (v0 >= v1) { bv = v0; bj = lane; bs = s0; }      // j0 < j1: ties -> lower j
    else          { bv = v1; bj = lane + 64; bs = s1; }
    for (int off = 32; off >= 1; off >>= 1) {
      float ov = __shfl_down(bv, off);
      int oj = __shfl_down(bj, off);
      int os = __shfl_down(bs, off);
      if (ov > bv || (ov == bv && oj < bj)) { bv = ov; bj = oj; bs = os; }
    }
    bv = __shfl(bv, 0); bj = __shfl(bj, 0); bs = __shfl(bs, 0);
    if (lane == 0) {
      int o = (((b << 7) + r) << 3) + k;
      lid[o] = bj; rv[o] = bv; shf[o] = bs;
    }
    if (bj == lane) v0 = -3.0e38f;
    if (bj == lane + 64) v1 = -3.0e38f;
  }
}

// ---------------------------------------------------------------- gather + DCT + bands (fp32, staged)
// Round 21: two work-halving DCT symmetries (D[k,719-l] = (-1)^k D[k,l], an
// exact identity of the table's cos argument, <=1ulp in the fp32 table):
//  - phase 2 l-fold: X[p,k] = sum_{l<360} (xe[l] +/- xe[719-l]) D[k,l], sign
//    by k-parity. Thread's k's (t, t+256, t+512) share parity -> uniform u/v
//    row choice. fma, LDS reads, Dt loads all halve. u/v separated by the
//    proven 16B shim (round-10/11 lesson: e/o broadcast groups must be
//    bank-phase-disjoint).
//  - phase 3 n-parity split: out[n] = En+On, out[719-n] = En-On where En/On
//    accumulate even/odd k of the band. 9 fma/k serves TWO outputs.
// fp32 reorder perturbation ~1e-6 rel — negligible vs the 0.0156 quantization
// floor. Gathers read coalesced xT rows.
__global__ __launch_bounds__(256) void k_out(const float* __restrict__ xT,
                                             const float* __restrict__ D,
                                             const float* __restrict__ Dt,
                                             const int* __restrict__ lid,
                                             const int* __restrict__ shf,
                                             const float* __restrict__ rv,
                                             float* __restrict__ out) {
  __shared__ __align__(16) float XsP[8640];   // X[k][12], p<9 used
  __shared__ __align__(16) float pool[8656];  // xep[720][12] -> u|shim|v -> obuf
  __shared__ int s_lid[8], s_shf[8];
  __shared__ float s_r[8];
  int b = blockIdx.x >> 7, c = blockIdx.x & 127;
  int t = threadIdx.x;
  if (t < 8) {
    int q = (((b << 7) + c) << 3) + t;
    s_lid[t] = lid[q]; s_shf[t] = shf[q]; s_r[t] = rv[q];
  }
  float* xep = pool;
  size_t cb = (size_t)(b * CCH + c) * LN;
  for (int l = t; l < LN; l += 256) xep[l * 12] = xT[cb + l];
  __syncthreads();
  for (int p = 1; p <= 8; p++) {
    float r = s_r[p - 1];
    if (fabsf(r) < 0.1f) {
      for (int l = t; l < LN; l += 256) xep[l * 12 + p] = xep[l * 12];
    } else {
      float sg = (r < 0.f) ? -1.f : 1.f;
      int ld = s_lid[p - 1], sh = s_shf[p - 1];
      size_t lb = (size_t)(b * CCH + ld) * LN;
      for (int l = t; l < LN; l += 256) {
        int tt = l - sh; tt = tt < 0 ? 0 : (tt > 719 ? 719 : tt);
        xep[l * 12 + p] = sg * xT[lb + tt];
      }
    }
  }
  __syncthreads();

  // ---- fold l <-> 719-l into u (rows 0..359) and v (shimmed region) ----
  // reg-stage reads, sync, then write (avoids read/write races).
  float4 a0[2], a1[2], a2[2], b0[2], b1[2], b2[2];
  int pl[2] = {t, t + 256};
  bool hv[2] = {true, (t + 256) < 360};
#pragma unroll
  for (int q = 0; q < 2; q++) {
    if (pl[q] < 360) {
      const float4* ra = (const float4*)&xep[pl[q] * 12];
      const float4* rb = (const float4*)&xep[(719 - pl[q]) * 12];
      a0[q] = ra[0]; a1[q] = ra[1]; a2[q] = ra[2];
      b0[q] = rb[0]; b1[q] = rb[1]; b2[q] = rb[2];
    }
  }
  __syncthreads();
  float* uB = pool;              // u rows: byte 48*l
  float* vB = pool + 4324;       // v rows: byte 17296+48*l (16B shim vs u)
#pragma unroll
  for (int q = 0; q < 2; q++) {
    if (pl[q] < 360 && hv[q]) {
      float4 u0, u1, u2, v0, v1, v2;
      u0.x = a0[q].x + b0[q].x; u0.y = a0[q].y + b0[q].y; u0.z = a0[q].z + b0[q].z; u0.w = a0[q].w + b0[q].w;
      u1.x = a1[q].x + b1[q].x; u1.y = a1[q].y + b1[q].y; u1.z = a1[q].z + b1[q].z; u1.w = a1[q].w + b1[q].w;
      u2.x = a2[q].x + b2[q].x; u2.y = a2[q].y + b2[q].y; u2.z = a2[q].z + b2[q].z; u2.w = a2[q].w + b2[q].w;
      v0.x = a0[q].x - b0[q].x; v0.y = a0[q].y - b0[q].y; v0.z = a0[q].z - b0[q].z; v0.w = a0[q].w - b0[q].w;
      v1.x = a1[q].x - b1[q].x; v1.y = a1[q].y - b1[q].y; v1.z = a1[q].z - b1[q].z; v1.w = a1[q].w - b1[q].w;
      v2.x = a2[q].x - b2[q].x; v2.y = a2[q].y - b2[q].y; v2.z = a2[q].z - b2[q].z; v2.w = a2[q].w - b2[q].w;
      float4* wu = (float4*)&uB[pl[q] * 12];
      float4* wvp = (float4*)&vB[pl[q] * 12];
      wu[0] = u0; wu[1] = u1; wu[2] = u2;
      wvp[0] = v0; wvp[1] = v1; wvp[2] = v2;
    }
  }
  __syncthreads();

  // Phase 2: X[p,k] = sum_{l<360} w[p,l]*D[k,l], w = u (k even) / v (k odd).
  {
    int k0 = t, k1 = t + 256, k2 = t + 512;
    int k2c = (k2 < LN) ? k2 : k0;
    const float* wbase = (t & 1) ? vB : uB;
    float s0[9], s1[9], s2[9];
#pragma unroll
    for (int p = 0; p < 9; p++) { s0[p] = 0.f; s1[p] = 0.f; s2[p] = 0.f; }
    const float* DtRow = Dt;
    for (int l = 0; l < 360; l++) {
      const float4* row = (const float4*)&wbase[l * 12];
      float4 q0 = row[0], q1 = row[1];
      float x8 = wbase[l * 12 + 8];
      float xl[9] = {q0.x, q0.y, q0.z, q0.w, q1.x, q1.y, q1.z, q1.w, x8};
      float d0 = DtRow[k0], d1 = DtRow[k1], d2 = DtRow[k2c];
      DtRow += LN;
#pragma unroll
      for (int p = 0; p < 9; p++) {
        s0[p] += d0 * xl[p];
        s1[p] += d1 * xl[p];
        s2[p] += d2 * xl[p];
      }
    }
#pragma unroll
    for (int p = 0; p < 9; p++) {
      XsP[k0 * 12 + p] = s0[p];
      XsP[k1 * 12 + p] = s1[p];
      if (k2 < LN) XsP[k2 * 12 + p] = s2[p];
    }
  }
  __syncthreads();

  // Phase 3: n-parity split. Thread owns pair P = c0p + (t&63), band f = t>>6.
  // En/On over the band's even/odd k; out[P] = En+On, out[719-P] = En-On.
  float* obuf = pool;
  size_t outbase = (size_t)((b << 7) + c) * (LN * 36);
  for (int c0p = 0; c0p < 360; c0p += 64) {
    int pr = t & 63;
    int f = t >> 6;
    int P = c0p + pr;
    int npair = (360 - c0p < 64) ? (360 - c0p) : 64;
    bool act = (P < 360);
    float En[9], On[9];
#pragma unroll
    for (int p = 0; p < 9; p++) { En[p] = 0.f; On[p] = 0.f; }
    if (act) {
      const float* Dp = D + (size_t)(f * 180) * LN + P;
      int kbase = f * 180;
      for (int kk = 0; kk < 180; kk += 2) {
        float d0 = Dp[0]; Dp += LN;
        float d1 = Dp[0]; Dp += LN;
        int k0 = kbase + kk;
        const float4* xr0 = (const float4*)&XsP[k0 * 12];
        float4 e0 = xr0[0], e1 = xr0[1];
        float e8 = XsP[k0 * 12 + 8];
        const float4* xr1 = (const float4*)&XsP[(k0 + 1) * 12];
        float4 o0 = xr1[0], o1 = xr1[1];
        float o8 = XsP[(k0 + 1) * 12 + 8];
        float xe_[9] = {e0.x, e0.y, e0.z, e0.w, e1.x, e1.y, e1.z, e1.w, e8};
        float xo_[9] = {o0.x, o0.y, o0.z, o0.w, o1.x, o1.y, o1.z, o1.w, o8};
#pragma unroll
        for (int p = 0; p < 9; p++) {
          En[p] += d0 * xe_[p];
          On[p] += d1 * xo_[p];
        }
      }
#pragma unroll
      for (int p = 0; p < 9; p++) {
        obuf[pr * 36 + p * 4 + f] = En[p] + On[p];
        obuf[(64 + pr) * 36 + p * 4 + f] = En[p] - On[p];
      }
    }
    __syncthreads();
    int tot = npair * 36;
    // low range: n = c0p + r (contiguous rows)
    for (int idx = t; idx < tot; idx += 256)
      out[outbase + (size_t)c0p * 36 + idx] = obuf[idx];
    // high range: n = 719 - (c0p + r)
    for (int idx = t; idx < tot; idx += 256) {
      int r = idx / 36, j = idx - r * 36;
      out[outbase + (size_t)(719 - c0p - r) * 36 + j] = obuf[(64 + r) * 36 + j];
    }
    __syncthreads();
  }
}

// ---------------------------------------------------------------- launch
extern "C" void kernel_launch(void* const* d_in, const int* in_sizes, int n_in,
                              void* d_out, int out_size, void* d_ws, size_t ws_size,
                              hipStream_t stream) {
  const float* x = (const float*)d_in[0];
  float* out = (float*)d_out;

  char* ws = (char*)d_ws;
  double* ct  = (double*)ws;                      // 720
  double* st  = ct + 720;                         // 720
  double2* CSm = (double2*)(st + 720);            // 184*384 interleaved (C,S)
  float*  nRr = (float*)(CSm + KROWS * TCOLS);    // 1024*361
  float*  nIr = nRr + 1024 * NBIN;                // 1024*361
  float*  Mv  = nIr + 1024 * NBIN;                // 8*128*128
  float*  rv  = Mv + 8 * 128 * 128;               // 8*128*8
  float*  D   = rv + 8 * 128 * 8;                 // 720*720 (16B-aligned)
  float*  Dt  = D + 720 * 720;                    // 720*720 transposed copy
  int*    Mi  = (int*)(Dt + 720 * 720);           // 8*128*128
  int*    lid = Mi + 8 * 128 * 128;               // 8*128*8
  int*    shf = lid + 8 * 128 * 8;                // 8*128*8
  int2*   ptab = (int2*)(shf + 8 * 128 * 8);      // 8128
  float*  xT  = (float*)(ptab + NPAIRS);          // 8*128*720 transposed input

  k_twiddle<<<3, 256, 0, stream>>>(ct, st);
  k_wmat<<<(KROWS * TCOLS + 255) / 256, 256, 0, stream>>>(ct, st, CSm);
  k_ptab<<<(NPAIRS + 255) / 256, 256, 0, stream>>>(ptab);
  k_dctmat<<<(720 * 720 + 255) / 256, 256, 0, stream>>>(D, Dt);
  k_xT<<<720, 256, 0, stream>>>(x, xT);
  k_rfft<<<8 * 128, 192, 0, stream>>>(xT, ct, st, nRr, nIr);
  k_pc<<<8 * NPG, 192, 0, stream>>>(nRr, nIr, CSm, ptab, Mv, Mi);
  k_topk<<<8 * 128, 64, 0, stream>>>(Mv, Mi, lid, shf, rv);
  k_out<<<8 * 128, 256, 0, stream>>>(xT, D, Dt, lid, shf, rv, out);
}